// Round 6
// baseline (2892.912 us; speedup 1.0000x reference)
//
#include <hip/hip_runtime.h>
#include <hip/hip_bf16.h>
#include <math.h>

#define B_SZ    32
#define LSEQ    1024
#define DIN     128
#define HDIM    256
#define NLAYERS 4
#define NSTATE  32
#define DOUT    10
#define M_ROWS  (B_SZ*LSEQ)   // 32768
#define CH      64            // scan chunk length
#define NCH     (LSEQ/CH)     // 16 chunks

typedef __hip_bfloat16 bf16;
typedef __attribute__((ext_vector_type(8))) short bf16x8;
typedef __attribute__((ext_vector_type(4))) float f32x4;

// ---------------- per-(layer,h,n) discretized params ----------------
__global__ void k_params(const float* __restrict__ log_dt, const float* __restrict__ A_re_log,
                         const float* __restrict__ A_im, const float* __restrict__ B_re,
                         const float* __restrict__ B_im, const float* __restrict__ C_re,
                         const float* __restrict__ C_im, float4* __restrict__ PWt,
                         float2* __restrict__ PA64) {
    int idx = blockIdx.x * 256 + threadIdx.x;       // layer*H*N + h*N + n
    int n = idx & 31, hn = idx >> 5;
    int h = hn & 255, layer = hn >> 8;
    float dt   = expf(log_dt[hn]);
    float Are  = -expf(A_re_log[idx]);
    float Aim  = A_im[idx];
    float dtAre = dt * Are, dtAim = dt * Aim;
    float ea   = expf(dtAre);
    float dAre = ea * cosf(dtAim), dAim = ea * sinf(dtAim);
    float nre = dAre - 1.0f, nim = dAim;            // dA - 1
    float inv = 1.0f / (Are * Are + Aim * Aim);
    float tre = (nre * Are + nim * Aim) * inv;      // (dA-1)/A
    float tim = (nim * Are - nre * Aim) * inv;
    float Brv = B_re[idx], Biv = B_im[idx];
    float dBre = Brv * tre - Biv * tim;
    float dBim = Brv * tim + Biv * tre;
    float Crv = C_re[idx], Civ = C_im[idx];
    float Wre = Crv * dBre - Civ * dBim;
    float Wim = Crv * dBim + Civ * dBre;
    int o = (layer * NSTATE + n) * HDIM + h;
    PWt[o] = make_float4(dAre, dAim, Wre, Wim);
    float e64 = expf(64.0f * dtAre);
    float ph  = 64.0f * dtAim;
    PA64[o] = make_float2(e64 * cosf(ph), e64 * sinf(ph));
}

// ---------------- one-off weight transpose+cast: Wt[layer][n(512)][k(256)] bf16 ----------------
__global__ void k_wcvt(const float* __restrict__ Wsrc, bf16* __restrict__ Wt) {
    int idx = blockIdx.x * 256 + threadIdx.x;   // ((layer*512)+n)*256+k
    int k = idx & 255;
    int n = (idx >> 8) & 511;
    int layer = idx >> 17;
    Wt[idx] = __float2bfloat16(Wsrc[((size_t)(layer * 256 + k)) * 512 + n]);
}

// ---------------- scan phase A: chunk-end states (all 32 modes in registers) ----------------
__global__ __launch_bounds__(256, 2) void k_scanA(const float* __restrict__ U,
                                                  const float4* __restrict__ PWt,
                                                  float2* __restrict__ E) {
    int c = blockIdx.x, b = blockIdx.y, h = threadIdx.x;
    const float* Ub = U + ((size_t)b * LSEQ + c * CH) * HDIM + h;
    float4 pw[NSTATE];
#pragma unroll
    for (int i = 0; i < NSTATE; ++i) pw[i] = PWt[i * HDIM + h];
    float sre[NSTATE] = {}, sim[NSTATE] = {};
    for (int j = 0; j < CH; j += 4) {
        float u0 = Ub[(j + 0) * HDIM], u1 = Ub[(j + 1) * HDIM];
        float u2 = Ub[(j + 2) * HDIM], u3 = Ub[(j + 3) * HDIM];
#define ASTEP(UU)                                                               \
        _Pragma("unroll")                                                       \
        for (int i = 0; i < NSTATE; ++i) {                                      \
            float nr = fmaf(pw[i].x, sre[i], fmaf(-pw[i].y, sim[i], pw[i].z * (UU))); \
            sim[i]   = fmaf(pw[i].x, sim[i], fmaf( pw[i].y, sre[i], pw[i].w * (UU))); \
            sre[i] = nr;                                                        \
        }
        ASTEP(u0) ASTEP(u1) ASTEP(u2) ASTEP(u3)
#undef ASTEP
    }
#pragma unroll
    for (int i = 0; i < NSTATE; ++i)
        E[((size_t)(b * NCH + c) * NSTATE + i) * HDIM + h] = make_float2(sre[i], sim[i]);
}

// ---------------- scan phase B: carry scan over chunks (in place) ----------------
__global__ void k_scanB(float2* __restrict__ E, const float2* __restrict__ PA64) {
    int n = blockIdx.x, b = blockIdx.y, h = threadIdx.x;
    float2 a = PA64[n * HDIM + h];
    float cr = 0.f, ci = 0.f;
    for (int c = 0; c < NCH; ++c) {
        size_t off = ((size_t)(b * NCH + c) * NSTATE + n) * HDIM + h;
        float2 e = E[off];
        E[off] = make_float2(cr, ci);
        float nr = fmaf(a.x, cr, fmaf(-a.y, ci, e.x));
        ci = fmaf(a.x, ci, fmaf(a.y, cr, e.y));
        cr = nr;
    }
}

// ---------------- scan phase C: seeded re-scan + D*u + GELU -> bf16 Y (register-only) ----------------
__global__ __launch_bounds__(256, 2) void k_scanC(const float* __restrict__ U,
                                                  const float4* __restrict__ PWt,
                                                  const float2* __restrict__ E,
                                                  const float* __restrict__ Dw,
                                                  bf16* __restrict__ Yout) {
    int c = blockIdx.x, b = blockIdx.y, h = threadIdx.x;
    const float* Ub = U + ((size_t)b * LSEQ + c * CH) * HDIM + h;
    bf16*        Yb = Yout + ((size_t)b * LSEQ + c * CH) * HDIM + h;
    float4 pw[NSTATE];
    float sre[NSTATE], sim[NSTATE];
#pragma unroll
    for (int i = 0; i < NSTATE; ++i) {
        pw[i] = PWt[i * HDIM + h];
        float2 e = E[((size_t)(b * NCH + c) * NSTATE + i) * HDIM + h];
        sre[i] = e.x; sim[i] = e.y;
    }
    float Dv = Dw[h];
    for (int j = 0; j < CH; j += 4) {
        float uu[4];
        uu[0] = Ub[(j + 0) * HDIM]; uu[1] = Ub[(j + 1) * HDIM];
        uu[2] = Ub[(j + 2) * HDIM]; uu[3] = Ub[(j + 3) * HDIM];
#pragma unroll
        for (int q = 0; q < 4; ++q) {
            float u = uu[q];
            float s = 0.f;
#pragma unroll
            for (int i = 0; i < NSTATE; ++i) {
                float nr = fmaf(pw[i].x, sre[i], fmaf(-pw[i].y, sim[i], pw[i].z * u));
                sim[i]   = fmaf(pw[i].x, sim[i], fmaf( pw[i].y, sre[i], pw[i].w * u));
                sre[i] = nr; s += nr;
            }
            float v = fmaf(Dv, u, 2.0f * s);
            // gelu(v) = v * sigmoid(2*z), z = 0.79788456*(v + 0.044715 v^3)
            float z2 = 1.5957691216057308f * (v + 0.044715f * v * v * v);
            float g = v / (1.0f + __expf(-z2));
            Yb[(j + q) * HDIM] = __float2bfloat16(g);
        }
    }
}

// ---------------- encoder GEMM: H0[M,256] = X[M,128]@W + b (fp32 vector) ----------------
__global__ __launch_bounds__(256) void k_enc(const float* __restrict__ X, const float* __restrict__ W,
                                             const float* __restrict__ bias, float* __restrict__ out) {
    __shared__ float As[128][33];
    __shared__ float Bs[32][128];
    int m0 = blockIdx.x * 128, n0 = blockIdx.y * 128;
    int tid = threadIdx.x;
    int tx = tid & 15, ty = tid >> 4;
    float acc[8][8] = {};
    for (int kt = 0; kt < DIN; kt += 32) {
#pragma unroll
        for (int i = 0; i < 16; ++i) {
            int e = tid + i * 256, kk = e & 31, mm = e >> 5;
            As[mm][kk] = X[(m0 + mm) * DIN + kt + kk];
        }
#pragma unroll
        for (int i = 0; i < 16; ++i) {
            int e = tid + i * 256, nn = e & 127, kk = e >> 7;
            Bs[kk][nn] = W[(kt + kk) * HDIM + n0 + nn];
        }
        __syncthreads();
#pragma unroll
        for (int kk = 0; kk < 32; ++kk) {
            float a[8], b[8];
#pragma unroll
            for (int i = 0; i < 8; ++i) a[i] = As[ty * 8 + i][kk];
#pragma unroll
            for (int j = 0; j < 8; ++j) b[j] = Bs[kk][tx * 8 + j];
#pragma unroll
            for (int i = 0; i < 8; ++i)
#pragma unroll
                for (int j = 0; j < 8; ++j) acc[i][j] = fmaf(a[i], b[j], acc[i][j]);
        }
        __syncthreads();
    }
#pragma unroll
    for (int i = 0; i < 8; ++i) {
        int m = m0 + ty * 8 + i;
#pragma unroll
        for (int j = 0; j < 8; ++j) {
            int n = n0 + tx * 8 + j;
            out[m * HDIM + n] = acc[i][j] + bias[n];
        }
    }
}

// ---------------- output GEMM + fused GLU, bf16 MFMA ----------------
__global__ __launch_bounds__(256) void k_glu(const bf16* __restrict__ Ybf,
                                             const bf16* __restrict__ Wt,
                                             const float* __restrict__ wb,
                                             float* __restrict__ G) {
    __shared__ short A_s[128 * 72];
    __shared__ short B1_s[64 * 72];
    __shared__ short B2_s[64 * 72];
    int tid = threadIdx.x;
    int lane = tid & 63, wv = tid >> 6;
    int quad = lane >> 4, fr = lane & 15;
    int m0 = blockIdx.x * 128, n0 = blockIdx.y * 64;
    f32x4 acc1[2][4], acc2[2][4];
#pragma unroll
    for (int mt = 0; mt < 2; ++mt)
#pragma unroll
        for (int nt = 0; nt < 4; ++nt) {
            acc1[mt][nt] = (f32x4){0.f,0.f,0.f,0.f};
            acc2[mt][nt] = (f32x4){0.f,0.f,0.f,0.f};
        }
    for (int kt = 0; kt < HDIM; kt += 64) {
#pragma unroll
        for (int i = 0; i < 4; ++i) {            // A tile: 128 rows x 64 k
            int e = tid + i * 256, row = e >> 3, cm = e & 7;
            *(uint4*)&A_s[row * 72 + cm * 8] =
                *(const uint4*)(Ybf + (size_t)(m0 + row) * HDIM + kt + cm * 8);
        }
#pragma unroll
        for (int i = 0; i < 2; ++i) {            // B tiles: 64 n-rows x 64 k each
            int e = tid + i * 256, row = e >> 3, cm = e & 7;
            *(uint4*)&B1_s[row * 72 + cm * 8] =
                *(const uint4*)(Wt + (size_t)(n0 + row) * HDIM + kt + cm * 8);
            *(uint4*)&B2_s[row * 72 + cm * 8] =
                *(const uint4*)(Wt + (size_t)(256 + n0 + row) * HDIM + kt + cm * 8);
        }
        __syncthreads();
#pragma unroll
        for (int s = 0; s < 2; ++s) {            // two K=32 MFMA steps per stage
            bf16x8 a[2], b1[4], b2[4];
#pragma unroll
            for (int mt = 0; mt < 2; ++mt)
                a[mt] = *(const bf16x8*)&A_s[(wv * 32 + mt * 16 + fr) * 72 + s * 32 + quad * 8];
#pragma unroll
            for (int nt = 0; nt < 4; ++nt) {
                b1[nt] = *(const bf16x8*)&B1_s[(nt * 16 + fr) * 72 + s * 32 + quad * 8];
                b2[nt] = *(const bf16x8*)&B2_s[(nt * 16 + fr) * 72 + s * 32 + quad * 8];
            }
#pragma unroll
            for (int mt = 0; mt < 2; ++mt)
#pragma unroll
                for (int nt = 0; nt < 4; ++nt) {
                    acc1[mt][nt] = __builtin_amdgcn_mfma_f32_16x16x32_bf16(a[mt], b1[nt], acc1[mt][nt], 0, 0, 0);
                    acc2[mt][nt] = __builtin_amdgcn_mfma_f32_16x16x32_bf16(a[mt], b2[nt], acc2[mt][nt], 0, 0, 0);
                }
        }
        __syncthreads();
    }
#pragma unroll
    for (int mt = 0; mt < 2; ++mt)
#pragma unroll
        for (int nt = 0; nt < 4; ++nt) {
            int n = n0 + nt * 16 + fr;
            float b1v = wb[n], b2v = wb[HDIM + n];
#pragma unroll
            for (int r = 0; r < 4; ++r) {
                int m = m0 + wv * 32 + mt * 16 + quad * 4 + r;
                float z1 = acc1[mt][nt][r] + b1v;
                float z2 = acc2[mt][nt][r] + b2v;
                G[(size_t)m * HDIM + n] = z1 / (1.0f + __expf(-z2));
            }
        }
}

// ---------------- residual + LayerNorm (in place on H) ----------------
__global__ void k_ln(const float* __restrict__ G, float* __restrict__ Hb,
                     const float* __restrict__ w, const float* __restrict__ bb) {
    int row = blockIdx.x, hh = threadIdx.x;
    float r = G[row * HDIM + hh] + Hb[row * HDIM + hh];
    float s = r;
#pragma unroll
    for (int m = 1; m < 64; m <<= 1) s += __shfl_xor(s, m, 64);
    __shared__ float red[8];
    int wv = hh >> 6, lane = hh & 63;
    if (lane == 0) red[wv] = s;
    __syncthreads();
    float mean = (red[0] + red[1] + red[2] + red[3]) * (1.0f / HDIM);
    float d = r - mean;
    float s2 = d * d;
#pragma unroll
    for (int m = 1; m < 64; m <<= 1) s2 += __shfl_xor(s2, m, 64);
    if (lane == 0) red[4 + wv] = s2;
    __syncthreads();
    float var = (red[4] + red[5] + red[6] + red[7]) * (1.0f / HDIM);
    float rstd = rsqrtf(var + 1e-5f);
    Hb[row * HDIM + hh] = d * rstd * w[hh] + bb[hh];
}

// ---------------- decoder ----------------
__global__ void k_dec(const float* __restrict__ Hb, const float* __restrict__ dw,
                      const float* __restrict__ db, float* __restrict__ out) {
    __shared__ float ws[HDIM * DOUT];
    int tid = threadIdx.x;                    // 320 threads
    for (int e = tid; e < HDIM * DOUT; e += 320) ws[e] = dw[e];
    __syncthreads();
    int r = tid / DOUT, o = tid - r * DOUT;
    int row = blockIdx.x * 32 + r;
    float acc = db[o];
    const float* hp = Hb + row * HDIM;
#pragma unroll 8
    for (int k = 0; k < HDIM; ++k) acc = fmaf(hp[k], ws[k * DOUT + o], acc);
    out[row * DOUT + o] = acc;
}

extern "C" void kernel_launch(void* const* d_in, const int* in_sizes, int n_in,
                              void* d_out, int out_size, void* d_ws, size_t ws_size,
                              hipStream_t stream) {
    const float* x        = (const float*)d_in[0];
    const float* enc_w    = (const float*)d_in[1];
    const float* enc_b    = (const float*)d_in[2];
    const float* log_dt   = (const float*)d_in[3];
    const float* A_re_log = (const float*)d_in[4];
    const float* A_im     = (const float*)d_in[5];
    const float* B_re     = (const float*)d_in[6];
    const float* B_im     = (const float*)d_in[7];
    const float* C_re     = (const float*)d_in[8];
    const float* C_im     = (const float*)d_in[9];
    const float* Dp       = (const float*)d_in[10];
    const float* ln_w     = (const float*)d_in[11];
    const float* ln_b     = (const float*)d_in[12];
    const float* out_w    = (const float*)d_in[13];
    const float* out_b    = (const float*)d_in[14];
    const float* dec_w    = (const float*)d_in[15];
    const float* dec_b    = (const float*)d_in[16];
    float* outp = (float*)d_out;

    float* w = (float*)d_ws;
    const size_t PWE = (size_t)NLAYERS * NSTATE * HDIM;         // 32768
    float4* PWt  = (float4*)w;                                  // 512 KB
    float2* PA64 = (float2*)(w + 4 * PWE);                      // 256 KB
    float* Hbuf = w + 6 * PWE;                                  // 33.5 MB
    float* Gbuf = Hbuf + (size_t)M_ROWS * HDIM;                 // 33.5 MB, aliased with E
    float2* Ebuf = (float2*)Gbuf;                               // dead when G live
    bf16* Ybf = (bf16*)(Gbuf + (size_t)M_ROWS * HDIM);          // 16.7 MB
    bf16* Wt  = Ybf + (size_t)M_ROWS * HDIM;                    // 1 MB

    k_params<<<NLAYERS * HDIM * NSTATE / 256, 256, 0, stream>>>(log_dt, A_re_log, A_im,
                                                                B_re, B_im, C_re, C_im, PWt, PA64);
    k_wcvt<<<NLAYERS * 512 * 256 / 256, 256, 0, stream>>>(out_w, Wt);

    dim3 ge(M_ROWS / 128, HDIM / 128);
    k_enc<<<ge, 256, 0, stream>>>(x, enc_w, enc_b, Hbuf);

    for (int layer = 0; layer < NLAYERS; ++layer) {
        const float4* pwl = (const float4*)PWt + (size_t)layer * NSTATE * HDIM;
        const float2* pal = (const float2*)PA64 + (size_t)layer * NSTATE * HDIM;
        dim3 gac(NCH, B_SZ);
        k_scanA<<<gac, 256, 0, stream>>>(Hbuf, pwl, Ebuf);
        dim3 gb(NSTATE, B_SZ);
        k_scanB<<<gb, 256, 0, stream>>>(Ebuf, pal);
        k_scanC<<<gac, 256, 0, stream>>>(Hbuf, pwl, Ebuf, Dp + layer * HDIM, Ybf);
        dim3 gg(M_ROWS / 128, HDIM / 64);
        k_glu<<<gg, 256, 0, stream>>>(Ybf, Wt + (size_t)layer * 512 * HDIM,
                                      out_b + layer * 2 * HDIM, Gbuf);
        k_ln<<<M_ROWS, HDIM, 0, stream>>>(Gbuf, Hbuf, ln_w + layer * HDIM, ln_b + layer * HDIM);
    }
    k_dec<<<M_ROWS / 32, 320, 0, stream>>>(Hbuf, dec_w, dec_b, outp);
}

// Round 7
// 855.491 us; speedup vs baseline: 3.3816x; 3.3816x over previous
//
#include <hip/hip_runtime.h>
#include <hip/hip_bf16.h>
#include <math.h>

#define B_SZ    32
#define LSEQ    1024
#define DIN     128
#define HDIM    256
#define NLAYERS 4
#define NSTATE  32
#define DOUT    10
#define M_ROWS  (B_SZ*LSEQ)   // 32768
#define CH      64            // scan chunk length
#define NCH     (LSEQ/CH)     // 16 chunks

typedef __hip_bfloat16 bf16;
typedef __attribute__((ext_vector_type(8))) short bf16x8;
typedef __attribute__((ext_vector_type(4))) float f32x4;

// ---------------- per-(layer,h,n) discretized params ----------------
__global__ void k_params(const float* __restrict__ log_dt, const float* __restrict__ A_re_log,
                         const float* __restrict__ A_im, const float* __restrict__ B_re,
                         const float* __restrict__ B_im, const float* __restrict__ C_re,
                         const float* __restrict__ C_im, float4* __restrict__ PWt,
                         float2* __restrict__ PA64) {
    int idx = blockIdx.x * 256 + threadIdx.x;       // layer*H*N + h*N + n
    int n = idx & 31, hn = idx >> 5;
    int h = hn & 255, layer = hn >> 8;
    float dt   = expf(log_dt[hn]);
    float Are  = -expf(A_re_log[idx]);
    float Aim  = A_im[idx];
    float dtAre = dt * Are, dtAim = dt * Aim;
    float ea   = expf(dtAre);
    float dAre = ea * cosf(dtAim), dAim = ea * sinf(dtAim);
    float nre = dAre - 1.0f, nim = dAim;            // dA - 1
    float inv = 1.0f / (Are * Are + Aim * Aim);
    float tre = (nre * Are + nim * Aim) * inv;      // (dA-1)/A
    float tim = (nim * Are - nre * Aim) * inv;
    float Brv = B_re[idx], Biv = B_im[idx];
    float dBre = Brv * tre - Biv * tim;
    float dBim = Brv * tim + Biv * tre;
    float Crv = C_re[idx], Civ = C_im[idx];
    float Wre = Crv * dBre - Civ * dBim;
    float Wim = Crv * dBim + Civ * dBre;
    int o = (layer * NSTATE + n) * HDIM + h;
    PWt[o] = make_float4(dAre, dAim, Wre, Wim);
    float e64 = expf(64.0f * dtAre);
    float ph  = 64.0f * dtAim;
    PA64[o] = make_float2(e64 * cosf(ph), e64 * sinf(ph));
}

// ---------------- one-off weight transpose+cast: Wt[layer][n(512)][k(256)] bf16 ----------------
__global__ void k_wcvt(const float* __restrict__ Wsrc, bf16* __restrict__ Wt) {
    int idx = blockIdx.x * 256 + threadIdx.x;   // ((layer*512)+n)*256+k
    int k = idx & 255;
    int n = (idx >> 8) & 511;
    int layer = idx >> 17;
    Wt[idx] = __float2bfloat16(Wsrc[((size_t)(layer * 256 + k)) * 512 + n]);
}

// ---------------- scan phase A: chunk-end states (8-mode tiles, 88 VGPR — proven) ----------------
__global__ __launch_bounds__(256) void k_scanA(const float* __restrict__ U,
                                               const float4* __restrict__ PWt,
                                               float2* __restrict__ E) {
    int c = blockIdx.x, b = blockIdx.y, h = threadIdx.x;
    const float* Ub = U + ((size_t)b * LSEQ + c * CH) * HDIM + h;
    for (int t = 0; t < 4; ++t) {                  // 4 mode-tiles of 8
        float4 pw[8];
#pragma unroll
        for (int i = 0; i < 8; ++i) pw[i] = PWt[(t * 8 + i) * HDIM + h];
        float sre[8] = {}, sim[8] = {};
        for (int j = 0; j < CH; j += 4) {
            float u0 = Ub[(j + 0) * HDIM], u1 = Ub[(j + 1) * HDIM];
            float u2 = Ub[(j + 2) * HDIM], u3 = Ub[(j + 3) * HDIM];
#define ASTEP(UU)                                                               \
            _Pragma("unroll")                                                   \
            for (int i = 0; i < 8; ++i) {                                       \
                float nr = fmaf(pw[i].x, sre[i], fmaf(-pw[i].y, sim[i], pw[i].z * (UU))); \
                sim[i]   = fmaf(pw[i].x, sim[i], fmaf( pw[i].y, sre[i], pw[i].w * (UU))); \
                sre[i] = nr;                                                    \
            }
            ASTEP(u0) ASTEP(u1) ASTEP(u2) ASTEP(u3)
#undef ASTEP
        }
#pragma unroll
        for (int i = 0; i < 8; ++i)
            E[((size_t)(b * NCH + c) * NSTATE + t * 8 + i) * HDIM + h] = make_float2(sre[i], sim[i]);
    }
}

// ---------------- scan phase B: carry scan over chunks (in place) ----------------
__global__ void k_scanB(float2* __restrict__ E, const float2* __restrict__ PA64) {
    int n = blockIdx.x, b = blockIdx.y, h = threadIdx.x;
    float2 a = PA64[n * HDIM + h];
    float cr = 0.f, ci = 0.f;
    for (int c = 0; c < NCH; ++c) {
        size_t off = ((size_t)(b * NCH + c) * NSTATE + n) * HDIM + h;
        float2 e = E[off];
        E[off] = make_float2(cr, ci);
        float nr = fmaf(a.x, cr, fmaf(-a.y, ci, e.x));
        ci = fmaf(a.x, ci, fmaf(a.y, cr, e.y));
        cr = nr;
    }
}

// ---------------- scan phase C: seeded re-scan, y[CH] in registers, no LDS ----------------
__global__ __launch_bounds__(256) void k_scanC(const float* __restrict__ U,
                                               const float4* __restrict__ PWt,
                                               const float2* __restrict__ E,
                                               const float* __restrict__ Dw,
                                               bf16* __restrict__ Yout) {
    int c = blockIdx.x, b = blockIdx.y, h = threadIdx.x;
    const float* Ub = U + ((size_t)b * LSEQ + c * CH) * HDIM + h;
    bf16*        Yb = Yout + ((size_t)b * LSEQ + c * CH) * HDIM + h;
    float y[CH];
    for (int t = 0; t < 4; ++t) {                  // 4 mode-tiles of 8
        float4 pw[8];
        float sre[8], sim[8];
#pragma unroll
        for (int i = 0; i < 8; ++i) {
            pw[i] = PWt[(t * 8 + i) * HDIM + h];
            float2 e = E[((size_t)(b * NCH + c) * NSTATE + t * 8 + i) * HDIM + h];
            sre[i] = e.x; sim[i] = e.y;
        }
#pragma unroll
        for (int j = 0; j < CH; ++j) {             // compile-time j: y[] stays in regs
            float u = Ub[j * HDIM];
            float s = 0.f;
#pragma unroll
            for (int i = 0; i < 8; ++i) {
                float nr = fmaf(pw[i].x, sre[i], fmaf(-pw[i].y, sim[i], pw[i].z * u));
                sim[i]   = fmaf(pw[i].x, sim[i], fmaf( pw[i].y, sre[i], pw[i].w * u));
                sre[i] = nr; s += nr;
            }
            if (t == 0) y[j] = s; else y[j] += s;
        }
    }
    float Dv = Dw[h];
#pragma unroll
    for (int j = 0; j < CH; ++j) {                 // epilogue: D*u + gelu (u re-read, L2-hot)
        float u = Ub[j * HDIM];
        float v = fmaf(Dv, u, 2.0f * y[j]);
        float z2 = 1.5957691216057308f * (v + 0.044715f * v * v * v);
        float g = v / (1.0f + __expf(-z2));        // gelu(v) = v*sigmoid(2z)
        Yb[j * HDIM] = __float2bfloat16(g);
    }
}

// ---------------- encoder GEMM: H0[M,256] = X[M,128]@W + b (fp32 vector) ----------------
__global__ __launch_bounds__(256) void k_enc(const float* __restrict__ X, const float* __restrict__ W,
                                             const float* __restrict__ bias, float* __restrict__ out) {
    __shared__ float As[128][33];
    __shared__ float Bs[32][128];
    int m0 = blockIdx.x * 128, n0 = blockIdx.y * 128;
    int tid = threadIdx.x;
    int tx = tid & 15, ty = tid >> 4;
    float acc[8][8] = {};
    for (int kt = 0; kt < DIN; kt += 32) {
#pragma unroll
        for (int i = 0; i < 16; ++i) {
            int e = tid + i * 256, kk = e & 31, mm = e >> 5;
            As[mm][kk] = X[(m0 + mm) * DIN + kt + kk];
        }
#pragma unroll
        for (int i = 0; i < 16; ++i) {
            int e = tid + i * 256, nn = e & 127, kk = e >> 7;
            Bs[kk][nn] = W[(kt + kk) * HDIM + n0 + nn];
        }
        __syncthreads();
#pragma unroll
        for (int kk = 0; kk < 32; ++kk) {
            float a[8], b[8];
#pragma unroll
            for (int i = 0; i < 8; ++i) a[i] = As[ty * 8 + i][kk];
#pragma unroll
            for (int j = 0; j < 8; ++j) b[j] = Bs[kk][tx * 8 + j];
#pragma unroll
            for (int i = 0; i < 8; ++i)
#pragma unroll
                for (int j = 0; j < 8; ++j) acc[i][j] = fmaf(a[i], b[j], acc[i][j]);
        }
        __syncthreads();
    }
#pragma unroll
    for (int i = 0; i < 8; ++i) {
        int m = m0 + ty * 8 + i;
#pragma unroll
        for (int j = 0; j < 8; ++j) {
            int n = n0 + tx * 8 + j;
            out[m * HDIM + n] = acc[i][j] + bias[n];
        }
    }
}

// ---------------- output GEMM + fused GLU, bf16 MFMA ----------------
__global__ __launch_bounds__(256) void k_glu(const bf16* __restrict__ Ybf,
                                             const bf16* __restrict__ Wt,
                                             const float* __restrict__ wb,
                                             float* __restrict__ G) {
    __shared__ short A_s[128 * 72];
    __shared__ short B1_s[64 * 72];
    __shared__ short B2_s[64 * 72];
    int tid = threadIdx.x;
    int lane = tid & 63, wv = tid >> 6;
    int quad = lane >> 4, fr = lane & 15;
    int m0 = blockIdx.x * 128, n0 = blockIdx.y * 64;
    f32x4 acc1[2][4], acc2[2][4];
#pragma unroll
    for (int mt = 0; mt < 2; ++mt)
#pragma unroll
        for (int nt = 0; nt < 4; ++nt) {
            acc1[mt][nt] = (f32x4){0.f,0.f,0.f,0.f};
            acc2[mt][nt] = (f32x4){0.f,0.f,0.f,0.f};
        }
    for (int kt = 0; kt < HDIM; kt += 64) {
#pragma unroll
        for (int i = 0; i < 4; ++i) {            // A tile: 128 rows x 64 k
            int e = tid + i * 256, row = e >> 3, cm = e & 7;
            *(uint4*)&A_s[row * 72 + cm * 8] =
                *(const uint4*)(Ybf + (size_t)(m0 + row) * HDIM + kt + cm * 8);
        }
#pragma unroll
        for (int i = 0; i < 2; ++i) {            // B tiles: 64 n-rows x 64 k each
            int e = tid + i * 256, row = e >> 3, cm = e & 7;
            *(uint4*)&B1_s[row * 72 + cm * 8] =
                *(const uint4*)(Wt + (size_t)(n0 + row) * HDIM + kt + cm * 8);
            *(uint4*)&B2_s[row * 72 + cm * 8] =
                *(const uint4*)(Wt + (size_t)(256 + n0 + row) * HDIM + kt + cm * 8);
        }
        __syncthreads();
#pragma unroll
        for (int s = 0; s < 2; ++s) {            // two K=32 MFMA steps per stage
            bf16x8 a[2], b1[4], b2[4];
#pragma unroll
            for (int mt = 0; mt < 2; ++mt)
                a[mt] = *(const bf16x8*)&A_s[(wv * 32 + mt * 16 + fr) * 72 + s * 32 + quad * 8];
#pragma unroll
            for (int nt = 0; nt < 4; ++nt) {
                b1[nt] = *(const bf16x8*)&B1_s[(nt * 16 + fr) * 72 + s * 32 + quad * 8];
                b2[nt] = *(const bf16x8*)&B2_s[(nt * 16 + fr) * 72 + s * 32 + quad * 8];
            }
#pragma unroll
            for (int mt = 0; mt < 2; ++mt)
#pragma unroll
                for (int nt = 0; nt < 4; ++nt) {
                    acc1[mt][nt] = __builtin_amdgcn_mfma_f32_16x16x32_bf16(a[mt], b1[nt], acc1[mt][nt], 0, 0, 0);
                    acc2[mt][nt] = __builtin_amdgcn_mfma_f32_16x16x32_bf16(a[mt], b2[nt], acc2[mt][nt], 0, 0, 0);
                }
        }
        __syncthreads();
    }
#pragma unroll
    for (int mt = 0; mt < 2; ++mt)
#pragma unroll
        for (int nt = 0; nt < 4; ++nt) {
            int n = n0 + nt * 16 + fr;
            float b1v = wb[n], b2v = wb[HDIM + n];
#pragma unroll
            for (int r = 0; r < 4; ++r) {
                int m = m0 + wv * 32 + mt * 16 + quad * 4 + r;
                float z1 = acc1[mt][nt][r] + b1v;
                float z2 = acc2[mt][nt][r] + b2v;
                G[(size_t)m * HDIM + n] = z1 / (1.0f + __expf(-z2));
            }
        }
}

// ---------------- residual + LayerNorm (in place on H) ----------------
__global__ void k_ln(const float* __restrict__ G, float* __restrict__ Hb,
                     const float* __restrict__ w, const float* __restrict__ bb) {
    int row = blockIdx.x, hh = threadIdx.x;
    float r = G[row * HDIM + hh] + Hb[row * HDIM + hh];
    float s = r;
#pragma unroll
    for (int m = 1; m < 64; m <<= 1) s += __shfl_xor(s, m, 64);
    __shared__ float red[8];
    int wv = hh >> 6, lane = hh & 63;
    if (lane == 0) red[wv] = s;
    __syncthreads();
    float mean = (red[0] + red[1] + red[2] + red[3]) * (1.0f / HDIM);
    float d = r - mean;
    float s2 = d * d;
#pragma unroll
    for (int m = 1; m < 64; m <<= 1) s2 += __shfl_xor(s2, m, 64);
    if (lane == 0) red[4 + wv] = s2;
    __syncthreads();
    float var = (red[4] + red[5] + red[6] + red[7]) * (1.0f / HDIM);
    float rstd = rsqrtf(var + 1e-5f);
    Hb[row * HDIM + hh] = d * rstd * w[hh] + bb[hh];
}

// ---------------- decoder ----------------
__global__ void k_dec(const float* __restrict__ Hb, const float* __restrict__ dw,
                      const float* __restrict__ db, float* __restrict__ out) {
    __shared__ float ws[HDIM * DOUT];
    int tid = threadIdx.x;                    // 320 threads
    for (int e = tid; e < HDIM * DOUT; e += 320) ws[e] = dw[e];
    __syncthreads();
    int r = tid / DOUT, o = tid - r * DOUT;
    int row = blockIdx.x * 32 + r;
    float acc = db[o];
    const float* hp = Hb + row * HDIM;
#pragma unroll 8
    for (int k = 0; k < HDIM; ++k) acc = fmaf(hp[k], ws[k * DOUT + o], acc);
    out[row * DOUT + o] = acc;
}

extern "C" void kernel_launch(void* const* d_in, const int* in_sizes, int n_in,
                              void* d_out, int out_size, void* d_ws, size_t ws_size,
                              hipStream_t stream) {
    const float* x        = (const float*)d_in[0];
    const float* enc_w    = (const float*)d_in[1];
    const float* enc_b    = (const float*)d_in[2];
    const float* log_dt   = (const float*)d_in[3];
    const float* A_re_log = (const float*)d_in[4];
    const float* A_im     = (const float*)d_in[5];
    const float* B_re     = (const float*)d_in[6];
    const float* B_im     = (const float*)d_in[7];
    const float* C_re     = (const float*)d_in[8];
    const float* C_im     = (const float*)d_in[9];
    const float* Dp       = (const float*)d_in[10];
    const float* ln_w     = (const float*)d_in[11];
    const float* ln_b     = (const float*)d_in[12];
    const float* out_w    = (const float*)d_in[13];
    const float* out_b    = (const float*)d_in[14];
    const float* dec_w    = (const float*)d_in[15];
    const float* dec_b    = (const float*)d_in[16];
    float* outp = (float*)d_out;

    float* w = (float*)d_ws;
    const size_t PWE = (size_t)NLAYERS * NSTATE * HDIM;         // 32768
    float4* PWt  = (float4*)w;                                  // 512 KB
    float2* PA64 = (float2*)(w + 4 * PWE);                      // 256 KB
    float* Hbuf = w + 6 * PWE;                                  // 33.5 MB
    float* Gbuf = Hbuf + (size_t)M_ROWS * HDIM;                 // 33.5 MB, aliased with E
    float2* Ebuf = (float2*)Gbuf;                               // dead when G live
    bf16* Ybf = (bf16*)(Gbuf + (size_t)M_ROWS * HDIM);          // 16.7 MB
    bf16* Wt  = Ybf + (size_t)M_ROWS * HDIM;                    // 1 MB

    k_params<<<NLAYERS * HDIM * NSTATE / 256, 256, 0, stream>>>(log_dt, A_re_log, A_im,
                                                                B_re, B_im, C_re, C_im, PWt, PA64);
    k_wcvt<<<NLAYERS * 512 * 256 / 256, 256, 0, stream>>>(out_w, Wt);

    dim3 ge(M_ROWS / 128, HDIM / 128);
    k_enc<<<ge, 256, 0, stream>>>(x, enc_w, enc_b, Hbuf);

    for (int layer = 0; layer < NLAYERS; ++layer) {
        const float4* pwl = (const float4*)PWt + (size_t)layer * NSTATE * HDIM;
        const float2* pal = (const float2*)PA64 + (size_t)layer * NSTATE * HDIM;
        dim3 gac(NCH, B_SZ);
        k_scanA<<<gac, 256, 0, stream>>>(Hbuf, pwl, Ebuf);
        dim3 gb(NSTATE, B_SZ);
        k_scanB<<<gb, 256, 0, stream>>>(Ebuf, pal);
        k_scanC<<<gac, 256, 0, stream>>>(Hbuf, pwl, Ebuf, Dp + layer * HDIM, Ybf);
        dim3 gg(M_ROWS / 128, HDIM / 64);
        k_glu<<<gg, 256, 0, stream>>>(Ybf, Wt + (size_t)layer * 512 * HDIM,
                                      out_b + layer * 2 * HDIM, Gbuf);
        k_ln<<<M_ROWS, HDIM, 0, stream>>>(Gbuf, Hbuf, ln_w + layer * HDIM, ln_b + layer * HDIM);
    }
    k_dec<<<M_ROWS / 32, 320, 0, stream>>>(Hbuf, dec_w, dec_b, outp);
}

// Round 8
// 838.056 us; speedup vs baseline: 3.4519x; 1.0208x over previous
//
#include <hip/hip_runtime.h>
#include <hip/hip_bf16.h>
#include <math.h>

#define B_SZ    32
#define LSEQ    1024
#define DIN     128
#define HDIM    256
#define NLAYERS 4
#define NSTATE  32
#define DOUT    10
#define M_ROWS  (B_SZ*LSEQ)   // 32768
#define CH      64            // scan chunk length
#define NCH     (LSEQ/CH)     // 16 chunks

typedef __hip_bfloat16 bf16;
typedef __attribute__((ext_vector_type(8))) short bf16x8;
typedef __attribute__((ext_vector_type(4))) float f32x4;
typedef __attribute__((ext_vector_type(2))) float f32x2;

__device__ __forceinline__ f32x2 pk_fma(f32x2 a, f32x2 b, f32x2 c) {
#if __has_builtin(__builtin_elementwise_fma)
    return __builtin_elementwise_fma(a, b, c);
#else
    f32x2 r; r.x = fmaf(a.x, b.x, c.x); r.y = fmaf(a.y, b.y, c.y); return r;
#endif
}

// ---------------- per-(layer,h,n) discretized params ----------------
__global__ void k_params(const float* __restrict__ log_dt, const float* __restrict__ A_re_log,
                         const float* __restrict__ A_im, const float* __restrict__ B_re,
                         const float* __restrict__ B_im, const float* __restrict__ C_re,
                         const float* __restrict__ C_im, float4* __restrict__ PWt,
                         float2* __restrict__ PA64) {
    int idx = blockIdx.x * 256 + threadIdx.x;       // layer*H*N + h*N + n
    int n = idx & 31, hn = idx >> 5;
    int h = hn & 255, layer = hn >> 8;
    float dt   = expf(log_dt[hn]);
    float Are  = -expf(A_re_log[idx]);
    float Aim  = A_im[idx];
    float dtAre = dt * Are, dtAim = dt * Aim;
    float ea   = expf(dtAre);
    float dAre = ea * cosf(dtAim), dAim = ea * sinf(dtAim);
    float nre = dAre - 1.0f, nim = dAim;            // dA - 1
    float inv = 1.0f / (Are * Are + Aim * Aim);
    float tre = (nre * Are + nim * Aim) * inv;      // (dA-1)/A
    float tim = (nim * Are - nre * Aim) * inv;
    float Brv = B_re[idx], Biv = B_im[idx];
    float dBre = Brv * tre - Biv * tim;
    float dBim = Brv * tim + Biv * tre;
    float Crv = C_re[idx], Civ = C_im[idx];
    float Wre = Crv * dBre - Civ * dBim;
    float Wim = Crv * dBim + Civ * dBre;
    int o = (layer * NSTATE + n) * HDIM + h;
    PWt[o] = make_float4(dAre, dAim, Wre, Wim);
    float e64 = expf(64.0f * dtAre);
    float ph  = 64.0f * dtAim;
    PA64[o] = make_float2(e64 * cosf(ph), e64 * sinf(ph));
}

// ---------------- one-off weight transpose+cast: Wt[layer][n(512)][k(256)] bf16 ----------------
__global__ void k_wcvt(const float* __restrict__ Wsrc, bf16* __restrict__ Wt) {
    int idx = blockIdx.x * 256 + threadIdx.x;   // ((layer*512)+n)*256+k
    int k = idx & 255;
    int n = (idx >> 8) & 511;
    int layer = idx >> 17;
    Wt[idx] = __float2bfloat16(Wsrc[((size_t)(layer * 256 + k)) * 512 + n]);
}

// ---------------- scan phase A: chunk-end states (pk-fp32 pairs, 1-wave blocks) ----------------
__global__ __launch_bounds__(64) void k_scanA(const float* __restrict__ U,
                                              const float4* __restrict__ PWt,
                                              float2* __restrict__ E) {
    int c = blockIdx.x, b = blockIdx.y;
    int h = blockIdx.z * 64 + threadIdx.x;
    const float* Ub = U + ((size_t)b * LSEQ + c * CH) * HDIM + h;
    for (int t = 0; t < 4; ++t) {                  // 4 mode-tiles of 8 = 4 pairs
        f32x2 ar[4], ai[4], wr[4], wi[4];
#pragma unroll
        for (int p = 0; p < 4; ++p) {
            float4 q0 = PWt[(t * 8 + 2 * p) * HDIM + h];
            float4 q1 = PWt[(t * 8 + 2 * p + 1) * HDIM + h];
            ar[p] = (f32x2){q0.x, q1.x}; ai[p] = (f32x2){q0.y, q1.y};
            wr[p] = (f32x2){q0.z, q1.z}; wi[p] = (f32x2){q0.w, q1.w};
        }
        f32x2 sr[4] = {}, si[4] = {};
        for (int j = 0; j < CH; j += 4) {
            float u0 = Ub[(j + 0) * HDIM], u1 = Ub[(j + 1) * HDIM];
            float u2 = Ub[(j + 2) * HDIM], u3 = Ub[(j + 3) * HDIM];
#define ASTEP(UU)                                                          \
            {                                                              \
                f32x2 uv = (f32x2){(UU), (UU)};                            \
                _Pragma("unroll")                                          \
                for (int p = 0; p < 4; ++p) {                              \
                    f32x2 nr = pk_fma(ar[p], sr[p], pk_fma(-ai[p], si[p], wr[p] * uv)); \
                    si[p]    = pk_fma(ar[p], si[p], pk_fma( ai[p], sr[p], wi[p] * uv)); \
                    sr[p] = nr;                                            \
                }                                                          \
            }
            ASTEP(u0) ASTEP(u1) ASTEP(u2) ASTEP(u3)
#undef ASTEP
        }
        size_t base = (size_t)(b * NCH + c) * NSTATE + t * 8;
#pragma unroll
        for (int p = 0; p < 4; ++p) {
            E[(base + 2 * p    ) * HDIM + h] = make_float2(sr[p].x, si[p].x);
            E[(base + 2 * p + 1) * HDIM + h] = make_float2(sr[p].y, si[p].y);
        }
    }
}

// ---------------- scan phase B: carry scan over chunks (in place) ----------------
__global__ void k_scanB(float2* __restrict__ E, const float2* __restrict__ PA64) {
    int n = blockIdx.x, b = blockIdx.y, h = threadIdx.x;
    float2 a = PA64[n * HDIM + h];
    float cr = 0.f, ci = 0.f;
    for (int c = 0; c < NCH; ++c) {
        size_t off = ((size_t)(b * NCH + c) * NSTATE + n) * HDIM + h;
        float2 e = E[off];
        E[off] = make_float2(cr, ci);
        float nr = fmaf(a.x, cr, fmaf(-a.y, ci, e.x));
        ci = fmaf(a.x, ci, fmaf(a.y, cr, e.y));
        cr = nr;
    }
}

// ---------------- scan phase C: seeded re-scan, y[CH] in regs, pk-fp32, + D*u + GELU ----------------
__global__ __launch_bounds__(64) void k_scanC(const float* __restrict__ U,
                                              const float4* __restrict__ PWt,
                                              const float2* __restrict__ E,
                                              const float* __restrict__ Dw,
                                              bf16* __restrict__ Yout) {
    int c = blockIdx.x, b = blockIdx.y;
    int h = blockIdx.z * 64 + threadIdx.x;
    const float* Ub = U + ((size_t)b * LSEQ + c * CH) * HDIM + h;
    bf16*        Yb = Yout + ((size_t)b * LSEQ + c * CH) * HDIM + h;
    float halfD = 0.5f * Dw[h];
    float y[CH];
    for (int t = 0; t < 4; ++t) {                  // 4 mode-tiles of 8 = 4 pairs
        f32x2 ar[4], ai[4], wr[4], wi[4], sr[4], si[4];
        size_t base = (size_t)(b * NCH + c) * NSTATE + t * 8;
#pragma unroll
        for (int p = 0; p < 4; ++p) {
            float4 q0 = PWt[(t * 8 + 2 * p) * HDIM + h];
            float4 q1 = PWt[(t * 8 + 2 * p + 1) * HDIM + h];
            ar[p] = (f32x2){q0.x, q1.x}; ai[p] = (f32x2){q0.y, q1.y};
            wr[p] = (f32x2){q0.z, q1.z}; wi[p] = (f32x2){q0.w, q1.w};
            float2 e0 = E[(base + 2 * p    ) * HDIM + h];
            float2 e1 = E[(base + 2 * p + 1) * HDIM + h];
            sr[p] = (f32x2){e0.x, e1.x}; si[p] = (f32x2){e0.y, e1.y};
        }
#pragma unroll
        for (int j = 0; j < CH; ++j) {             // compile-time j: y[] stays in regs
            float u = Ub[j * HDIM];
            f32x2 uv = (f32x2){u, u};
            f32x2 sacc = (f32x2){0.f, 0.f};
#pragma unroll
            for (int p = 0; p < 4; ++p) {
                f32x2 nr = pk_fma(ar[p], sr[p], pk_fma(-ai[p], si[p], wr[p] * uv));
                si[p]    = pk_fma(ar[p], si[p], pk_fma( ai[p], sr[p], wi[p] * uv));
                sr[p] = nr; sacc += nr;
            }
            float s = sacc.x + sacc.y;
            if (t == 0) y[j] = fmaf(halfD, u, s); else y[j] += s;
        }
    }
#pragma unroll
    for (int j = 0; j < CH; ++j) {                 // epilogue: gelu(2*y)
        float v = 2.0f * y[j];
        float z2 = 1.5957691216057308f * (v + 0.044715f * v * v * v);
        float g = v / (1.0f + __expf(-z2));        // gelu(v) = v*sigmoid(2z)
        Yb[j * HDIM] = __float2bfloat16(g);
    }
}

// ---------------- encoder GEMM: H0[M,256] = X[M,128]@W + b (fp32 vector) ----------------
__global__ __launch_bounds__(256) void k_enc(const float* __restrict__ X, const float* __restrict__ W,
                                             const float* __restrict__ bias, float* __restrict__ out) {
    __shared__ float As[128][33];
    __shared__ float Bs[32][128];
    int m0 = blockIdx.x * 128, n0 = blockIdx.y * 128;
    int tid = threadIdx.x;
    int tx = tid & 15, ty = tid >> 4;
    float acc[8][8] = {};
    for (int kt = 0; kt < DIN; kt += 32) {
#pragma unroll
        for (int i = 0; i < 16; ++i) {
            int e = tid + i * 256, kk = e & 31, mm = e >> 5;
            As[mm][kk] = X[(m0 + mm) * DIN + kt + kk];
        }
#pragma unroll
        for (int i = 0; i < 16; ++i) {
            int e = tid + i * 256, nn = e & 127, kk = e >> 7;
            Bs[kk][nn] = W[(kt + kk) * HDIM + n0 + nn];
        }
        __syncthreads();
#pragma unroll
        for (int kk = 0; kk < 32; ++kk) {
            float a[8], b[8];
#pragma unroll
            for (int i = 0; i < 8; ++i) a[i] = As[ty * 8 + i][kk];
#pragma unroll
            for (int j = 0; j < 8; ++j) b[j] = Bs[kk][tx * 8 + j];
#pragma unroll
            for (int i = 0; i < 8; ++i)
#pragma unroll
                for (int j = 0; j < 8; ++j) acc[i][j] = fmaf(a[i], b[j], acc[i][j]);
        }
        __syncthreads();
    }
#pragma unroll
    for (int i = 0; i < 8; ++i) {
        int m = m0 + ty * 8 + i;
#pragma unroll
        for (int j = 0; j < 8; ++j) {
            int n = n0 + tx * 8 + j;
            out[m * HDIM + n] = acc[i][j] + bias[n];
        }
    }
}

// ---------------- output GEMM + fused GLU, bf16 MFMA ----------------
__global__ __launch_bounds__(256) void k_glu(const bf16* __restrict__ Ybf,
                                             const bf16* __restrict__ Wt,
                                             const float* __restrict__ wb,
                                             float* __restrict__ G) {
    __shared__ short A_s[128 * 72];
    __shared__ short B1_s[64 * 72];
    __shared__ short B2_s[64 * 72];
    int tid = threadIdx.x;
    int lane = tid & 63, wv = tid >> 6;
    int quad = lane >> 4, fr = lane & 15;
    int m0 = blockIdx.x * 128, n0 = blockIdx.y * 64;
    f32x4 acc1[2][4], acc2[2][4];
#pragma unroll
    for (int mt = 0; mt < 2; ++mt)
#pragma unroll
        for (int nt = 0; nt < 4; ++nt) {
            acc1[mt][nt] = (f32x4){0.f,0.f,0.f,0.f};
            acc2[mt][nt] = (f32x4){0.f,0.f,0.f,0.f};
        }
    for (int kt = 0; kt < HDIM; kt += 64) {
#pragma unroll
        for (int i = 0; i < 4; ++i) {            // A tile: 128 rows x 64 k
            int e = tid + i * 256, row = e >> 3, cm = e & 7;
            *(uint4*)&A_s[row * 72 + cm * 8] =
                *(const uint4*)(Ybf + (size_t)(m0 + row) * HDIM + kt + cm * 8);
        }
#pragma unroll
        for (int i = 0; i < 2; ++i) {            // B tiles: 64 n-rows x 64 k each
            int e = tid + i * 256, row = e >> 3, cm = e & 7;
            *(uint4*)&B1_s[row * 72 + cm * 8] =
                *(const uint4*)(Wt + (size_t)(n0 + row) * HDIM + kt + cm * 8);
            *(uint4*)&B2_s[row * 72 + cm * 8] =
                *(const uint4*)(Wt + (size_t)(256 + n0 + row) * HDIM + kt + cm * 8);
        }
        __syncthreads();
#pragma unroll
        for (int s = 0; s < 2; ++s) {            // two K=32 MFMA steps per stage
            bf16x8 a[2], b1[4], b2[4];
#pragma unroll
            for (int mt = 0; mt < 2; ++mt)
                a[mt] = *(const bf16x8*)&A_s[(wv * 32 + mt * 16 + fr) * 72 + s * 32 + quad * 8];
#pragma unroll
            for (int nt = 0; nt < 4; ++nt) {
                b1[nt] = *(const bf16x8*)&B1_s[(nt * 16 + fr) * 72 + s * 32 + quad * 8];
                b2[nt] = *(const bf16x8*)&B2_s[(nt * 16 + fr) * 72 + s * 32 + quad * 8];
            }
#pragma unroll
            for (int mt = 0; mt < 2; ++mt)
#pragma unroll
                for (int nt = 0; nt < 4; ++nt) {
                    acc1[mt][nt] = __builtin_amdgcn_mfma_f32_16x16x32_bf16(a[mt], b1[nt], acc1[mt][nt], 0, 0, 0);
                    acc2[mt][nt] = __builtin_amdgcn_mfma_f32_16x16x32_bf16(a[mt], b2[nt], acc2[mt][nt], 0, 0, 0);
                }
        }
        __syncthreads();
    }
#pragma unroll
    for (int mt = 0; mt < 2; ++mt)
#pragma unroll
        for (int nt = 0; nt < 4; ++nt) {
            int n = n0 + nt * 16 + fr;
            float b1v = wb[n], b2v = wb[HDIM + n];
#pragma unroll
            for (int r = 0; r < 4; ++r) {
                int m = m0 + wv * 32 + mt * 16 + quad * 4 + r;
                float z1 = acc1[mt][nt][r] + b1v;
                float z2 = acc2[mt][nt][r] + b2v;
                G[(size_t)m * HDIM + n] = z1 / (1.0f + __expf(-z2));
            }
        }
}

// ---------------- residual + LayerNorm (in place on H) ----------------
__global__ void k_ln(const float* __restrict__ G, float* __restrict__ Hb,
                     const float* __restrict__ w, const float* __restrict__ bb) {
    int row = blockIdx.x, hh = threadIdx.x;
    float r = G[row * HDIM + hh] + Hb[row * HDIM + hh];
    float s = r;
#pragma unroll
    for (int m = 1; m < 64; m <<= 1) s += __shfl_xor(s, m, 64);
    __shared__ float red[8];
    int wv = hh >> 6, lane = hh & 63;
    if (lane == 0) red[wv] = s;
    __syncthreads();
    float mean = (red[0] + red[1] + red[2] + red[3]) * (1.0f / HDIM);
    float d = r - mean;
    float s2 = d * d;
#pragma unroll
    for (int m = 1; m < 64; m <<= 1) s2 += __shfl_xor(s2, m, 64);
    if (lane == 0) red[4 + wv] = s2;
    __syncthreads();
    float var = (red[4] + red[5] + red[6] + red[7]) * (1.0f / HDIM);
    float rstd = rsqrtf(var + 1e-5f);
    Hb[row * HDIM + hh] = d * rstd * w[hh] + bb[hh];
}

// ---------------- decoder ----------------
__global__ void k_dec(const float* __restrict__ Hb, const float* __restrict__ dw,
                      const float* __restrict__ db, float* __restrict__ out) {
    __shared__ float ws[HDIM * DOUT];
    int tid = threadIdx.x;                    // 320 threads
    for (int e = tid; e < HDIM * DOUT; e += 320) ws[e] = dw[e];
    __syncthreads();
    int r = tid / DOUT, o = tid - r * DOUT;
    int row = blockIdx.x * 32 + r;
    float acc = db[o];
    const float* hp = Hb + row * HDIM;
#pragma unroll 8
    for (int k = 0; k < HDIM; ++k) acc = fmaf(hp[k], ws[k * DOUT + o], acc);
    out[row * DOUT + o] = acc;
}

extern "C" void kernel_launch(void* const* d_in, const int* in_sizes, int n_in,
                              void* d_out, int out_size, void* d_ws, size_t ws_size,
                              hipStream_t stream) {
    const float* x        = (const float*)d_in[0];
    const float* enc_w    = (const float*)d_in[1];
    const float* enc_b    = (const float*)d_in[2];
    const float* log_dt   = (const float*)d_in[3];
    const float* A_re_log = (const float*)d_in[4];
    const float* A_im     = (const float*)d_in[5];
    const float* B_re     = (const float*)d_in[6];
    const float* B_im     = (const float*)d_in[7];
    const float* C_re     = (const float*)d_in[8];
    const float* C_im     = (const float*)d_in[9];
    const float* Dp       = (const float*)d_in[10];
    const float* ln_w     = (const float*)d_in[11];
    const float* ln_b     = (const float*)d_in[12];
    const float* out_w    = (const float*)d_in[13];
    const float* out_b    = (const float*)d_in[14];
    const float* dec_w    = (const float*)d_in[15];
    const float* dec_b    = (const float*)d_in[16];
    float* outp = (float*)d_out;

    float* w = (float*)d_ws;
    const size_t PWE = (size_t)NLAYERS * NSTATE * HDIM;         // 32768
    float4* PWt  = (float4*)w;                                  // 512 KB
    float2* PA64 = (float2*)(w + 4 * PWE);                      // 256 KB
    float* Hbuf = w + 6 * PWE;                                  // 33.5 MB
    float* Gbuf = Hbuf + (size_t)M_ROWS * HDIM;                 // 33.5 MB, aliased with E
    float2* Ebuf = (float2*)Gbuf;                               // dead when G live
    bf16* Ybf = (bf16*)(Gbuf + (size_t)M_ROWS * HDIM);          // 16.7 MB
    bf16* Wt  = Ybf + (size_t)M_ROWS * HDIM;                    // 1 MB

    k_params<<<NLAYERS * HDIM * NSTATE / 256, 256, 0, stream>>>(log_dt, A_re_log, A_im,
                                                                B_re, B_im, C_re, C_im, PWt, PA64);
    k_wcvt<<<NLAYERS * 512 * 256 / 256, 256, 0, stream>>>(out_w, Wt);

    dim3 ge(M_ROWS / 128, HDIM / 128);
    k_enc<<<ge, 256, 0, stream>>>(x, enc_w, enc_b, Hbuf);

    for (int layer = 0; layer < NLAYERS; ++layer) {
        const float4* pwl = (const float4*)PWt + (size_t)layer * NSTATE * HDIM;
        const float2* pal = (const float2*)PA64 + (size_t)layer * NSTATE * HDIM;
        dim3 gac(NCH, B_SZ, HDIM / 64);
        k_scanA<<<gac, 64, 0, stream>>>(Hbuf, pwl, Ebuf);
        dim3 gb(NSTATE, B_SZ);
        k_scanB<<<gb, 256, 0, stream>>>(Ebuf, pal);
        k_scanC<<<gac, 64, 0, stream>>>(Hbuf, pwl, Ebuf, Dp + layer * HDIM, Ybf);
        dim3 gg(M_ROWS / 128, HDIM / 64);
        k_glu<<<gg, 256, 0, stream>>>(Ybf, Wt + (size_t)layer * 512 * HDIM,
                                      out_b + layer * 2 * HDIM, Gbuf);
        k_ln<<<M_ROWS, HDIM, 0, stream>>>(Gbuf, Hbuf, ln_w + layer * HDIM, ln_b + layer * HDIM);
    }
    k_dec<<<M_ROWS / 32, 320, 0, stream>>>(Hbuf, dec_w, dec_b, outp);
}

// Round 9
// 770.058 us; speedup vs baseline: 3.7567x; 1.0883x over previous
//
#include <hip/hip_runtime.h>
#include <hip/hip_bf16.h>
#include <math.h>

#define B_SZ    32
#define LSEQ    1024
#define DIN     128
#define HDIM    256
#define NLAYERS 4
#define NSTATE  32
#define DOUT    10
#define M_ROWS  (B_SZ*LSEQ)   // 32768
#define CH      64            // scan chunk length
#define NCH     (LSEQ/CH)     // 16 chunks

typedef __hip_bfloat16 bf16;
typedef __attribute__((ext_vector_type(8))) short bf16x8;
typedef __attribute__((ext_vector_type(4))) float f32x4;
typedef __attribute__((ext_vector_type(2))) float f32x2;

__device__ __forceinline__ f32x2 pk_fma(f32x2 a, f32x2 b, f32x2 c) {
#if __has_builtin(__builtin_elementwise_fma)
    return __builtin_elementwise_fma(a, b, c);
#else
    f32x2 r; r.x = fmaf(a.x, b.x, c.x); r.y = fmaf(a.y, b.y, c.y); return r;
#endif
}

// ---------------- per-(layer,h,n) discretized params ----------------
__global__ void k_params(const float* __restrict__ log_dt, const float* __restrict__ A_re_log,
                         const float* __restrict__ A_im, const float* __restrict__ B_re,
                         const float* __restrict__ B_im, const float* __restrict__ C_re,
                         const float* __restrict__ C_im, float4* __restrict__ PWt,
                         float2* __restrict__ PA64) {
    int idx = blockIdx.x * 256 + threadIdx.x;       // layer*H*N + h*N + n
    int n = idx & 31, hn = idx >> 5;
    int h = hn & 255, layer = hn >> 8;
    float dt   = expf(log_dt[hn]);
    float Are  = -expf(A_re_log[idx]);
    float Aim  = A_im[idx];
    float dtAre = dt * Are, dtAim = dt * Aim;
    float ea   = expf(dtAre);
    float dAre = ea * cosf(dtAim), dAim = ea * sinf(dtAim);
    float nre = dAre - 1.0f, nim = dAim;            // dA - 1
    float inv = 1.0f / (Are * Are + Aim * Aim);
    float tre = (nre * Are + nim * Aim) * inv;      // (dA-1)/A
    float tim = (nim * Are - nre * Aim) * inv;
    float Brv = B_re[idx], Biv = B_im[idx];
    float dBre = Brv * tre - Biv * tim;
    float dBim = Brv * tim + Biv * tre;
    float Crv = C_re[idx], Civ = C_im[idx];
    float Wre = Crv * dBre - Civ * dBim;
    float Wim = Crv * dBim + Civ * dBre;
    int o = (layer * NSTATE + n) * HDIM + h;
    PWt[o] = make_float4(dAre, dAim, Wre, Wim);
    float e64 = expf(64.0f * dtAre);
    float ph  = 64.0f * dtAim;
    PA64[o] = make_float2(e64 * cosf(ph), e64 * sinf(ph));
}

// ---------------- one-off weight transpose+cast: Wt[layer][n(512)][k(256)] bf16 ----------------
__global__ void k_wcvt(const float* __restrict__ Wsrc, bf16* __restrict__ Wt) {
    int idx = blockIdx.x * 256 + threadIdx.x;   // ((layer*512)+n)*256+k
    int k = idx & 255;
    int n = (idx >> 8) & 511;
    int layer = idx >> 17;
    Wt[idx] = __float2bfloat16(Wsrc[((size_t)(layer * 256 + k)) * 512 + n]);
}

// ---------------- scan phase A: chunk-end states, 16 modes/thread (mode-split x2) ----------------
// grid (NCH, B, 8): z = hgroup*2 + modehalf; block = 64 (one wave)
__global__ __launch_bounds__(64) void k_scanA(const float* __restrict__ U,
                                              const float4* __restrict__ PWt,
                                              float2* __restrict__ E) {
    int c = blockIdx.x, b = blockIdx.y;
    int mh = blockIdx.z & 1, hg = blockIdx.z >> 1;
    int h = hg * 64 + threadIdx.x;
    int m0 = mh * 16;
    const float* Ub = U + ((size_t)b * LSEQ + c * CH) * HDIM + h;
    f32x2 ar[8], ai[8], wr[8], wi[8], sr[8], si[8];
#pragma unroll
    for (int p = 0; p < 8; ++p) {
        float4 q0 = PWt[(m0 + 2 * p) * HDIM + h];
        float4 q1 = PWt[(m0 + 2 * p + 1) * HDIM + h];
        ar[p] = (f32x2){q0.x, q1.x}; ai[p] = (f32x2){q0.y, q1.y};
        wr[p] = (f32x2){q0.z, q1.z}; wi[p] = (f32x2){q0.w, q1.w};
        sr[p] = (f32x2){0.f, 0.f};   si[p] = (f32x2){0.f, 0.f};
    }
    for (int j = 0; j < CH; j += 4) {
        float u0 = Ub[(j + 0) * HDIM], u1 = Ub[(j + 1) * HDIM];
        float u2 = Ub[(j + 2) * HDIM], u3 = Ub[(j + 3) * HDIM];
#define ASTEP(UU)                                                          \
        {                                                                  \
            f32x2 uv = (f32x2){(UU), (UU)};                                \
            _Pragma("unroll")                                              \
            for (int p = 0; p < 8; ++p) {                                  \
                f32x2 nr = pk_fma(ar[p], sr[p], pk_fma(-ai[p], si[p], wr[p] * uv)); \
                si[p]    = pk_fma(ar[p], si[p], pk_fma( ai[p], sr[p], wi[p] * uv)); \
                sr[p] = nr;                                                \
            }                                                              \
        }
        ASTEP(u0) ASTEP(u1) ASTEP(u2) ASTEP(u3)
#undef ASTEP
    }
    size_t base = (size_t)(b * NCH + c) * NSTATE + m0;
#pragma unroll
    for (int p = 0; p < 8; ++p) {
        E[(base + 2 * p    ) * HDIM + h] = make_float2(sr[p].x, si[p].x);
        E[(base + 2 * p + 1) * HDIM + h] = make_float2(sr[p].y, si[p].y);
    }
}

// ---------------- scan phase B: carry scan over chunks (in place) ----------------
__global__ void k_scanB(float2* __restrict__ E, const float2* __restrict__ PA64) {
    int n = blockIdx.x, b = blockIdx.y, h = threadIdx.x;
    float2 a = PA64[n * HDIM + h];
    float cr = 0.f, ci = 0.f;
    for (int c = 0; c < NCH; ++c) {
        size_t off = ((size_t)(b * NCH + c) * NSTATE + n) * HDIM + h;
        float2 e = E[off];
        E[off] = make_float2(cr, ci);
        float nr = fmaf(a.x, cr, fmaf(-a.y, ci, e.x));
        ci = fmaf(a.x, ci, fmaf(a.y, cr, e.y));
        cr = nr;
    }
}

// ---------------- scan phase C: seeded re-scan, mode-split x2, fp16 LDS partials ----------------
// grid (NCH, B, 4): z = hgroup; block = 128 (2 waves: wave = mode-half, lanes = 64 h)
__global__ __launch_bounds__(128) void k_scanC(const float* __restrict__ U,
                                               const float4* __restrict__ PWt,
                                               const float2* __restrict__ E,
                                               const float* __restrict__ Dw,
                                               bf16* __restrict__ Yout) {
    __shared__ _Float16 y_s[2][CH][64];
    int c = blockIdx.x, b = blockIdx.y, hg = blockIdx.z;
    int tid = threadIdx.x;
    int w = tid >> 6, lane = tid & 63;
    int h = hg * 64 + lane;
    int m0 = w * 16;
    const float* Ub = U + ((size_t)b * LSEQ + c * CH) * HDIM + h;
    float halfD = (w == 0) ? 0.5f * Dw[h] : 0.0f;
    f32x2 ar[8], ai[8], wr[8], wi[8], sr[8], si[8];
    size_t ebase = (size_t)(b * NCH + c) * NSTATE + m0;
#pragma unroll
    for (int p = 0; p < 8; ++p) {
        float4 q0 = PWt[(m0 + 2 * p) * HDIM + h];
        float4 q1 = PWt[(m0 + 2 * p + 1) * HDIM + h];
        ar[p] = (f32x2){q0.x, q1.x}; ai[p] = (f32x2){q0.y, q1.y};
        wr[p] = (f32x2){q0.z, q1.z}; wi[p] = (f32x2){q0.w, q1.w};
        float2 e0 = E[(ebase + 2 * p    ) * HDIM + h];
        float2 e1 = E[(ebase + 2 * p + 1) * HDIM + h];
        sr[p] = (f32x2){e0.x, e1.x}; si[p] = (f32x2){e0.y, e1.y};
    }
#pragma unroll 4
    for (int j = 0; j < CH; ++j) {
        float u = Ub[j * HDIM];
        f32x2 uv = (f32x2){u, u};
        f32x2 sacc = (f32x2){0.f, 0.f};
#pragma unroll
        for (int p = 0; p < 8; ++p) {
            f32x2 nr = pk_fma(ar[p], sr[p], pk_fma(-ai[p], si[p], wr[p] * uv));
            si[p]    = pk_fma(ar[p], si[p], pk_fma( ai[p], sr[p], wi[p] * uv));
            sr[p] = nr; sacc += nr;
        }
        y_s[w][j][lane] = (_Float16)(fmaf(halfD, u, sacc.x + sacc.y));
    }
    __syncthreads();
    for (int idx = tid; idx < CH * 64; idx += 128) {
        int j = idx >> 6, hh = idx & 63;
        float v = 2.0f * ((float)y_s[0][j][hh] + (float)y_s[1][j][hh]);
        float z2 = 1.5957691216057308f * (v + 0.044715f * v * v * v);
        float g = v / (1.0f + __expf(-z2));        // gelu(v) = v*sigmoid(2z)
        Yout[((size_t)b * LSEQ + c * CH + j) * HDIM + hg * 64 + hh] = __float2bfloat16(g);
    }
}

// ---------------- encoder GEMM: H0[M,256] = X[M,128]@W + b (fp32 vector) ----------------
__global__ __launch_bounds__(256) void k_enc(const float* __restrict__ X, const float* __restrict__ W,
                                             const float* __restrict__ bias, float* __restrict__ out) {
    __shared__ float As[128][33];
    __shared__ float Bs[32][128];
    int m0 = blockIdx.x * 128, n0 = blockIdx.y * 128;
    int tid = threadIdx.x;
    int tx = tid & 15, ty = tid >> 4;
    float acc[8][8] = {};
    for (int kt = 0; kt < DIN; kt += 32) {
#pragma unroll
        for (int i = 0; i < 16; ++i) {
            int e = tid + i * 256, kk = e & 31, mm = e >> 5;
            As[mm][kk] = X[(m0 + mm) * DIN + kt + kk];
        }
#pragma unroll
        for (int i = 0; i < 16; ++i) {
            int e = tid + i * 256, nn = e & 127, kk = e >> 7;
            Bs[kk][nn] = W[(kt + kk) * HDIM + n0 + nn];
        }
        __syncthreads();
#pragma unroll
        for (int kk = 0; kk < 32; ++kk) {
            float a[8], b[8];
#pragma unroll
            for (int i = 0; i < 8; ++i) a[i] = As[ty * 8 + i][kk];
#pragma unroll
            for (int j = 0; j < 8; ++j) b[j] = Bs[kk][tx * 8 + j];
#pragma unroll
            for (int i = 0; i < 8; ++i)
#pragma unroll
                for (int j = 0; j < 8; ++j) acc[i][j] = fmaf(a[i], b[j], acc[i][j]);
        }
        __syncthreads();
    }
#pragma unroll
    for (int i = 0; i < 8; ++i) {
        int m = m0 + ty * 8 + i;
#pragma unroll
        for (int j = 0; j < 8; ++j) {
            int n = n0 + tx * 8 + j;
            out[m * HDIM + n] = acc[i][j] + bias[n];
        }
    }
}

// ---------------- output GEMM + fused GLU, bf16 MFMA ----------------
__global__ __launch_bounds__(256) void k_glu(const bf16* __restrict__ Ybf,
                                             const bf16* __restrict__ Wt,
                                             const float* __restrict__ wb,
                                             float* __restrict__ G) {
    __shared__ short A_s[128 * 72];
    __shared__ short B1_s[64 * 72];
    __shared__ short B2_s[64 * 72];
    int tid = threadIdx.x;
    int lane = tid & 63, wv = tid >> 6;
    int quad = lane >> 4, fr = lane & 15;
    int m0 = blockIdx.x * 128, n0 = blockIdx.y * 64;
    f32x4 acc1[2][4], acc2[2][4];
#pragma unroll
    for (int mt = 0; mt < 2; ++mt)
#pragma unroll
        for (int nt = 0; nt < 4; ++nt) {
            acc1[mt][nt] = (f32x4){0.f,0.f,0.f,0.f};
            acc2[mt][nt] = (f32x4){0.f,0.f,0.f,0.f};
        }
    for (int kt = 0; kt < HDIM; kt += 64) {
#pragma unroll
        for (int i = 0; i < 4; ++i) {            // A tile: 128 rows x 64 k
            int e = tid + i * 256, row = e >> 3, cm = e & 7;
            *(uint4*)&A_s[row * 72 + cm * 8] =
                *(const uint4*)(Ybf + (size_t)(m0 + row) * HDIM + kt + cm * 8);
        }
#pragma unroll
        for (int i = 0; i < 2; ++i) {            // B tiles: 64 n-rows x 64 k each
            int e = tid + i * 256, row = e >> 3, cm = e & 7;
            *(uint4*)&B1_s[row * 72 + cm * 8] =
                *(const uint4*)(Wt + (size_t)(n0 + row) * HDIM + kt + cm * 8);
            *(uint4*)&B2_s[row * 72 + cm * 8] =
                *(const uint4*)(Wt + (size_t)(256 + n0 + row) * HDIM + kt + cm * 8);
        }
        __syncthreads();
#pragma unroll
        for (int s = 0; s < 2; ++s) {            // two K=32 MFMA steps per stage
            bf16x8 a[2], b1[4], b2[4];
#pragma unroll
            for (int mt = 0; mt < 2; ++mt)
                a[mt] = *(const bf16x8*)&A_s[(wv * 32 + mt * 16 + fr) * 72 + s * 32 + quad * 8];
#pragma unroll
            for (int nt = 0; nt < 4; ++nt) {
                b1[nt] = *(const bf16x8*)&B1_s[(nt * 16 + fr) * 72 + s * 32 + quad * 8];
                b2[nt] = *(const bf16x8*)&B2_s[(nt * 16 + fr) * 72 + s * 32 + quad * 8];
            }
#pragma unroll
            for (int mt = 0; mt < 2; ++mt)
#pragma unroll
                for (int nt = 0; nt < 4; ++nt) {
                    acc1[mt][nt] = __builtin_amdgcn_mfma_f32_16x16x32_bf16(a[mt], b1[nt], acc1[mt][nt], 0, 0, 0);
                    acc2[mt][nt] = __builtin_amdgcn_mfma_f32_16x16x32_bf16(a[mt], b2[nt], acc2[mt][nt], 0, 0, 0);
                }
        }
        __syncthreads();
    }
#pragma unroll
    for (int mt = 0; mt < 2; ++mt)
#pragma unroll
        for (int nt = 0; nt < 4; ++nt) {
            int n = n0 + nt * 16 + fr;
            float b1v = wb[n], b2v = wb[HDIM + n];
#pragma unroll
            for (int r = 0; r < 4; ++r) {
                int m = m0 + wv * 32 + mt * 16 + quad * 4 + r;
                float z1 = acc1[mt][nt][r] + b1v;
                float z2 = acc2[mt][nt][r] + b2v;
                G[(size_t)m * HDIM + n] = z1 / (1.0f + __expf(-z2));
            }
        }
}

// ---------------- residual + LayerNorm (in place on H) ----------------
__global__ void k_ln(const float* __restrict__ G, float* __restrict__ Hb,
                     const float* __restrict__ w, const float* __restrict__ bb) {
    int row = blockIdx.x, hh = threadIdx.x;
    float r = G[row * HDIM + hh] + Hb[row * HDIM + hh];
    float s = r;
#pragma unroll
    for (int m = 1; m < 64; m <<= 1) s += __shfl_xor(s, m, 64);
    __shared__ float red[8];
    int wv = hh >> 6, lane = hh & 63;
    if (lane == 0) red[wv] = s;
    __syncthreads();
    float mean = (red[0] + red[1] + red[2] + red[3]) * (1.0f / HDIM);
    float d = r - mean;
    float s2 = d * d;
#pragma unroll
    for (int m = 1; m < 64; m <<= 1) s2 += __shfl_xor(s2, m, 64);
    if (lane == 0) red[4 + wv] = s2;
    __syncthreads();
    float var = (red[4] + red[5] + red[6] + red[7]) * (1.0f / HDIM);
    float rstd = rsqrtf(var + 1e-5f);
    Hb[row * HDIM + hh] = d * rstd * w[hh] + bb[hh];
}

// ---------------- decoder ----------------
__global__ void k_dec(const float* __restrict__ Hb, const float* __restrict__ dw,
                      const float* __restrict__ db, float* __restrict__ out) {
    __shared__ float ws[HDIM * DOUT];
    int tid = threadIdx.x;                    // 320 threads
    for (int e = tid; e < HDIM * DOUT; e += 320) ws[e] = dw[e];
    __syncthreads();
    int r = tid / DOUT, o = tid - r * DOUT;
    int row = blockIdx.x * 32 + r;
    float acc = db[o];
    const float* hp = Hb + row * HDIM;
#pragma unroll 8
    for (int k = 0; k < HDIM; ++k) acc = fmaf(hp[k], ws[k * DOUT + o], acc);
    out[row * DOUT + o] = acc;
}

extern "C" void kernel_launch(void* const* d_in, const int* in_sizes, int n_in,
                              void* d_out, int out_size, void* d_ws, size_t ws_size,
                              hipStream_t stream) {
    const float* x        = (const float*)d_in[0];
    const float* enc_w    = (const float*)d_in[1];
    const float* enc_b    = (const float*)d_in[2];
    const float* log_dt   = (const float*)d_in[3];
    const float* A_re_log = (const float*)d_in[4];
    const float* A_im     = (const float*)d_in[5];
    const float* B_re     = (const float*)d_in[6];
    const float* B_im     = (const float*)d_in[7];
    const float* C_re     = (const float*)d_in[8];
    const float* C_im     = (const float*)d_in[9];
    const float* Dp       = (const float*)d_in[10];
    const float* ln_w     = (const float*)d_in[11];
    const float* ln_b     = (const float*)d_in[12];
    const float* out_w    = (const float*)d_in[13];
    const float* out_b    = (const float*)d_in[14];
    const float* dec_w    = (const float*)d_in[15];
    const float* dec_b    = (const float*)d_in[16];
    float* outp = (float*)d_out;

    float* w = (float*)d_ws;
    const size_t PWE = (size_t)NLAYERS * NSTATE * HDIM;         // 32768
    float4* PWt  = (float4*)w;                                  // 512 KB
    float2* PA64 = (float2*)(w + 4 * PWE);                      // 256 KB
    float* Hbuf = w + 6 * PWE;                                  // 33.5 MB
    float* Gbuf = Hbuf + (size_t)M_ROWS * HDIM;                 // 33.5 MB, aliased with E
    float2* Ebuf = (float2*)Gbuf;                               // dead when G live
    bf16* Ybf = (bf16*)(Gbuf + (size_t)M_ROWS * HDIM);          // 16.7 MB
    bf16* Wt  = Ybf + (size_t)M_ROWS * HDIM;                    // 1 MB

    k_params<<<NLAYERS * HDIM * NSTATE / 256, 256, 0, stream>>>(log_dt, A_re_log, A_im,
                                                                B_re, B_im, C_re, C_im, PWt, PA64);
    k_wcvt<<<NLAYERS * 512 * 256 / 256, 256, 0, stream>>>(out_w, Wt);

    dim3 ge(M_ROWS / 128, HDIM / 128);
    k_enc<<<ge, 256, 0, stream>>>(x, enc_w, enc_b, Hbuf);

    for (int layer = 0; layer < NLAYERS; ++layer) {
        const float4* pwl = (const float4*)PWt + (size_t)layer * NSTATE * HDIM;
        const float2* pal = (const float2*)PA64 + (size_t)layer * NSTATE * HDIM;
        dim3 gsa(NCH, B_SZ, 8);
        k_scanA<<<gsa, 64, 0, stream>>>(Hbuf, pwl, Ebuf);
        dim3 gb(NSTATE, B_SZ);
        k_scanB<<<gb, 256, 0, stream>>>(Ebuf, pal);
        dim3 gsc(NCH, B_SZ, 4);
        k_scanC<<<gsc, 128, 0, stream>>>(Hbuf, pwl, Ebuf, Dp + layer * HDIM, Ybf);
        dim3 gg(M_ROWS / 128, HDIM / 64);
        k_glu<<<gg, 256, 0, stream>>>(Ybf, Wt + (size_t)layer * 512 * HDIM,
                                      out_b + layer * 2 * HDIM, Gbuf);
        k_ln<<<M_ROWS, HDIM, 0, stream>>>(Gbuf, Hbuf, ln_w + layer * HDIM, ln_b + layer * HDIM);
    }
    k_dec<<<M_ROWS / 32, 320, 0, stream>>>(Hbuf, dec_w, dec_b, outp);
}

// Round 10
// 639.852 us; speedup vs baseline: 4.5212x; 1.2035x over previous
//
#include <hip/hip_runtime.h>
#include <hip/hip_bf16.h>
#include <math.h>

#define B_SZ    32
#define LSEQ    1024
#define DIN     128
#define HDIM    256
#define NLAYERS 4
#define NSTATE  32
#define DOUT    10
#define M_ROWS  (B_SZ*LSEQ)   // 32768
#define CH      64            // scan chunk length
#define NCH     (LSEQ/CH)     // 16 chunks
#define NBC     (B_SZ*NCH)    // 512 chunk-columns

typedef __hip_bfloat16 bf16;
typedef __attribute__((ext_vector_type(8))) short bf16x8;
typedef __attribute__((ext_vector_type(4))) float f32x4;

// ---------------- per-(layer,h,n) discretized params ----------------
__global__ void k_params(const float* __restrict__ log_dt, const float* __restrict__ A_re_log,
                         const float* __restrict__ A_im, const float* __restrict__ B_re,
                         const float* __restrict__ B_im, const float* __restrict__ C_re,
                         const float* __restrict__ C_im, float4* __restrict__ PWt,
                         float2* __restrict__ PA64) {
    int idx = blockIdx.x * 256 + threadIdx.x;       // layer*H*N + h*N + n
    int n = idx & 31, hn = idx >> 5;
    int h = hn & 255, layer = hn >> 8;
    float dt   = expf(log_dt[hn]);
    float Are  = -expf(A_re_log[idx]);
    float Aim  = A_im[idx];
    float dtAre = dt * Are, dtAim = dt * Aim;
    float ea   = expf(dtAre);
    float dAre = ea * cosf(dtAim), dAim = ea * sinf(dtAim);
    float nre = dAre - 1.0f, nim = dAim;            // dA - 1
    float inv = 1.0f / (Are * Are + Aim * Aim);
    float tre = (nre * Are + nim * Aim) * inv;      // (dA-1)/A
    float tim = (nim * Are - nre * Aim) * inv;
    float Brv = B_re[idx], Biv = B_im[idx];
    float dBre = Brv * tre - Biv * tim;
    float dBim = Brv * tim + Biv * tre;
    float Crv = C_re[idx], Civ = C_im[idx];
    float Wre = Crv * dBre - Civ * dBim;
    float Wim = Crv * dBim + Civ * dBre;
    int o = (layer * NSTATE + n) * HDIM + h;        // [layer][n][h]
    PWt[o] = make_float4(dAre, dAim, Wre, Wim);
    float e64 = expf(64.0f * dtAre);
    float ph  = 64.0f * dtAim;
    PA64[o] = make_float2(e64 * cosf(ph), e64 * sinf(ph));
}

// ---------------- Toeplitz kernel values: Td[lh][d] = 2 Re sum_n W dA^d, d=0..64 ----------------
__global__ void k_td(const float4* __restrict__ PWt, float* __restrict__ Td) {
    int lh = blockIdx.x * 256 + threadIdx.x;        // layer*256 + h
    int layer = lh >> 8, h = lh & 255;
    const float4* P = PWt + (size_t)layer * NSTATE * HDIM;
    float acc[65];
#pragma unroll
    for (int d = 0; d < 65; ++d) acc[d] = 0.f;
    for (int n = 0; n < NSTATE; ++n) {
        float4 q = P[n * HDIM + h];
        float zr = q.z, zi = q.w;                   // W * dA^0
#pragma unroll
        for (int d = 0; d < 65; ++d) {
            acc[d] += zr;
            float nzr = zr * q.x - zi * q.y;
            zi = zr * q.y + zi * q.x;
            zr = nzr;
        }
    }
    for (int d = 0; d < 65; ++d) Td[(size_t)lh * 66 + d] = 2.f * acc[d];
}

// ---------------- one-off weight transpose+cast: Wt[layer][n(512)][k(256)] bf16 ----------------
__global__ void k_wcvt(const float* __restrict__ Wsrc, bf16* __restrict__ Wt) {
    int idx = blockIdx.x * 256 + threadIdx.x;   // ((layer*512)+n)*256+k
    int k = idx & 255;
    int n = (idx >> 8) & 511;
    int layer = idx >> 17;
    Wt[idx] = __float2bfloat16(Wsrc[((size_t)(layer * 256 + k)) * 512 + n]);
}

// ---------------- transpose Hbuf fp32 [m][h] -> Ut bf16 [h][m] ----------------
__global__ __launch_bounds__(256) void k_tr(const float* __restrict__ H, bf16* __restrict__ Ut) {
    __shared__ bf16 t_s[64][72];
    int m0 = blockIdx.x * 64, h0 = blockIdx.y * 64;
    int tid = threadIdx.x;
#pragma unroll
    for (int i = 0; i < 4; ++i) {                  // 1024 float4 reads (64m x 64h)
        int q = tid + i * 256, row = q >> 4, seg = q & 15;
        float4 v = *(const float4*)&H[(size_t)(m0 + row) * HDIM + h0 + seg * 4];
        t_s[seg * 4 + 0][row] = __float2bfloat16(v.x);
        t_s[seg * 4 + 1][row] = __float2bfloat16(v.y);
        t_s[seg * 4 + 2][row] = __float2bfloat16(v.z);
        t_s[seg * 4 + 3][row] = __float2bfloat16(v.w);
    }
    __syncthreads();
#pragma unroll
    for (int i = 0; i < 2; ++i) {                  // 512 uint4 writes (64h rows x 64m)
        int q = tid + i * 256, row = q >> 3, seg = q & 7;
        *(uint4*)&Ut[(size_t)(h0 + row) * M_ROWS + m0 + seg * 8] = *(uint4*)&t_s[row][seg * 8];
    }
}

// ---------------- transpose Yt bf16 [h][m] -> Y bf16 [m][h] ----------------
__global__ __launch_bounds__(256) void k_trY(const bf16* __restrict__ Yt, bf16* __restrict__ Y) {
    __shared__ bf16 t_s[64][72];
    int m0 = blockIdx.x * 64, h0 = blockIdx.y * 64;
    int tid = threadIdx.x;
#pragma unroll
    for (int i = 0; i < 2; ++i) {                  // read 64h rows x 64m
        int q = tid + i * 256, row = q >> 3, seg = q & 7;
        uint4 v = *(const uint4*)&Yt[(size_t)(h0 + row) * M_ROWS + m0 + seg * 8];
        const bf16* pv = (const bf16*)&v;
#pragma unroll
        for (int e = 0; e < 8; ++e) t_s[seg * 8 + e][row] = pv[e];   // t_s[m][h]
    }
    __syncthreads();
#pragma unroll
    for (int i = 0; i < 2; ++i) {                  // write 64m rows x 64h
        int q = tid + i * 256, row = q >> 3, seg = q & 7;
        *(uint4*)&Y[(size_t)(m0 + row) * HDIM + h0 + seg * 8] = *(uint4*)&t_s[row][seg * 8];
    }
}

// ---------------- conv phase A (MFMA): E[h][comp][bc] = V_h @ u ----------------
// grid (HDIM, NBC/128), block 256 (4 waves)
__global__ __launch_bounds__(256) void k_convA(const bf16* __restrict__ Ut,
                                               const float4* __restrict__ PW,
                                               float* __restrict__ E) {
    __shared__ bf16 V_s[64 * 72];
    __shared__ bf16 u_s[128 * 72];
    __shared__ float o_s[64 * 132];
    int h = blockIdx.x, bc0 = blockIdx.y * 128;
    int tid = threadIdx.x;
    int lane = tid & 63, wv = tid >> 6, quad = lane >> 4, fr = lane & 15;
    if (tid < 64) {                                // V[comp][j] = Re/Im(W dA^(63-j))
        int n = tid >> 1, isIm = tid & 1;
        float4 q = PW[n * HDIM + h];
        float zr = q.z, zi = q.w;                  // W
        for (int jj = 0; jj < 64; ++jj) {
            int j = 63 - jj;
            V_s[tid * 72 + j] = __float2bfloat16(isIm ? zi : zr);
            float nzr = zr * q.x - zi * q.y;
            zi = zr * q.y + zi * q.x;
            zr = nzr;
        }
    }
#pragma unroll
    for (int i = 0; i < 4; ++i) {                  // stage u tile [bc][j]
        int q = tid + i * 256, row = q >> 3, c8 = q & 7;
        *(uint4*)&u_s[row * 72 + c8 * 8] =
            *(const uint4*)&Ut[(size_t)h * M_ROWS + (size_t)(bc0 + row) * 64 + c8 * 8];
    }
    __syncthreads();
    f32x4 acc[4][2];
#pragma unroll
    for (int mt = 0; mt < 4; ++mt)
#pragma unroll
        for (int nf = 0; nf < 2; ++nf) acc[mt][nf] = (f32x4){0.f, 0.f, 0.f, 0.f};
#pragma unroll
    for (int ks = 0; ks < 2; ++ks) {
        bf16x8 a[4], b[2];
#pragma unroll
        for (int mt = 0; mt < 4; ++mt)
            a[mt] = *(const bf16x8*)&V_s[(mt * 16 + fr) * 72 + ks * 32 + quad * 8];
#pragma unroll
        for (int nf = 0; nf < 2; ++nf)
            b[nf] = *(const bf16x8*)&u_s[(wv * 32 + nf * 16 + fr) * 72 + ks * 32 + quad * 8];
#pragma unroll
        for (int mt = 0; mt < 4; ++mt)
#pragma unroll
            for (int nf = 0; nf < 2; ++nf)
                acc[mt][nf] = __builtin_amdgcn_mfma_f32_16x16x32_bf16(a[mt], b[nf], acc[mt][nf], 0, 0, 0);
    }
#pragma unroll
    for (int mt = 0; mt < 4; ++mt)
#pragma unroll
        for (int nf = 0; nf < 2; ++nf)
#pragma unroll
            for (int r = 0; r < 4; ++r)
                o_s[(mt * 16 + quad * 4 + r) * 132 + wv * 32 + nf * 16 + fr] = acc[mt][nf][r];
    __syncthreads();
#pragma unroll
    for (int i = 0; i < 32; ++i) {                 // coalesced E store
        int q = tid + i * 256, comp = q >> 7, bcl = q & 127;
        E[((size_t)h * 64 + comp) * NBC + bc0 + bcl] = o_s[comp * 132 + bcl];
    }
}

// ---------------- carry scan over chunks: E -> Carry[h][bc][2n(re),2n+1(im)] bf16 ----------------
__global__ void k_scanB2(const float* __restrict__ E, const float2* __restrict__ PA,
                         bf16* __restrict__ Carry) {
    int h = blockIdx.x;
    int b = blockIdx.y * 8 + (threadIdx.x >> 5);
    int n = threadIdx.x & 31;
    float2 a = PA[n * HDIM + h];
    const float* Er = E + ((size_t)h * 64 + 2 * n) * NBC;
    const float* Ei = Er + NBC;
    bf16* C = Carry + (size_t)h * NBC * 64;
    float cr = 0.f, ci = 0.f;
    for (int c = 0; c < NCH; ++c) {
        int bc = b * NCH + c;
        C[(size_t)bc * 64 + 2 * n]     = __float2bfloat16(cr);
        C[(size_t)bc * 64 + 2 * n + 1] = __float2bfloat16(ci);
        float er = Er[bc], ei = Ei[bc];
        float nr = fmaf(a.x, cr, fmaf(-a.y, ci, er));
        ci = fmaf(a.x, ci, fmaf(a.y, cr, ei));
        cr = nr;
    }
}

// ---------------- conv phase C (MFMA): Yt[h][bc*64+l] = gelu([T|M]@[u;carry] + D*u) ----------------
// grid (HDIM, NBC/128), block 256
__global__ __launch_bounds__(256) void k_convC(const bf16* __restrict__ Ut,
                                               const bf16* __restrict__ Carry,
                                               const float* __restrict__ Tdl,
                                               const float4* __restrict__ PW,
                                               const float* __restrict__ Dw,
                                               bf16* __restrict__ Yt) {
    __shared__ bf16 A_s[64 * 136];                 // [l][k2], k2<64: T, k2>=64: M
    __shared__ bf16 u_s[128 * 72];
    __shared__ bf16 c_s[128 * 72];
    __shared__ bf16 o_s[128 * 72];
    __shared__ float Td_s[65];
    int h = blockIdx.x, bc0 = blockIdx.y * 128;
    int tid = threadIdx.x;
    int lane = tid & 63, wv = tid >> 6, quad = lane >> 4, fr = lane & 15;
    if (tid < 65) Td_s[tid] = Tdl[(size_t)h * 66 + tid];
    if (tid < 64) {                                // M[l][2n]=2Re(dA^{l+1}); [2n+1]=-2Im
        int n = tid >> 1, isIm = tid & 1;
        float4 q = PW[n * HDIM + h];
        float zr = q.x, zi = q.y;                  // dA^1
        for (int l = 0; l < 64; ++l) {
            A_s[l * 136 + 64 + tid] = __float2bfloat16(isIm ? -2.f * zi : 2.f * zr);
            float nzr = zr * q.x - zi * q.y;
            zi = zr * q.y + zi * q.x;
            zr = nzr;
        }
    }
    __syncthreads();                               // Td_s ready
#pragma unroll
    for (int i = 0; i < 16; ++i) {                 // Toeplitz T fill
        int q = tid + i * 256, l = q >> 6, j = q & 63, d = l - j;
        A_s[l * 136 + j] = __float2bfloat16(d >= 0 ? Td_s[d] : 0.f);
    }
#pragma unroll
    for (int i = 0; i < 4; ++i) {                  // stage u, carry tiles
        int q = tid + i * 256, row = q >> 3, c8 = q & 7;
        *(uint4*)&u_s[row * 72 + c8 * 8] =
            *(const uint4*)&Ut[(size_t)h * M_ROWS + (size_t)(bc0 + row) * 64 + c8 * 8];
        *(uint4*)&c_s[row * 72 + c8 * 8] =
            *(const uint4*)&Carry[((size_t)h * NBC + bc0 + row) * 64 + c8 * 8];
    }
    __syncthreads();
    f32x4 acc[4][2];
#pragma unroll
    for (int mt = 0; mt < 4; ++mt)
#pragma unroll
        for (int nf = 0; nf < 2; ++nf) acc[mt][nf] = (f32x4){0.f, 0.f, 0.f, 0.f};
#pragma unroll
    for (int ks = 0; ks < 4; ++ks) {
        bf16x8 a[4], b[2];
#pragma unroll
        for (int mt = 0; mt < 4; ++mt)
            a[mt] = *(const bf16x8*)&A_s[(mt * 16 + fr) * 136 + ks * 32 + quad * 8];
#pragma unroll
        for (int nf = 0; nf < 2; ++nf) {
            int row = (wv * 32 + nf * 16 + fr) * 72;
            b[nf] = (ks < 2) ? *(const bf16x8*)&u_s[row + ks * 32 + quad * 8]
                             : *(const bf16x8*)&c_s[row + (ks - 2) * 32 + quad * 8];
        }
#pragma unroll
        for (int mt = 0; mt < 4; ++mt)
#pragma unroll
            for (int nf = 0; nf < 2; ++nf)
                acc[mt][nf] = __builtin_amdgcn_mfma_f32_16x16x32_bf16(a[mt], b[nf], acc[mt][nf], 0, 0, 0);
    }
    float Dv = Dw[h];
#pragma unroll
    for (int mt = 0; mt < 4; ++mt)
#pragma unroll
        for (int nf = 0; nf < 2; ++nf) {
            int bcl = wv * 32 + nf * 16 + fr;
#pragma unroll
            for (int r = 0; r < 4; ++r) {
                int l = mt * 16 + quad * 4 + r;
                float u = __bfloat162float(u_s[bcl * 72 + l]);
                float v = fmaf(Dv, u, acc[mt][nf][r]);
                float z2 = 1.5957691216057308f * (v + 0.044715f * v * v * v);
                o_s[bcl * 72 + l] = __float2bfloat16(v / (1.f + __expf(-z2)));
            }
        }
    __syncthreads();
#pragma unroll
    for (int i = 0; i < 4; ++i) {                  // coalesced Yt store
        int q = tid + i * 256, row = q >> 3, c8 = q & 7;
        *(uint4*)&Yt[(size_t)h * M_ROWS + (size_t)(bc0 + row) * 64 + c8 * 8] =
            *(uint4*)&o_s[row * 72 + c8 * 8];
    }
}

// ---------------- encoder GEMM: H0[M,256] = X[M,128]@W + b (fp32 vector) ----------------
__global__ __launch_bounds__(256) void k_enc(const float* __restrict__ X, const float* __restrict__ W,
                                             const float* __restrict__ bias, float* __restrict__ out) {
    __shared__ float As[128][33];
    __shared__ float Bs[32][128];
    int m0 = blockIdx.x * 128, n0 = blockIdx.y * 128;
    int tid = threadIdx.x;
    int tx = tid & 15, ty = tid >> 4;
    float acc[8][8] = {};
    for (int kt = 0; kt < DIN; kt += 32) {
#pragma unroll
        for (int i = 0; i < 16; ++i) {
            int e = tid + i * 256, kk = e & 31, mm = e >> 5;
            As[mm][kk] = X[(m0 + mm) * DIN + kt + kk];
        }
#pragma unroll
        for (int i = 0; i < 16; ++i) {
            int e = tid + i * 256, nn = e & 127, kk = e >> 7;
            Bs[kk][nn] = W[(kt + kk) * HDIM + n0 + nn];
        }
        __syncthreads();
#pragma unroll
        for (int kk = 0; kk < 32; ++kk) {
            float a[8], b[8];
#pragma unroll
            for (int i = 0; i < 8; ++i) a[i] = As[ty * 8 + i][kk];
#pragma unroll
            for (int j = 0; j < 8; ++j) b[j] = Bs[kk][tx * 8 + j];
#pragma unroll
            for (int i = 0; i < 8; ++i)
#pragma unroll
                for (int j = 0; j < 8; ++j) acc[i][j] = fmaf(a[i], b[j], acc[i][j]);
        }
        __syncthreads();
    }
#pragma unroll
    for (int i = 0; i < 8; ++i) {
        int m = m0 + ty * 8 + i;
#pragma unroll
        for (int j = 0; j < 8; ++j) {
            int n = n0 + tx * 8 + j;
            out[m * HDIM + n] = acc[i][j] + bias[n];
        }
    }
}

// ---------------- output GEMM + fused GLU, bf16 MFMA ----------------
__global__ __launch_bounds__(256) void k_glu(const bf16* __restrict__ Ybf,
                                             const bf16* __restrict__ Wt,
                                             const float* __restrict__ wb,
                                             float* __restrict__ G) {
    __shared__ short A_s[128 * 72];
    __shared__ short B1_s[64 * 72];
    __shared__ short B2_s[64 * 72];
    int tid = threadIdx.x;
    int lane = tid & 63, wv = tid >> 6;
    int quad = lane >> 4, fr = lane & 15;
    int m0 = blockIdx.x * 128, n0 = blockIdx.y * 64;
    f32x4 acc1[2][4], acc2[2][4];
#pragma unroll
    for (int mt = 0; mt < 2; ++mt)
#pragma unroll
        for (int nt = 0; nt < 4; ++nt) {
            acc1[mt][nt] = (f32x4){0.f,0.f,0.f,0.f};
            acc2[mt][nt] = (f32x4){0.f,0.f,0.f,0.f};
        }
    for (int kt = 0; kt < HDIM; kt += 64) {
#pragma unroll
        for (int i = 0; i < 4; ++i) {
            int e = tid + i * 256, row = e >> 3, cm = e & 7;
            *(uint4*)&A_s[row * 72 + cm * 8] =
                *(const uint4*)(Ybf + (size_t)(m0 + row) * HDIM + kt + cm * 8);
        }
#pragma unroll
        for (int i = 0; i < 2; ++i) {
            int e = tid + i * 256, row = e >> 3, cm = e & 7;
            *(uint4*)&B1_s[row * 72 + cm * 8] =
                *(const uint4*)(Wt + (size_t)(n0 + row) * HDIM + kt + cm * 8);
            *(uint4*)&B2_s[row * 72 + cm * 8] =
                *(const uint4*)(Wt + (size_t)(256 + n0 + row) * HDIM + kt + cm * 8);
        }
        __syncthreads();
#pragma unroll
        for (int s = 0; s < 2; ++s) {
            bf16x8 a[2], b1[4], b2[4];
#pragma unroll
            for (int mt = 0; mt < 2; ++mt)
                a[mt] = *(const bf16x8*)&A_s[(wv * 32 + mt * 16 + fr) * 72 + s * 32 + quad * 8];
#pragma unroll
            for (int nt = 0; nt < 4; ++nt) {
                b1[nt] = *(const bf16x8*)&B1_s[(nt * 16 + fr) * 72 + s * 32 + quad * 8];
                b2[nt] = *(const bf16x8*)&B2_s[(nt * 16 + fr) * 72 + s * 32 + quad * 8];
            }
#pragma unroll
            for (int mt = 0; mt < 2; ++mt)
#pragma unroll
                for (int nt = 0; nt < 4; ++nt) {
                    acc1[mt][nt] = __builtin_amdgcn_mfma_f32_16x16x32_bf16(a[mt], b1[nt], acc1[mt][nt], 0, 0, 0);
                    acc2[mt][nt] = __builtin_amdgcn_mfma_f32_16x16x32_bf16(a[mt], b2[nt], acc2[mt][nt], 0, 0, 0);
                }
        }
        __syncthreads();
    }
#pragma unroll
    for (int mt = 0; mt < 2; ++mt)
#pragma unroll
        for (int nt = 0; nt < 4; ++nt) {
            int n = n0 + nt * 16 + fr;
            float b1v = wb[n], b2v = wb[HDIM + n];
#pragma unroll
            for (int r = 0; r < 4; ++r) {
                int m = m0 + wv * 32 + mt * 16 + quad * 4 + r;
                float z1 = acc1[mt][nt][r] + b1v;
                float z2 = acc2[mt][nt][r] + b2v;
                G[(size_t)m * HDIM + n] = z1 / (1.0f + __expf(-z2));
            }
        }
}

// ---------------- residual + LayerNorm (in place on H) ----------------
__global__ void k_ln(const float* __restrict__ G, float* __restrict__ Hb,
                     const float* __restrict__ w, const float* __restrict__ bb) {
    int row = blockIdx.x, hh = threadIdx.x;
    float r = G[row * HDIM + hh] + Hb[row * HDIM + hh];
    float s = r;
#pragma unroll
    for (int m = 1; m < 64; m <<= 1) s += __shfl_xor(s, m, 64);
    __shared__ float red[8];
    int wv = hh >> 6, lane = hh & 63;
    if (lane == 0) red[wv] = s;
    __syncthreads();
    float mean = (red[0] + red[1] + red[2] + red[3]) * (1.0f / HDIM);
    float d = r - mean;
    float s2 = d * d;
#pragma unroll
    for (int m = 1; m < 64; m <<= 1) s2 += __shfl_xor(s2, m, 64);
    if (lane == 0) red[4 + wv] = s2;
    __syncthreads();
    float var = (red[4] + red[5] + red[6] + red[7]) * (1.0f / HDIM);
    float rstd = rsqrtf(var + 1e-5f);
    Hb[row * HDIM + hh] = d * rstd * w[hh] + bb[hh];
}

// ---------------- decoder ----------------
__global__ void k_dec(const float* __restrict__ Hb, const float* __restrict__ dw,
                      const float* __restrict__ db, float* __restrict__ out) {
    __shared__ float ws[HDIM * DOUT];
    int tid = threadIdx.x;                    // 320 threads
    for (int e = tid; e < HDIM * DOUT; e += 320) ws[e] = dw[e];
    __syncthreads();
    int r = tid / DOUT, o = tid - r * DOUT;
    int row = blockIdx.x * 32 + r;
    float acc = db[o];
    const float* hp = Hb + row * HDIM;
#pragma unroll 8
    for (int k = 0; k < HDIM; ++k) acc = fmaf(hp[k], ws[k * DOUT + o], acc);
    out[row * DOUT + o] = acc;
}

extern "C" void kernel_launch(void* const* d_in, const int* in_sizes, int n_in,
                              void* d_out, int out_size, void* d_ws, size_t ws_size,
                              hipStream_t stream) {
    const float* x        = (const float*)d_in[0];
    const float* enc_w    = (const float*)d_in[1];
    const float* enc_b    = (const float*)d_in[2];
    const float* log_dt   = (const float*)d_in[3];
    const float* A_re_log = (const float*)d_in[4];
    const float* A_im     = (const float*)d_in[5];
    const float* B_re     = (const float*)d_in[6];
    const float* B_im     = (const float*)d_in[7];
    const float* C_re     = (const float*)d_in[8];
    const float* C_im     = (const float*)d_in[9];
    const float* Dp       = (const float*)d_in[10];
    const float* ln_w     = (const float*)d_in[11];
    const float* ln_b     = (const float*)d_in[12];
    const float* out_w    = (const float*)d_in[13];
    const float* out_b    = (const float*)d_in[14];
    const float* dec_w    = (const float*)d_in[15];
    const float* dec_b    = (const float*)d_in[16];
    float* outp = (float*)d_out;

    float* w = (float*)d_ws;
    const size_t PWE = (size_t)NLAYERS * NSTATE * HDIM;   // 32768
    const size_t MH  = (size_t)M_ROWS * HDIM;             // 8388608
    float4* PWt  = (float4*)w;                            // 512 KB
    float2* PA64 = (float2*)(w + 4 * PWE);                // 256 KB
    float*  Td   = w + 6 * PWE;                           // 4*256*66 floats
    float*  Hbuf = Td + (size_t)NLAYERS * HDIM * 66;      // 33.5 MB fp32
    float*  R2   = Hbuf + MH;                             // 33.5 MB: E / Yt / G
    bf16*   R3   = (bf16*)(R2 + MH);                      // 16.7 MB: Ut / Ybf
    bf16*   Carry = R3 + MH;                              // 16.7 MB
    bf16*   Wt    = Carry + MH;                           // 1 MB
    float*  E   = R2;
    bf16*   Yt  = (bf16*)R2;
    float*  G   = R2;
    bf16*   Ut  = R3;
    bf16*   Ybf = R3;

    k_params<<<NLAYERS * HDIM * NSTATE / 256, 256, 0, stream>>>(log_dt, A_re_log, A_im,
                                                                B_re, B_im, C_re, C_im, PWt, PA64);
    k_td<<<NLAYERS, 256, 0, stream>>>(PWt, Td);
    k_wcvt<<<NLAYERS * 512 * 256 / 256, 256, 0, stream>>>(out_w, Wt);

    dim3 ge(M_ROWS / 128, HDIM / 128);
    k_enc<<<ge, 256, 0, stream>>>(x, enc_w, enc_b, Hbuf);

    dim3 gtr(M_ROWS / 64, HDIM / 64);
    dim3 gconv(HDIM, NBC / 128);
    dim3 gsb(HDIM, 4);
    dim3 gg(M_ROWS / 128, HDIM / 64);

    for (int layer = 0; layer < NLAYERS; ++layer) {
        const float4* pwl = PWt + (size_t)layer * NSTATE * HDIM;
        const float2* pal = PA64 + (size_t)layer * NSTATE * HDIM;
        const float*  tdl = Td + (size_t)layer * HDIM * 66;
        k_tr<<<gtr, 256, 0, stream>>>(Hbuf, Ut);
        k_convA<<<gconv, 256, 0, stream>>>(Ut, pwl, E);
        k_scanB2<<<gsb, 256, 0, stream>>>(E, pal, Carry);
        k_convC<<<gconv, 256, 0, stream>>>(Ut, Carry, tdl, pwl, Dp + layer * HDIM, Yt);
        k_trY<<<gtr, 256, 0, stream>>>(Yt, Ybf);
        k_glu<<<gg, 256, 0, stream>>>(Ybf, Wt + (size_t)layer * 512 * HDIM,
                                      out_b + layer * 2 * HDIM, G);
        k_ln<<<M_ROWS, HDIM, 0, stream>>>(G, Hbuf, ln_w + layer * HDIM, ln_b + layer * HDIM);
    }
    k_dec<<<M_ROWS / 32, 320, 0, stream>>>(Hbuf, dec_w, dec_b, outp);
}

// Round 11
// 601.935 us; speedup vs baseline: 4.8060x; 1.0630x over previous
//
#include <hip/hip_runtime.h>
#include <hip/hip_bf16.h>
#include <math.h>

#define B_SZ    32
#define LSEQ    1024
#define DIN     128
#define HDIM    256
#define NLAYERS 4
#define NSTATE  32
#define DOUT    10
#define M_ROWS  (B_SZ*LSEQ)   // 32768
#define CH      64            // scan chunk length
#define NCH     (LSEQ/CH)     // 16 chunks
#define NBC     (B_SZ*NCH)    // 512 chunk-columns

typedef __hip_bfloat16 bf16;
typedef __attribute__((ext_vector_type(8))) short bf16x8;
typedef __attribute__((ext_vector_type(4))) float f32x4;

__device__ __forceinline__ unsigned short f2bu(float x) {
    bf16 b = __float2bfloat16(x);
    return *(unsigned short*)&b;
}

// ---------------- per-(layer,h,n) discretized params ----------------
__global__ void k_params(const float* __restrict__ log_dt, const float* __restrict__ A_re_log,
                         const float* __restrict__ A_im, const float* __restrict__ B_re,
                         const float* __restrict__ B_im, const float* __restrict__ C_re,
                         const float* __restrict__ C_im, float4* __restrict__ PWt,
                         float2* __restrict__ PA64) {
    int idx = blockIdx.x * 256 + threadIdx.x;       // layer*H*N + h*N + n
    int n = idx & 31, hn = idx >> 5;
    int h = hn & 255, layer = hn >> 8;
    float dt   = expf(log_dt[hn]);
    float Are  = -expf(A_re_log[idx]);
    float Aim  = A_im[idx];
    float dtAre = dt * Are, dtAim = dt * Aim;
    float ea   = expf(dtAre);
    float dAre = ea * cosf(dtAim), dAim = ea * sinf(dtAim);
    float nre = dAre - 1.0f, nim = dAim;            // dA - 1
    float inv = 1.0f / (Are * Are + Aim * Aim);
    float tre = (nre * Are + nim * Aim) * inv;      // (dA-1)/A
    float tim = (nim * Are - nre * Aim) * inv;
    float Brv = B_re[idx], Biv = B_im[idx];
    float dBre = Brv * tre - Biv * tim;
    float dBim = Brv * tim + Biv * tre;
    float Crv = C_re[idx], Civ = C_im[idx];
    float Wre = Crv * dBre - Civ * dBim;
    float Wim = Crv * dBim + Civ * dBre;
    int o = (layer * NSTATE + n) * HDIM + h;        // [layer][n][h]
    PWt[o] = make_float4(dAre, dAim, Wre, Wim);
    float e64 = expf(64.0f * dtAre);
    float ph  = 64.0f * dtAim;
    PA64[o] = make_float2(e64 * cosf(ph), e64 * sinf(ph));
}

// ---------------- Toeplitz kernel values: Td[lh][d] = 2 Re sum_n W dA^d, d=0..64 ----------------
__global__ void k_td(const float4* __restrict__ PWt, float* __restrict__ Td) {
    int lh = blockIdx.x * 256 + threadIdx.x;        // layer*256 + h
    int layer = lh >> 8, h = lh & 255;
    const float4* P = PWt + (size_t)layer * NSTATE * HDIM;
    float acc[65];
#pragma unroll
    for (int d = 0; d < 65; ++d) acc[d] = 0.f;
    for (int n = 0; n < NSTATE; ++n) {
        float4 q = P[n * HDIM + h];
        float zr = q.z, zi = q.w;                   // W * dA^0
#pragma unroll
        for (int d = 0; d < 65; ++d) {
            acc[d] += zr;
            float nzr = zr * q.x - zi * q.y;
            zi = zr * q.y + zi * q.x;
            zr = nzr;
        }
    }
    for (int d = 0; d < 65; ++d) Td[(size_t)lh * 66 + d] = 2.f * acc[d];
}

// ---------------- V/M matrices for one layer (bf16): V[h][comp][j], M[h][comp][l] ----------------
// V[2n][j]=Re(W dA^(63-j)), V[2n+1][j]=Im; M[2n][l]=2Re(dA^(l+1)), M[2n+1][l]=-2Im
__global__ void k_vm(const float4* __restrict__ PW, bf16* __restrict__ Vg, bf16* __restrict__ Mg) {
    int idx = blockIdx.x * 256 + threadIdx.x;       // h*64 + comp
    int comp = idx & 63, h = idx >> 6;
    int n = comp >> 1, isIm = comp & 1;
    float4 q = PW[n * HDIM + h];
    float zr = q.z, zi = q.w;                       // W dA^0
    float wr = q.x, wi = q.y;                       // dA^1
    unsigned short vbuf[64], mbuf[64];
#pragma unroll
    for (int d = 0; d < 64; ++d) {
        vbuf[63 - d] = f2bu(isIm ? zi : zr);
        float nzr = zr * q.x - zi * q.y;
        zi = zr * q.y + zi * q.x;  zr = nzr;
        mbuf[d] = f2bu(isIm ? -2.f * wi : 2.f * wr);
        float nwr = wr * q.x - wi * q.y;
        wi = wr * q.y + wi * q.x;  wr = nwr;
    }
    unsigned int* Vrow = (unsigned int*)(Vg + (size_t)idx * 64);
    unsigned int* Mrow = (unsigned int*)(Mg + (size_t)idx * 64);
#pragma unroll
    for (int s = 0; s < 32; ++s) {
        Vrow[s] = (unsigned int)vbuf[2 * s] | ((unsigned int)vbuf[2 * s + 1] << 16);
        Mrow[s] = (unsigned int)mbuf[2 * s] | ((unsigned int)mbuf[2 * s + 1] << 16);
    }
}

// ---------------- one-off weight transpose+cast: Wt[layer][n(512)][k(256)] bf16 ----------------
__global__ void k_wcvt(const float* __restrict__ Wsrc, bf16* __restrict__ Wt) {
    int idx = blockIdx.x * 256 + threadIdx.x;   // ((layer*512)+n)*256+k
    int k = idx & 255;
    int n = (idx >> 8) & 511;
    int layer = idx >> 17;
    Wt[idx] = __float2bfloat16(Wsrc[((size_t)(layer * 256 + k)) * 512 + n]);
}

// ---------------- one-off encoder weight transpose+cast: Wet[n(256)][k(128)] bf16 ----------------
__global__ void k_wenc(const float* __restrict__ Wsrc, bf16* __restrict__ Wet) {
    int idx = blockIdx.x * 256 + threadIdx.x;   // n*128+k
    int k = idx & 127, n = idx >> 7;
    Wet[idx] = __float2bfloat16(Wsrc[(size_t)k * HDIM + n]);
}

// ---------------- transpose Hbuf fp32 [m][h] -> Ut bf16 [h][m] ----------------
__global__ __launch_bounds__(256) void k_tr(const float* __restrict__ H, bf16* __restrict__ Ut) {
    __shared__ bf16 t_s[64][72];
    int m0 = blockIdx.x * 64, h0 = blockIdx.y * 64;
    int tid = threadIdx.x;
#pragma unroll
    for (int i = 0; i < 4; ++i) {
        int q = tid + i * 256, row = q >> 4, seg = q & 15;
        float4 v = *(const float4*)&H[(size_t)(m0 + row) * HDIM + h0 + seg * 4];
        t_s[seg * 4 + 0][row] = __float2bfloat16(v.x);
        t_s[seg * 4 + 1][row] = __float2bfloat16(v.y);
        t_s[seg * 4 + 2][row] = __float2bfloat16(v.z);
        t_s[seg * 4 + 3][row] = __float2bfloat16(v.w);
    }
    __syncthreads();
#pragma unroll
    for (int i = 0; i < 2; ++i) {
        int q = tid + i * 256, row = q >> 3, seg = q & 7;
        *(uint4*)&Ut[(size_t)(h0 + row) * M_ROWS + m0 + seg * 8] = *(uint4*)&t_s[row][seg * 8];
    }
}

// ---------------- transpose Yt bf16 [h][m] -> Y bf16 [m][h] ----------------
__global__ __launch_bounds__(256) void k_trY(const bf16* __restrict__ Yt, bf16* __restrict__ Y) {
    __shared__ bf16 t_s[64][72];
    int m0 = blockIdx.x * 64, h0 = blockIdx.y * 64;
    int tid = threadIdx.x;
#pragma unroll
    for (int i = 0; i < 2; ++i) {
        int q = tid + i * 256, row = q >> 3, seg = q & 7;
        uint4 v = *(const uint4*)&Yt[(size_t)(h0 + row) * M_ROWS + m0 + seg * 8];
        const bf16* pv = (const bf16*)&v;
#pragma unroll
        for (int e = 0; e < 8; ++e) t_s[seg * 8 + e][row] = pv[e];
    }
    __syncthreads();
#pragma unroll
    for (int i = 0; i < 2; ++i) {
        int q = tid + i * 256, row = q >> 3, seg = q & 7;
        *(uint4*)&Y[(size_t)(m0 + row) * HDIM + h0 + seg * 8] = *(uint4*)&t_s[row][seg * 8];
    }
}

// ---------------- encoder GEMM (bf16 MFMA): H = X@We + b, + transposed Ut output ----------------
// grid (M_ROWS/128, HDIM/64), block 256
__global__ __launch_bounds__(256) void k_enc2(const float* __restrict__ X, const bf16* __restrict__ Wet,
                                              const float* __restrict__ bias, float* __restrict__ H,
                                              bf16* __restrict__ Ut) {
    __shared__ bf16 A_s[128 * 136];
    __shared__ bf16 B_s[64 * 136];
    int tid = threadIdx.x;
    int lane = tid & 63, wv = tid >> 6, quad = lane >> 4, fr = lane & 15;
    int m0 = blockIdx.x * 128, n0 = blockIdx.y * 64;
#pragma unroll
    for (int i = 0; i < 16; ++i) {               // stage X fp32 -> bf16 [m][k]
        int q = tid + i * 256, row = q >> 5, seg = q & 31;
        float4 v = *(const float4*)&X[(size_t)(m0 + row) * DIN + seg * 4];
        bf16* dst = &A_s[row * 136 + seg * 4];
        dst[0] = __float2bfloat16(v.x); dst[1] = __float2bfloat16(v.y);
        dst[2] = __float2bfloat16(v.z); dst[3] = __float2bfloat16(v.w);
    }
#pragma unroll
    for (int i = 0; i < 4; ++i) {                // stage Wet [n][k]
        int q = tid + i * 256, row = q >> 4, seg = q & 15;
        *(uint4*)&B_s[row * 136 + seg * 8] = *(const uint4*)&Wet[(size_t)(n0 + row) * DIN + seg * 8];
    }
    __syncthreads();
    f32x4 acc[2][4];
#pragma unroll
    for (int mt = 0; mt < 2; ++mt)
#pragma unroll
        for (int nt = 0; nt < 4; ++nt) acc[mt][nt] = (f32x4){0.f, 0.f, 0.f, 0.f};
#pragma unroll
    for (int ks = 0; ks < 4; ++ks) {
        bf16x8 a[2], b[4];
#pragma unroll
        for (int mt = 0; mt < 2; ++mt)
            a[mt] = *(const bf16x8*)&A_s[(wv * 32 + mt * 16 + fr) * 136 + ks * 32 + quad * 8];
#pragma unroll
        for (int nt = 0; nt < 4; ++nt)
            b[nt] = *(const bf16x8*)&B_s[(nt * 16 + fr) * 136 + ks * 32 + quad * 8];
#pragma unroll
        for (int mt = 0; mt < 2; ++mt)
#pragma unroll
            for (int nt = 0; nt < 4; ++nt)
                acc[mt][nt] = __builtin_amdgcn_mfma_f32_16x16x32_bf16(a[mt], b[nt], acc[mt][nt], 0, 0, 0);
    }
    __syncthreads();                             // B_s reuse as transpose bounce
#pragma unroll
    for (int mt = 0; mt < 2; ++mt)
#pragma unroll
        for (int nt = 0; nt < 4; ++nt) {
            int n = n0 + nt * 16 + fr;
            float bv = bias[n];
#pragma unroll
            for (int r = 0; r < 4; ++r) {
                int m = m0 + wv * 32 + mt * 16 + quad * 4 + r;
                float hv = acc[mt][nt][r] + bv;
                H[(size_t)m * HDIM + n] = hv;
                B_s[(nt * 16 + fr) * 136 + (wv * 32 + mt * 16 + quad * 4 + r)] = __float2bfloat16(hv);
            }
        }
    __syncthreads();
#pragma unroll
    for (int i = 0; i < 4; ++i) {                // coalesced Ut store [h][m]
        int q = tid + i * 256, row = q >> 4, seg = q & 15;
        *(uint4*)&Ut[(size_t)(n0 + row) * M_ROWS + m0 + seg * 8] = *(uint4*)&B_s[row * 136 + seg * 8];
    }
}

// ---------------- conv phase A (MFMA): E[h][comp][bc] = V_h @ u ----------------
__global__ __launch_bounds__(256) void k_convA(const bf16* __restrict__ Ut,
                                               const bf16* __restrict__ Vg,
                                               float* __restrict__ E) {
    __shared__ bf16 V_s[64 * 72];
    __shared__ bf16 u_s[128 * 72];
    __shared__ float o_s[64 * 132];
    int h = blockIdx.x, bc0 = blockIdx.y * 128;
    int tid = threadIdx.x;
    int lane = tid & 63, wv = tid >> 6, quad = lane >> 4, fr = lane & 15;
#pragma unroll
    for (int i = 0; i < 2; ++i) {                // stage V from global
        int q = tid + i * 256, row = q >> 3, seg = q & 7;
        *(uint4*)&V_s[row * 72 + seg * 8] =
            *(const uint4*)&Vg[((size_t)h * 64 + row) * 64 + seg * 8];
    }
#pragma unroll
    for (int i = 0; i < 4; ++i) {                // stage u tile [bc][j]
        int q = tid + i * 256, row = q >> 3, c8 = q & 7;
        *(uint4*)&u_s[row * 72 + c8 * 8] =
            *(const uint4*)&Ut[(size_t)h * M_ROWS + (size_t)(bc0 + row) * 64 + c8 * 8];
    }
    __syncthreads();
    f32x4 acc[4][2];
#pragma unroll
    for (int mt = 0; mt < 4; ++mt)
#pragma unroll
        for (int nf = 0; nf < 2; ++nf) acc[mt][nf] = (f32x4){0.f, 0.f, 0.f, 0.f};
#pragma unroll
    for (int ks = 0; ks < 2; ++ks) {
        bf16x8 a[4], b[2];
#pragma unroll
        for (int mt = 0; mt < 4; ++mt)
            a[mt] = *(const bf16x8*)&V_s[(mt * 16 + fr) * 72 + ks * 32 + quad * 8];
#pragma unroll
        for (int nf = 0; nf < 2; ++nf)
            b[nf] = *(const bf16x8*)&u_s[(wv * 32 + nf * 16 + fr) * 72 + ks * 32 + quad * 8];
#pragma unroll
        for (int mt = 0; mt < 4; ++mt)
#pragma unroll
            for (int nf = 0; nf < 2; ++nf)
                acc[mt][nf] = __builtin_amdgcn_mfma_f32_16x16x32_bf16(a[mt], b[nf], acc[mt][nf], 0, 0, 0);
    }
#pragma unroll
    for (int mt = 0; mt < 4; ++mt)
#pragma unroll
        for (int nf = 0; nf < 2; ++nf)
#pragma unroll
            for (int r = 0; r < 4; ++r)
                o_s[(mt * 16 + quad * 4 + r) * 132 + wv * 32 + nf * 16 + fr] = acc[mt][nf][r];
    __syncthreads();
#pragma unroll
    for (int i = 0; i < 32; ++i) {               // coalesced E store
        int q = tid + i * 256, comp = q >> 7, bcl = q & 127;
        E[((size_t)h * 64 + comp) * NBC + bc0 + bcl] = o_s[comp * 132 + bcl];
    }
}

// ---------------- carry scan: E -> Carry[h][bc][comp] bf16, reg-resident ----------------
__global__ void k_scanB2(const float* __restrict__ E, const float2* __restrict__ PA,
                         bf16* __restrict__ Carry) {
    int h = blockIdx.x;
    int b = blockIdx.y * 8 + (threadIdx.x >> 5);
    int n = threadIdx.x & 31;
    float2 a = PA[n * HDIM + h];
    const float* Er = E + ((size_t)h * 64 + 2 * n) * NBC + b * NCH;
    const float* Ei = Er + NBC;
    float er[16], ei[16];
#pragma unroll
    for (int s = 0; s < 4; ++s) {                // full-line vector preloads
        *(float4*)&er[s * 4] = *(const float4*)&Er[s * 4];
        *(float4*)&ei[s * 4] = *(const float4*)&Ei[s * 4];
    }
    unsigned int* C = (unsigned int*)Carry + ((size_t)h * NBC + b * NCH) * 32 + n;
    float cr = 0.f, ci = 0.f;
#pragma unroll
    for (int c = 0; c < NCH; ++c) {              // coalesced packed stores
        C[c * 32] = (unsigned int)f2bu(cr) | ((unsigned int)f2bu(ci) << 16);
        float nr = fmaf(a.x, cr, fmaf(-a.y, ci, er[c]));
        ci = fmaf(a.x, ci, fmaf(a.y, cr, ei[c]));
        cr = nr;
    }
}

// ---------------- conv phase C (MFMA): Yt = gelu([T|M]@[u;carry] + D*u) ----------------
__global__ __launch_bounds__(256) void k_convC(const bf16* __restrict__ Ut,
                                               const bf16* __restrict__ Carry,
                                               const float* __restrict__ Tdl,
                                               const bf16* __restrict__ Mg,
                                               const float* __restrict__ Dw,
                                               bf16* __restrict__ Yt) {
    __shared__ bf16 A_s[64 * 136];               // [l][k2], k2<64: T, k2>=64: M
    __shared__ bf16 u_s[128 * 72];
    __shared__ bf16 c_s[128 * 72];
    __shared__ bf16 o_s[128 * 72];
    __shared__ float Td_s[65];
    int h = blockIdx.x, bc0 = blockIdx.y * 128;
    int tid = threadIdx.x;
    int lane = tid & 63, wv = tid >> 6, quad = lane >> 4, fr = lane & 15;
    if (tid < 65) Td_s[tid] = Tdl[(size_t)h * 66 + tid];
#pragma unroll
    for (int i = 0; i < 2; ++i) {                // stage M from global (transposed into A_s)
        int q = tid + i * 256, comp = q >> 3, seg = q & 7;
        uint4 v = *(const uint4*)&Mg[((size_t)h * 64 + comp) * 64 + seg * 8];
        const bf16* pv = (const bf16*)&v;
#pragma unroll
        for (int e = 0; e < 8; ++e) A_s[(seg * 8 + e) * 136 + 64 + comp] = pv[e];
    }
#pragma unroll
    for (int i = 0; i < 4; ++i) {                // stage u, carry tiles
        int q = tid + i * 256, row = q >> 3, c8 = q & 7;
        *(uint4*)&u_s[row * 72 + c8 * 8] =
            *(const uint4*)&Ut[(size_t)h * M_ROWS + (size_t)(bc0 + row) * 64 + c8 * 8];
        *(uint4*)&c_s[row * 72 + c8 * 8] =
            *(const uint4*)&Carry[((size_t)h * NBC + bc0 + row) * 64 + c8 * 8];
    }
    __syncthreads();                             // Td_s ready
#pragma unroll
    for (int i = 0; i < 16; ++i) {               // Toeplitz T fill
        int q = tid + i * 256, l = q >> 6, j = q & 63, d = l - j;
        A_s[l * 136 + j] = __float2bfloat16(d >= 0 ? Td_s[d] : 0.f);
    }
    __syncthreads();
    f32x4 acc[4][2];
#pragma unroll
    for (int mt = 0; mt < 4; ++mt)
#pragma unroll
        for (int nf = 0; nf < 2; ++nf) acc[mt][nf] = (f32x4){0.f, 0.f, 0.f, 0.f};
#pragma unroll
    for (int ks = 0; ks < 4; ++ks) {
        bf16x8 a[4], b[2];
#pragma unroll
        for (int mt = 0; mt < 4; ++mt)
            a[mt] = *(const bf16x8*)&A_s[(mt * 16 + fr) * 136 + ks * 32 + quad * 8];
#pragma unroll
        for (int nf = 0; nf < 2; ++nf) {
            int row = (wv * 32 + nf * 16 + fr) * 72;
            b[nf] = (ks < 2) ? *(const bf16x8*)&u_s[row + ks * 32 + quad * 8]
                             : *(const bf16x8*)&c_s[row + (ks - 2) * 32 + quad * 8];
        }
#pragma unroll
        for (int mt = 0; mt < 4; ++mt)
#pragma unroll
            for (int nf = 0; nf < 2; ++nf)
                acc[mt][nf] = __builtin_amdgcn_mfma_f32_16x16x32_bf16(a[mt], b[nf], acc[mt][nf], 0, 0, 0);
    }
    float Dv = Dw[h];
#pragma unroll
    for (int mt = 0; mt < 4; ++mt)
#pragma unroll
        for (int nf = 0; nf < 2; ++nf) {
            int bcl = wv * 32 + nf * 16 + fr;
#pragma unroll
            for (int r = 0; r < 4; ++r) {
                int l = mt * 16 + quad * 4 + r;
                float u = __bfloat162float(u_s[bcl * 72 + l]);
                float v = fmaf(Dv, u, acc[mt][nf][r]);
                float z2 = 1.5957691216057308f * (v + 0.044715f * v * v * v);
                o_s[bcl * 72 + l] = __float2bfloat16(v / (1.f + __expf(-z2)));
            }
        }
    __syncthreads();
#pragma unroll
    for (int i = 0; i < 4; ++i) {                // coalesced Yt store
        int q = tid + i * 256, row = q >> 3, c8 = q & 7;
        *(uint4*)&Yt[(size_t)h * M_ROWS + (size_t)(bc0 + row) * 64 + c8 * 8] =
            *(uint4*)&o_s[row * 72 + c8 * 8];
    }
}

// ---------------- output GEMM + fused GLU, bf16 MFMA, bf16 G out ----------------
__global__ __launch_bounds__(256) void k_glu(const bf16* __restrict__ Ybf,
                                             const bf16* __restrict__ Wt,
                                             const float* __restrict__ wb,
                                             bf16* __restrict__ G) {
    __shared__ short A_s[128 * 72];
    __shared__ short B1_s[64 * 72];
    __shared__ short B2_s[64 * 72];
    int tid = threadIdx.x;
    int lane = tid & 63, wv = tid >> 6;
    int quad = lane >> 4, fr = lane & 15;
    int m0 = blockIdx.x * 128, n0 = blockIdx.y * 64;
    f32x4 acc1[2][4], acc2[2][4];
#pragma unroll
    for (int mt = 0; mt < 2; ++mt)
#pragma unroll
        for (int nt = 0; nt < 4; ++nt) {
            acc1[mt][nt] = (f32x4){0.f,0.f,0.f,0.f};
            acc2[mt][nt] = (f32x4){0.f,0.f,0.f,0.f};
        }
    for (int kt = 0; kt < HDIM; kt += 64) {
#pragma unroll
        for (int i = 0; i < 4; ++i) {
            int e = tid + i * 256, row = e >> 3, cm = e & 7;
            *(uint4*)&A_s[row * 72 + cm * 8] =
                *(const uint4*)(Ybf + (size_t)(m0 + row) * HDIM + kt + cm * 8);
        }
#pragma unroll
        for (int i = 0; i < 2; ++i) {
            int e = tid + i * 256, row = e >> 3, cm = e & 7;
            *(uint4*)&B1_s[row * 72 + cm * 8] =
                *(const uint4*)(Wt + (size_t)(n0 + row) * HDIM + kt + cm * 8);
            *(uint4*)&B2_s[row * 72 + cm * 8] =
                *(const uint4*)(Wt + (size_t)(256 + n0 + row) * HDIM + kt + cm * 8);
        }
        __syncthreads();
#pragma unroll
        for (int s = 0; s < 2; ++s) {
            bf16x8 a[2], b1[4], b2[4];
#pragma unroll
            for (int mt = 0; mt < 2; ++mt)
                a[mt] = *(const bf16x8*)&A_s[(wv * 32 + mt * 16 + fr) * 72 + s * 32 + quad * 8];
#pragma unroll
            for (int nt = 0; nt < 4; ++nt) {
                b1[nt] = *(const bf16x8*)&B1_s[(nt * 16 + fr) * 72 + s * 32 + quad * 8];
                b2[nt] = *(const bf16x8*)&B2_s[(nt * 16 + fr) * 72 + s * 32 + quad * 8];
            }
#pragma unroll
            for (int mt = 0; mt < 2; ++mt)
#pragma unroll
                for (int nt = 0; nt < 4; ++nt) {
                    acc1[mt][nt] = __builtin_amdgcn_mfma_f32_16x16x32_bf16(a[mt], b1[nt], acc1[mt][nt], 0, 0, 0);
                    acc2[mt][nt] = __builtin_amdgcn_mfma_f32_16x16x32_bf16(a[mt], b2[nt], acc2[mt][nt], 0, 0, 0);
                }
        }
        __syncthreads();
    }
#pragma unroll
    for (int mt = 0; mt < 2; ++mt)
#pragma unroll
        for (int nt = 0; nt < 4; ++nt) {
            int n = n0 + nt * 16 + fr;
            float b1v = wb[n], b2v = wb[HDIM + n];
#pragma unroll
            for (int r = 0; r < 4; ++r) {
                int m = m0 + wv * 32 + mt * 16 + quad * 4 + r;
                float z1 = acc1[mt][nt][r] + b1v;
                float z2 = acc2[mt][nt][r] + b2v;
                G[(size_t)m * HDIM + n] = __float2bfloat16(z1 / (1.0f + __expf(-z2)));
            }
        }
}

// ---------------- residual + LayerNorm (in place on H), bf16 G in ----------------
__global__ void k_ln(const bf16* __restrict__ G, float* __restrict__ Hb,
                     const float* __restrict__ w, const float* __restrict__ bb) {
    int row = blockIdx.x, hh = threadIdx.x;
    float r = __bfloat162float(G[(size_t)row * HDIM + hh]) + Hb[(size_t)row * HDIM + hh];
    float s = r;
#pragma unroll
    for (int m = 1; m < 64; m <<= 1) s += __shfl_xor(s, m, 64);
    __shared__ float red[8];
    int wv = hh >> 6, lane = hh & 63;
    if (lane == 0) red[wv] = s;
    __syncthreads();
    float mean = (red[0] + red[1] + red[2] + red[3]) * (1.0f / HDIM);
    float d = r - mean;
    float s2 = d * d;
#pragma unroll
    for (int m = 1; m < 64; m <<= 1) s2 += __shfl_xor(s2, m, 64);
    if (lane == 0) red[4 + wv] = s2;
    __syncthreads();
    float var = (red[4] + red[5] + red[6] + red[7]) * (1.0f / HDIM);
    float rstd = rsqrtf(var + 1e-5f);
    Hb[(size_t)row * HDIM + hh] = d * rstd * w[hh] + bb[hh];
}

// ---------------- decoder ----------------
__global__ void k_dec(const float* __restrict__ Hb, const float* __restrict__ dw,
                      const float* __restrict__ db, float* __restrict__ out) {
    __shared__ float ws[HDIM * DOUT];
    int tid = threadIdx.x;                    // 320 threads
    for (int e = tid; e < HDIM * DOUT; e += 320) ws[e] = dw[e];
    __syncthreads();
    int r = tid / DOUT, o = tid - r * DOUT;
    int row = blockIdx.x * 32 + r;
    float acc = db[o];
    const float* hp = Hb + (size_t)row * HDIM;
#pragma unroll 8
    for (int k = 0; k < HDIM; ++k) acc = fmaf(hp[k], ws[k * DOUT + o], acc);
    out[row * DOUT + o] = acc;
}

extern "C" void kernel_launch(void* const* d_in, const int* in_sizes, int n_in,
                              void* d_out, int out_size, void* d_ws, size_t ws_size,
                              hipStream_t stream) {
    const float* x        = (const float*)d_in[0];
    const float* enc_w    = (const float*)d_in[1];
    const float* enc_b    = (const float*)d_in[2];
    const float* log_dt   = (const float*)d_in[3];
    const float* A_re_log = (const float*)d_in[4];
    const float* A_im     = (const float*)d_in[5];
    const float* B_re     = (const float*)d_in[6];
    const float* B_im     = (const float*)d_in[7];
    const float* C_re     = (const float*)d_in[8];
    const float* C_im     = (const float*)d_in[9];
    const float* Dp       = (const float*)d_in[10];
    const float* ln_w     = (const float*)d_in[11];
    const float* ln_b     = (const float*)d_in[12];
    const float* out_w    = (const float*)d_in[13];
    const float* out_b    = (const float*)d_in[14];
    const float* dec_w    = (const float*)d_in[15];
    const float* dec_b    = (const float*)d_in[16];
    float* outp = (float*)d_out;

    float* w = (float*)d_ws;
    const size_t PWE = (size_t)NLAYERS * NSTATE * HDIM;   // 32768
    const size_t MH  = (size_t)M_ROWS * HDIM;             // 8388608
    float4* PWt  = (float4*)w;                            // 512 KB
    float2* PA64 = (float2*)(w + 4 * PWE);                // 256 KB
    float*  Td   = w + 6 * PWE;                           // 270 KB
    float*  Hbuf = Td + (size_t)NLAYERS * HDIM * 66;      // 33.5 MB fp32
    float*  R2   = Hbuf + MH;                             // 33.5 MB: E fp32 / Yt bf16 / G bf16
    bf16*   R3   = (bf16*)(R2 + MH);                      // 16.7 MB: Ut / Ybf
    bf16*   Carry = R3 + MH;                              // 16.7 MB
    bf16*   Wt    = Carry + MH;                           // 1 MB
    bf16*   Wet   = Wt + (size_t)NLAYERS * 512 * HDIM;    // 64 KB
    bf16*   Vg    = Wet + (size_t)HDIM * DIN;             // 2 MB (per-layer reuse)
    bf16*   Mg    = Vg + (size_t)HDIM * 64 * 64;          // 2 MB
    float*  E   = R2;
    bf16*   Yt  = (bf16*)R2;
    bf16*   G   = (bf16*)R2;
    bf16*   Ut  = R3;
    bf16*   Ybf = R3;

    k_params<<<NLAYERS * HDIM * NSTATE / 256, 256, 0, stream>>>(log_dt, A_re_log, A_im,
                                                                B_re, B_im, C_re, C_im, PWt, PA64);
    k_td<<<NLAYERS, 256, 0, stream>>>(PWt, Td);
    k_wcvt<<<NLAYERS * 512 * 256 / 256, 256, 0, stream>>>(out_w, Wt);
    k_wenc<<<HDIM * DIN / 256, 256, 0, stream>>>(enc_w, Wet);

    dim3 ge(M_ROWS / 128, HDIM / 64);
    k_enc2<<<ge, 256, 0, stream>>>(x, Wet, enc_b, Hbuf, Ut);

    dim3 gtr(M_ROWS / 64, HDIM / 64);
    dim3 gconv(HDIM, NBC / 128);
    dim3 gsb(HDIM, 4);
    dim3 gg(M_ROWS / 128, HDIM / 64);

    for (int layer = 0; layer < NLAYERS; ++layer) {
        const float4* pwl = PWt + (size_t)layer * NSTATE * HDIM;
        const float2* pal = PA64 + (size_t)layer * NSTATE * HDIM;
        const float*  tdl = Td + (size_t)layer * HDIM * 66;
        k_vm<<<HDIM * 64 / 256, 256, 0, stream>>>(pwl, Vg, Mg);
        k_convA<<<gconv, 256, 0, stream>>>(Ut, Vg, E);
        k_scanB2<<<gsb, 256, 0, stream>>>(E, pal, Carry);
        k_convC<<<gconv, 256, 0, stream>>>(Ut, Carry, tdl, Mg, Dp + layer * HDIM, Yt);
        k_trY<<<gtr, 256, 0, stream>>>(Yt, Ybf);
        k_glu<<<gg, 256, 0, stream>>>(Ybf, Wt + (size_t)layer * 512 * HDIM,
                                      out_b + layer * 2 * HDIM, G);
        k_ln<<<M_ROWS, 256, 0, stream>>>(G, Hbuf, ln_w + layer * HDIM, ln_b + layer * HDIM);
        if (layer < NLAYERS - 1)
            k_tr<<<gtr, 256, 0, stream>>>(Hbuf, Ut);
    }
    k_dec<<<M_ROWS / 32, 320, 0, stream>>>(Hbuf, dec_w, dec_b, outp);
}

// Round 12
// 546.082 us; speedup vs baseline: 5.2976x; 1.1023x over previous
//
#include <hip/hip_runtime.h>
#include <hip/hip_bf16.h>
#include <math.h>

#define B_SZ    32
#define LSEQ    1024
#define DIN     128
#define HDIM    256
#define NLAYERS 4
#define NSTATE  32
#define DOUT    10
#define M_ROWS  (B_SZ*LSEQ)   // 32768
#define CH      64            // scan chunk length
#define NCH     (LSEQ/CH)     // 16 chunks
#define NBC     (B_SZ*NCH)    // 512 chunk-columns

typedef __hip_bfloat16 bf16;
typedef __attribute__((ext_vector_type(8))) short bf16x8;
typedef __attribute__((ext_vector_type(4))) float f32x4;

__device__ __forceinline__ unsigned short f2bu(float x) {
    bf16 b = __float2bfloat16(x);
    return *(unsigned short*)&b;
}

// ---------------- per-(layer,h,n) discretized params ----------------
__global__ void k_params(const float* __restrict__ log_dt, const float* __restrict__ A_re_log,
                         const float* __restrict__ A_im, const float* __restrict__ B_re,
                         const float* __restrict__ B_im, const float* __restrict__ C_re,
                         const float* __restrict__ C_im, float4* __restrict__ PWt,
                         float2* __restrict__ PA64) {
    int idx = blockIdx.x * 256 + threadIdx.x;       // layer*H*N + h*N + n
    int n = idx & 31, hn = idx >> 5;
    int h = hn & 255, layer = hn >> 8;
    float dt   = expf(log_dt[hn]);
    float Are  = -expf(A_re_log[idx]);
    float Aim  = A_im[idx];
    float dtAre = dt * Are, dtAim = dt * Aim;
    float ea   = expf(dtAre);
    float dAre = ea * cosf(dtAim), dAim = ea * sinf(dtAim);
    float nre = dAre - 1.0f, nim = dAim;            // dA - 1
    float inv = 1.0f / (Are * Are + Aim * Aim);
    float tre = (nre * Are + nim * Aim) * inv;      // (dA-1)/A
    float tim = (nim * Are - nre * Aim) * inv;
    float Brv = B_re[idx], Biv = B_im[idx];
    float dBre = Brv * tre - Biv * tim;
    float dBim = Brv * tim + Biv * tre;
    float Crv = C_re[idx], Civ = C_im[idx];
    float Wre = Crv * dBre - Civ * dBim;
    float Wim = Crv * dBim + Civ * dBre;
    int o = (layer * NSTATE + n) * HDIM + h;        // [layer][n][h]
    PWt[o] = make_float4(dAre, dAim, Wre, Wim);
    float e64 = expf(64.0f * dtAre);
    float ph  = 64.0f * dtAim;
    PA64[o] = make_float2(e64 * cosf(ph), e64 * sinf(ph));
}

// ---------------- Toeplitz kernel values: Td[lh][d] = 2 Re sum_n W dA^d, d=0..64 ----------------
__global__ void k_td(const float4* __restrict__ PWt, float* __restrict__ Td) {
    int lh = blockIdx.x * 256 + threadIdx.x;        // layer*256 + h
    int layer = lh >> 8, h = lh & 255;
    const float4* P = PWt + (size_t)layer * NSTATE * HDIM;
    float acc[65];
#pragma unroll
    for (int d = 0; d < 65; ++d) acc[d] = 0.f;
    for (int n = 0; n < NSTATE; ++n) {
        float4 q = P[n * HDIM + h];
        float zr = q.z, zi = q.w;                   // W * dA^0
#pragma unroll
        for (int d = 0; d < 65; ++d) {
            acc[d] += zr;
            float nzr = zr * q.x - zi * q.y;
            zi = zr * q.y + zi * q.x;
            zr = nzr;
        }
    }
    for (int d = 0; d < 65; ++d) Td[(size_t)lh * 66 + d] = 2.f * acc[d];
}

// ---------------- V/M matrices for one layer (bf16): V[h][comp][j], M[h][comp][l] ----------------
__global__ void k_vm(const float4* __restrict__ PW, bf16* __restrict__ Vg, bf16* __restrict__ Mg) {
    int idx = blockIdx.x * 256 + threadIdx.x;       // h*64 + comp
    int comp = idx & 63, h = idx >> 6;
    int n = comp >> 1, isIm = comp & 1;
    float4 q = PW[n * HDIM + h];
    float zr = q.z, zi = q.w;                       // W dA^0
    float wr = q.x, wi = q.y;                       // dA^1
    unsigned short vbuf[64], mbuf[64];
#pragma unroll
    for (int d = 0; d < 64; ++d) {
        vbuf[63 - d] = f2bu(isIm ? zi : zr);
        float nzr = zr * q.x - zi * q.y;
        zi = zr * q.y + zi * q.x;  zr = nzr;
        mbuf[d] = f2bu(isIm ? -2.f * wi : 2.f * wr);
        float nwr = wr * q.x - wi * q.y;
        wi = wr * q.y + wi * q.x;  wr = nwr;
    }
    unsigned int* Vrow = (unsigned int*)(Vg + (size_t)idx * 64);
    unsigned int* Mrow = (unsigned int*)(Mg + (size_t)idx * 64);
#pragma unroll
    for (int s = 0; s < 32; ++s) {
        Vrow[s] = (unsigned int)vbuf[2 * s] | ((unsigned int)vbuf[2 * s + 1] << 16);
        Mrow[s] = (unsigned int)mbuf[2 * s] | ((unsigned int)mbuf[2 * s + 1] << 16);
    }
}

// ---------------- one-off weight transpose+cast: Wt[layer][n(512)][k(256)] bf16 ----------------
__global__ void k_wcvt(const float* __restrict__ Wsrc, bf16* __restrict__ Wt) {
    int idx = blockIdx.x * 256 + threadIdx.x;   // ((layer*512)+n)*256+k
    int k = idx & 255;
    int n = (idx >> 8) & 511;
    int layer = idx >> 17;
    Wt[idx] = __float2bfloat16(Wsrc[((size_t)(layer * 256 + k)) * 512 + n]);
}

// ---------------- one-off encoder weight transpose+cast: Wet[n(256)][k(128)] bf16 ----------------
__global__ void k_wenc(const float* __restrict__ Wsrc, bf16* __restrict__ Wet) {
    int idx = blockIdx.x * 256 + threadIdx.x;   // n*128+k
    int k = idx & 127, n = idx >> 7;
    Wet[idx] = __float2bfloat16(Wsrc[(size_t)k * HDIM + n]);
}

// ---------------- transpose Yt bf16 [h][m] -> Y bf16 [m][h] ----------------
__global__ __launch_bounds__(256) void k_trY(const bf16* __restrict__ Yt, bf16* __restrict__ Y) {
    __shared__ bf16 t_s[64][72];
    int m0 = blockIdx.x * 64, h0 = blockIdx.y * 64;
    int tid = threadIdx.x;
#pragma unroll
    for (int i = 0; i < 2; ++i) {
        int q = tid + i * 256, row = q >> 3, seg = q & 7;
        uint4 v = *(const uint4*)&Yt[(size_t)(h0 + row) * M_ROWS + m0 + seg * 8];
        const bf16* pv = (const bf16*)&v;
#pragma unroll
        for (int e = 0; e < 8; ++e) t_s[seg * 8 + e][row] = pv[e];
    }
    __syncthreads();
#pragma unroll
    for (int i = 0; i < 2; ++i) {
        int q = tid + i * 256, row = q >> 3, seg = q & 7;
        *(uint4*)&Y[(size_t)(m0 + row) * HDIM + h0 + seg * 8] = *(uint4*)&t_s[row][seg * 8];
    }
}

// ---------------- encoder GEMM (bf16 MFMA): H = X@We + b, + transposed Ut output ----------------
__global__ __launch_bounds__(256) void k_enc2(const float* __restrict__ X, const bf16* __restrict__ Wet,
                                              const float* __restrict__ bias, float* __restrict__ H,
                                              bf16* __restrict__ Ut) {
    __shared__ bf16 A_s[128 * 136];
    __shared__ bf16 B_s[64 * 136];
    int tid = threadIdx.x;
    int lane = tid & 63, wv = tid >> 6, quad = lane >> 4, fr = lane & 15;
    int m0 = blockIdx.x * 128, n0 = blockIdx.y * 64;
#pragma unroll
    for (int i = 0; i < 16; ++i) {               // stage X fp32 -> bf16 [m][k]
        int q = tid + i * 256, row = q >> 5, seg = q & 31;
        float4 v = *(const float4*)&X[(size_t)(m0 + row) * DIN + seg * 4];
        bf16* dst = &A_s[row * 136 + seg * 4];
        dst[0] = __float2bfloat16(v.x); dst[1] = __float2bfloat16(v.y);
        dst[2] = __float2bfloat16(v.z); dst[3] = __float2bfloat16(v.w);
    }
#pragma unroll
    for (int i = 0; i < 4; ++i) {                // stage Wet [n][k]
        int q = tid + i * 256, row = q >> 4, seg = q & 15;
        *(uint4*)&B_s[row * 136 + seg * 8] = *(const uint4*)&Wet[(size_t)(n0 + row) * DIN + seg * 8];
    }
    __syncthreads();
    f32x4 acc[2][4];
#pragma unroll
    for (int mt = 0; mt < 2; ++mt)
#pragma unroll
        for (int nt = 0; nt < 4; ++nt) acc[mt][nt] = (f32x4){0.f, 0.f, 0.f, 0.f};
#pragma unroll
    for (int ks = 0; ks < 4; ++ks) {
        bf16x8 a[2], b[4];
#pragma unroll
        for (int mt = 0; mt < 2; ++mt)
            a[mt] = *(const bf16x8*)&A_s[(wv * 32 + mt * 16 + fr) * 136 + ks * 32 + quad * 8];
#pragma unroll
        for (int nt = 0; nt < 4; ++nt)
            b[nt] = *(const bf16x8*)&B_s[(nt * 16 + fr) * 136 + ks * 32 + quad * 8];
#pragma unroll
        for (int mt = 0; mt < 2; ++mt)
#pragma unroll
            for (int nt = 0; nt < 4; ++nt)
                acc[mt][nt] = __builtin_amdgcn_mfma_f32_16x16x32_bf16(a[mt], b[nt], acc[mt][nt], 0, 0, 0);
    }
    __syncthreads();                             // B_s reuse as transpose bounce
#pragma unroll
    for (int mt = 0; mt < 2; ++mt)
#pragma unroll
        for (int nt = 0; nt < 4; ++nt) {
            int n = n0 + nt * 16 + fr;
            float bv = bias[n];
#pragma unroll
            for (int r = 0; r < 4; ++r) {
                int m = m0 + wv * 32 + mt * 16 + quad * 4 + r;
                float hv = acc[mt][nt][r] + bv;
                H[(size_t)m * HDIM + n] = hv;
                B_s[(nt * 16 + fr) * 136 + (wv * 32 + mt * 16 + quad * 4 + r)] = __float2bfloat16(hv);
            }
        }
    __syncthreads();
#pragma unroll
    for (int i = 0; i < 4; ++i) {                // coalesced Ut store [h][m]
        int q = tid + i * 256, row = q >> 4, seg = q & 15;
        *(uint4*)&Ut[(size_t)(n0 + row) * M_ROWS + m0 + seg * 8] = *(uint4*)&B_s[row * 136 + seg * 8];
    }
}

// ---------------- conv phase A (MFMA): E[h][comp][bc] = V_h @ u ----------------
__global__ __launch_bounds__(256) void k_convA(const bf16* __restrict__ Ut,
                                               const bf16* __restrict__ Vg,
                                               float* __restrict__ E) {
    __shared__ bf16 V_s[64 * 72];
    __shared__ bf16 u_s[128 * 72];
    __shared__ float o_s[64 * 132];
    int h = blockIdx.x, bc0 = blockIdx.y * 128;
    int tid = threadIdx.x;
    int lane = tid & 63, wv = tid >> 6, quad = lane >> 4, fr = lane & 15;
#pragma unroll
    for (int i = 0; i < 2; ++i) {                // stage V from global
        int q = tid + i * 256, row = q >> 3, seg = q & 7;
        *(uint4*)&V_s[row * 72 + seg * 8] =
            *(const uint4*)&Vg[((size_t)h * 64 + row) * 64 + seg * 8];
    }
#pragma unroll
    for (int i = 0; i < 4; ++i) {                // stage u tile [bc][j]
        int q = tid + i * 256, row = q >> 3, c8 = q & 7;
        *(uint4*)&u_s[row * 72 + c8 * 8] =
            *(const uint4*)&Ut[(size_t)h * M_ROWS + (size_t)(bc0 + row) * 64 + c8 * 8];
    }
    __syncthreads();
    f32x4 acc[4][2];
#pragma unroll
    for (int mt = 0; mt < 4; ++mt)
#pragma unroll
        for (int nf = 0; nf < 2; ++nf) acc[mt][nf] = (f32x4){0.f, 0.f, 0.f, 0.f};
#pragma unroll
    for (int ks = 0; ks < 2; ++ks) {
        bf16x8 a[4], b[2];
#pragma unroll
        for (int mt = 0; mt < 4; ++mt)
            a[mt] = *(const bf16x8*)&V_s[(mt * 16 + fr) * 72 + ks * 32 + quad * 8];
#pragma unroll
        for (int nf = 0; nf < 2; ++nf)
            b[nf] = *(const bf16x8*)&u_s[(wv * 32 + nf * 16 + fr) * 72 + ks * 32 + quad * 8];
#pragma unroll
        for (int mt = 0; mt < 4; ++mt)
#pragma unroll
            for (int nf = 0; nf < 2; ++nf)
                acc[mt][nf] = __builtin_amdgcn_mfma_f32_16x16x32_bf16(a[mt], b[nf], acc[mt][nf], 0, 0, 0);
    }
#pragma unroll
    for (int mt = 0; mt < 4; ++mt)
#pragma unroll
        for (int nf = 0; nf < 2; ++nf)
#pragma unroll
            for (int r = 0; r < 4; ++r)
                o_s[(mt * 16 + quad * 4 + r) * 132 + wv * 32 + nf * 16 + fr] = acc[mt][nf][r];
    __syncthreads();
#pragma unroll
    for (int i = 0; i < 32; ++i) {               // coalesced E store
        int q = tid + i * 256, comp = q >> 7, bcl = q & 127;
        E[((size_t)h * 64 + comp) * NBC + bc0 + bcl] = o_s[comp * 132 + bcl];
    }
}

// ---------------- conv phase C (MFMA) + in-block carry scan ----------------
// grid (HDIM, NBC/128): a 128-bc tile = 8 complete batches (8*NCH) -> carry chains fit in-block
__global__ __launch_bounds__(256) void k_convC(const bf16* __restrict__ Ut,
                                               const float* __restrict__ E,
                                               const float* __restrict__ Tdl,
                                               const bf16* __restrict__ Mg,
                                               const float2* __restrict__ PA,
                                               const float* __restrict__ Dw,
                                               bf16* __restrict__ Yt) {
    __shared__ bf16 A_s[64 * 136];               // [l][k2], k2<64: T, k2>=64: M
    __shared__ bf16 u_s[128 * 72];
    __shared__ bf16 c_s[128 * 72];
    __shared__ bf16 o_s[128 * 72];
    __shared__ float Td_s[65];
    int h = blockIdx.x, bc0 = blockIdx.y * 128;
    int tid = threadIdx.x;
    int lane = tid & 63, wv = tid >> 6, quad = lane >> 4, fr = lane & 15;
    if (tid < 65) Td_s[tid] = Tdl[(size_t)h * 66 + tid];
#pragma unroll
    for (int i = 0; i < 2; ++i) {                // stage M from global (transposed into A_s)
        int q = tid + i * 256, comp = q >> 3, seg = q & 7;
        uint4 v = *(const uint4*)&Mg[((size_t)h * 64 + comp) * 64 + seg * 8];
        const bf16* pv = (const bf16*)&v;
#pragma unroll
        for (int e = 0; e < 8; ++e) A_s[(seg * 8 + e) * 136 + 64 + comp] = pv[e];
    }
#pragma unroll
    for (int i = 0; i < 4; ++i) {                // stage u tile
        int q = tid + i * 256, row = q >> 3, c8 = q & 7;
        *(uint4*)&u_s[row * 72 + c8 * 8] =
            *(const uint4*)&Ut[(size_t)h * M_ROWS + (size_t)(bc0 + row) * 64 + c8 * 8];
    }
    {                                            // in-block carry scan: thread = (b_local, n)
        int bl = tid >> 5, n = tid & 31;
        float2 a = PA[n * HDIM + h];
        const float* Er = E + ((size_t)h * 64 + 2 * n) * NBC + bc0 + bl * NCH;
        const float* Ei = Er + NBC;
        float er[NCH], ei[NCH];
#pragma unroll
        for (int s = 0; s < 4; ++s) {
            *(float4*)&er[s * 4] = *(const float4*)&Er[s * 4];
            *(float4*)&ei[s * 4] = *(const float4*)&Ei[s * 4];
        }
        float cr = 0.f, ci = 0.f;
#pragma unroll
        for (int c = 0; c < NCH; ++c) {
            *(unsigned int*)&c_s[(bl * NCH + c) * 72 + 2 * n] =
                (unsigned int)f2bu(cr) | ((unsigned int)f2bu(ci) << 16);
            float nr = fmaf(a.x, cr, fmaf(-a.y, ci, er[c]));
            ci = fmaf(a.x, ci, fmaf(a.y, cr, ei[c]));
            cr = nr;
        }
    }
    __syncthreads();                             // Td_s + staging + carries ready
#pragma unroll
    for (int i = 0; i < 16; ++i) {               // Toeplitz T fill
        int q = tid + i * 256, l = q >> 6, j = q & 63, d = l - j;
        A_s[l * 136 + j] = __float2bfloat16(d >= 0 ? Td_s[d] : 0.f);
    }
    __syncthreads();
    f32x4 acc[4][2];
#pragma unroll
    for (int mt = 0; mt < 4; ++mt)
#pragma unroll
        for (int nf = 0; nf < 2; ++nf) acc[mt][nf] = (f32x4){0.f, 0.f, 0.f, 0.f};
#pragma unroll
    for (int ks = 0; ks < 4; ++ks) {
        bf16x8 a[4], b[2];
#pragma unroll
        for (int mt = 0; mt < 4; ++mt)
            a[mt] = *(const bf16x8*)&A_s[(mt * 16 + fr) * 136 + ks * 32 + quad * 8];
#pragma unroll
        for (int nf = 0; nf < 2; ++nf) {
            int row = (wv * 32 + nf * 16 + fr) * 72;
            b[nf] = (ks < 2) ? *(const bf16x8*)&u_s[row + ks * 32 + quad * 8]
                             : *(const bf16x8*)&c_s[row + (ks - 2) * 32 + quad * 8];
        }
#pragma unroll
        for (int mt = 0; mt < 4; ++mt)
#pragma unroll
            for (int nf = 0; nf < 2; ++nf)
                acc[mt][nf] = __builtin_amdgcn_mfma_f32_16x16x32_bf16(a[mt], b[nf], acc[mt][nf], 0, 0, 0);
    }
    float Dv = Dw[h];
#pragma unroll
    for (int mt = 0; mt < 4; ++mt)
#pragma unroll
        for (int nf = 0; nf < 2; ++nf) {
            int bcl = wv * 32 + nf * 16 + fr;
#pragma unroll
            for (int r = 0; r < 4; ++r) {
                int l = mt * 16 + quad * 4 + r;
                float u = __bfloat162float(u_s[bcl * 72 + l]);
                float v = fmaf(Dv, u, acc[mt][nf][r]);
                float z2 = 1.5957691216057308f * (v + 0.044715f * v * v * v);
                o_s[bcl * 72 + l] = __float2bfloat16(v / (1.f + __expf(-z2)));
            }
        }
    __syncthreads();
#pragma unroll
    for (int i = 0; i < 4; ++i) {                // coalesced Yt store
        int q = tid + i * 256, row = q >> 3, c8 = q & 7;
        *(uint4*)&Yt[(size_t)h * M_ROWS + (size_t)(bc0 + row) * 64 + c8 * 8] =
            *(uint4*)&o_s[row * 72 + c8 * 8];
    }
}

// ---------------- output GEMM + fused GLU, bf16 MFMA, bf16 G out ----------------
__global__ __launch_bounds__(256) void k_glu(const bf16* __restrict__ Ybf,
                                             const bf16* __restrict__ Wt,
                                             const float* __restrict__ wb,
                                             bf16* __restrict__ G) {
    __shared__ short A_s[128 * 72];
    __shared__ short B1_s[64 * 72];
    __shared__ short B2_s[64 * 72];
    int tid = threadIdx.x;
    int lane = tid & 63, wv = tid >> 6;
    int quad = lane >> 4, fr = lane & 15;
    int m0 = blockIdx.x * 128, n0 = blockIdx.y * 64;
    f32x4 acc1[2][4], acc2[2][4];
#pragma unroll
    for (int mt = 0; mt < 2; ++mt)
#pragma unroll
        for (int nt = 0; nt < 4; ++nt) {
            acc1[mt][nt] = (f32x4){0.f,0.f,0.f,0.f};
            acc2[mt][nt] = (f32x4){0.f,0.f,0.f,0.f};
        }
    for (int kt = 0; kt < HDIM; kt += 64) {
#pragma unroll
        for (int i = 0; i < 4; ++i) {
            int e = tid + i * 256, row = e >> 3, cm = e & 7;
            *(uint4*)&A_s[row * 72 + cm * 8] =
                *(const uint4*)(Ybf + (size_t)(m0 + row) * HDIM + kt + cm * 8);
        }
#pragma unroll
        for (int i = 0; i < 2; ++i) {
            int e = tid + i * 256, row = e >> 3, cm = e & 7;
            *(uint4*)&B1_s[row * 72 + cm * 8] =
                *(const uint4*)(Wt + (size_t)(n0 + row) * HDIM + kt + cm * 8);
            *(uint4*)&B2_s[row * 72 + cm * 8] =
                *(const uint4*)(Wt + (size_t)(256 + n0 + row) * HDIM + kt + cm * 8);
        }
        __syncthreads();
#pragma unroll
        for (int s = 0; s < 2; ++s) {
            bf16x8 a[2], b1[4], b2[4];
#pragma unroll
            for (int mt = 0; mt < 2; ++mt)
                a[mt] = *(const bf16x8*)&A_s[(wv * 32 + mt * 16 + fr) * 72 + s * 32 + quad * 8];
#pragma unroll
            for (int nt = 0; nt < 4; ++nt) {
                b1[nt] = *(const bf16x8*)&B1_s[(nt * 16 + fr) * 72 + s * 32 + quad * 8];
                b2[nt] = *(const bf16x8*)&B2_s[(nt * 16 + fr) * 72 + s * 32 + quad * 8];
            }
#pragma unroll
            for (int mt = 0; mt < 2; ++mt)
#pragma unroll
                for (int nt = 0; nt < 4; ++nt) {
                    acc1[mt][nt] = __builtin_amdgcn_mfma_f32_16x16x32_bf16(a[mt], b1[nt], acc1[mt][nt], 0, 0, 0);
                    acc2[mt][nt] = __builtin_amdgcn_mfma_f32_16x16x32_bf16(a[mt], b2[nt], acc2[mt][nt], 0, 0, 0);
                }
        }
        __syncthreads();
    }
#pragma unroll
    for (int mt = 0; mt < 2; ++mt)
#pragma unroll
        for (int nt = 0; nt < 4; ++nt) {
            int n = n0 + nt * 16 + fr;
            float b1v = wb[n], b2v = wb[HDIM + n];
#pragma unroll
            for (int r = 0; r < 4; ++r) {
                int m = m0 + wv * 32 + mt * 16 + quad * 4 + r;
                float z1 = acc1[mt][nt][r] + b1v;
                float z2 = acc2[mt][nt][r] + b2v;
                G[(size_t)m * HDIM + n] = __float2bfloat16(z1 / (1.0f + __expf(-z2)));
            }
        }
}

// ---------------- residual + LayerNorm, 64-row tiles, fused transposed Ut emit ----------------
// grid M_ROWS/64, block 256 (thread = (row r = tid&63, h-quarter qd = tid>>6))
__global__ __launch_bounds__(256) void k_ln2(const bf16* __restrict__ G, float* __restrict__ Hb,
                                             const float* __restrict__ w, const float* __restrict__ bb,
                                             bf16* __restrict__ Ut, int writeUt) {
    __shared__ bf16 t_s[256][72];
    __shared__ float red[2][4][64];
    __shared__ float stat[2][64];
    __shared__ float w_s[256], b_s[256];
    int m0 = blockIdx.x * 64;
    int tid = threadIdx.x;
    int r = tid & 63, qd = tid >> 6;
    w_s[tid] = w[tid]; b_s[tid] = bb[tid];
    const bf16* Gp = G + (size_t)(m0 + r) * HDIM + qd * 64;
    float*      Hp = Hb + (size_t)(m0 + r) * HDIM + qd * 64;
    float rv[64];
    float sum = 0.f, sq = 0.f;
#pragma unroll
    for (int j = 0; j < 64; j += 8) {
        uint4 gv = *(const uint4*)&Gp[j];
        const bf16* gp = (const bf16*)&gv;
        float4 h0 = *(const float4*)&Hp[j];
        float4 h1 = *(const float4*)&Hp[j + 4];
        float hv[8] = {h0.x, h0.y, h0.z, h0.w, h1.x, h1.y, h1.z, h1.w};
#pragma unroll
        for (int e = 0; e < 8; ++e) {
            float v = __bfloat162float(gp[e]) + hv[e];
            rv[j + e] = v; sum += v; sq += v * v;
        }
    }
    red[0][qd][r] = sum; red[1][qd][r] = sq;
    __syncthreads();
    if (tid < 64) {
        float s  = red[0][0][tid] + red[0][1][tid] + red[0][2][tid] + red[0][3][tid];
        float s2 = red[1][0][tid] + red[1][1][tid] + red[1][2][tid] + red[1][3][tid];
        float mean = s * (1.f / HDIM);
        float var = s2 * (1.f / HDIM) - mean * mean;
        stat[0][tid] = mean; stat[1][tid] = rsqrtf(var + 1e-5f);
    }
    __syncthreads();
    float mean = stat[0][r], rstd = stat[1][r];
#pragma unroll
    for (int j = 0; j < 64; ++j)
        rv[j] = (rv[j] - mean) * rstd * w_s[qd * 64 + j] + b_s[qd * 64 + j];
#pragma unroll
    for (int j = 0; j < 64; j += 4)
        *(float4*)&Hp[j] = make_float4(rv[j], rv[j + 1], rv[j + 2], rv[j + 3]);
    if (writeUt) {
#pragma unroll
        for (int j = 0; j < 64; ++j) t_s[qd * 64 + j][r] = __float2bfloat16(rv[j]);
        __syncthreads();
#pragma unroll
        for (int i = 0; i < 8; ++i) {            // coalesced Ut store: 256 h rows x 64 m
            int q = tid + i * 256, hh = q >> 3, seg = q & 7;
            *(uint4*)&Ut[(size_t)hh * M_ROWS + m0 + seg * 8] = *(uint4*)&t_s[hh][seg * 8];
        }
    }
}

// ---------------- decoder ----------------
__global__ void k_dec(const float* __restrict__ Hb, const float* __restrict__ dw,
                      const float* __restrict__ db, float* __restrict__ out) {
    __shared__ float ws[HDIM * DOUT];
    int tid = threadIdx.x;                    // 320 threads
    for (int e = tid; e < HDIM * DOUT; e += 320) ws[e] = dw[e];
    __syncthreads();
    int r = tid / DOUT, o = tid - r * DOUT;
    int row = blockIdx.x * 32 + r;
    float acc = db[o];
    const float* hp = Hb + (size_t)row * HDIM;
#pragma unroll 8
    for (int k = 0; k < HDIM; ++k) acc = fmaf(hp[k], ws[k * DOUT + o], acc);
    out[row * DOUT + o] = acc;
}

extern "C" void kernel_launch(void* const* d_in, const int* in_sizes, int n_in,
                              void* d_out, int out_size, void* d_ws, size_t ws_size,
                              hipStream_t stream) {
    const float* x        = (const float*)d_in[0];
    const float* enc_w    = (const float*)d_in[1];
    const float* enc_b    = (const float*)d_in[2];
    const float* log_dt   = (const float*)d_in[3];
    const float* A_re_log = (const float*)d_in[4];
    const float* A_im     = (const float*)d_in[5];
    const float* B_re     = (const float*)d_in[6];
    const float* B_im     = (const float*)d_in[7];
    const float* C_re     = (const float*)d_in[8];
    const float* C_im     = (const float*)d_in[9];
    const float* Dp       = (const float*)d_in[10];
    const float* ln_w     = (const float*)d_in[11];
    const float* ln_b     = (const float*)d_in[12];
    const float* out_w    = (const float*)d_in[13];
    const float* out_b    = (const float*)d_in[14];
    const float* dec_w    = (const float*)d_in[15];
    const float* dec_b    = (const float*)d_in[16];
    float* outp = (float*)d_out;

    float* w = (float*)d_ws;
    const size_t PWE = (size_t)NLAYERS * NSTATE * HDIM;   // 32768
    const size_t MH  = (size_t)M_ROWS * HDIM;             // 8388608
    float4* PWt  = (float4*)w;                            // 512 KB
    float2* PA64 = (float2*)(w + 4 * PWE);                // 256 KB
    float*  Td   = w + 6 * PWE;                           // 270 KB
    float*  Hbuf = Td + (size_t)NLAYERS * HDIM * 66;      // 33.5 MB fp32
    float*  E    = Hbuf + MH;                             // 33.5 MB fp32 (dedicated)
    bf16*   R4   = (bf16*)(E + MH);                       // 16.7 MB: Yt then G
    bf16*   R3   = R4 + MH;                               // 16.7 MB: Ut then Ybf
    bf16*   Wt   = R3 + MH;                               // 1 MB
    bf16*   Wet  = Wt + (size_t)NLAYERS * 512 * HDIM;     // 64 KB
    bf16*   Vg   = Wet + (size_t)HDIM * DIN;              // 2 MB (per-layer reuse)
    bf16*   Mg   = Vg + (size_t)HDIM * 64 * 64;           // 2 MB
    bf16*   Yt  = R4;
    bf16*   G   = R4;
    bf16*   Ut  = R3;
    bf16*   Ybf = R3;

    k_params<<<NLAYERS * HDIM * NSTATE / 256, 256, 0, stream>>>(log_dt, A_re_log, A_im,
                                                                B_re, B_im, C_re, C_im, PWt, PA64);
    k_td<<<NLAYERS, 256, 0, stream>>>(PWt, Td);
    k_wcvt<<<NLAYERS * 512 * 256 / 256, 256, 0, stream>>>(out_w, Wt);
    k_wenc<<<HDIM * DIN / 256, 256, 0, stream>>>(enc_w, Wet);

    dim3 ge(M_ROWS / 128, HDIM / 64);
    k_enc2<<<ge, 256, 0, stream>>>(x, Wet, enc_b, Hbuf, Ut);

    dim3 gtr(M_ROWS / 64, HDIM / 64);
    dim3 gconv(HDIM, NBC / 128);
    dim3 gg(M_ROWS / 128, HDIM / 64);

    for (int layer = 0; layer < NLAYERS; ++layer) {
        const float4* pwl = PWt + (size_t)layer * NSTATE * HDIM;
        const float2* pal = PA64 + (size_t)layer * NSTATE * HDIM;
        const float*  tdl = Td + (size_t)layer * HDIM * 66;
        k_vm<<<HDIM * 64 / 256, 256, 0, stream>>>(pwl, Vg, Mg);
        k_convA<<<gconv, 256, 0, stream>>>(Ut, Vg, E);
        k_convC<<<gconv, 256, 0, stream>>>(Ut, E, tdl, Mg, pal, Dp + layer * HDIM, Yt);
        k_trY<<<gtr, 256, 0, stream>>>(Yt, Ybf);
        k_glu<<<gg, 256, 0, stream>>>(Ybf, Wt + (size_t)layer * 512 * HDIM,
                                      out_b + layer * 2 * HDIM, G);
        k_ln2<<<M_ROWS / 64, 256, 0, stream>>>(G, Hbuf, ln_w + layer * HDIM,
                                               ln_b + layer * HDIM, Ut,
                                               layer < NLAYERS - 1 ? 1 : 0);
    }
    k_dec<<<M_ROWS / 32, 320, 0, stream>>>(Hbuf, dec_w, dec_b, outp);
}

// Round 13
// 491.363 us; speedup vs baseline: 5.8875x; 1.1114x over previous
//
#include <hip/hip_runtime.h>
#include <hip/hip_bf16.h>
#include <math.h>

#define B_SZ    32
#define LSEQ    1024
#define DIN     128
#define HDIM    256
#define NLAYERS 4
#define NSTATE  32
#define DOUT    10
#define M_ROWS  (B_SZ*LSEQ)   // 32768
#define CH      64            // scan chunk length
#define NCH     (LSEQ/CH)     // 16 chunks
#define NBC     (B_SZ*NCH)    // 512 chunk-columns

typedef __hip_bfloat16 bf16;
typedef __attribute__((ext_vector_type(8))) short bf16x8;
typedef __attribute__((ext_vector_type(4))) float f32x4;

__device__ __forceinline__ unsigned short f2bu(float x) {
    bf16 b = __float2bfloat16(x);
    return *(unsigned short*)&b;
}
__device__ __forceinline__ float bu2f(unsigned short u) {
    bf16 b = *(bf16*)&u;
    return __bfloat162float(b);
}

// ---------------- per-(layer,h,n) discretized params ----------------
__global__ void k_params(const float* __restrict__ log_dt, const float* __restrict__ A_re_log,
                         const float* __restrict__ A_im, const float* __restrict__ B_re,
                         const float* __restrict__ B_im, const float* __restrict__ C_re,
                         const float* __restrict__ C_im, float4* __restrict__ PWt,
                         float2* __restrict__ PA64) {
    int idx = blockIdx.x * 256 + threadIdx.x;       // layer*H*N + h*N + n
    int n = idx & 31, hn = idx >> 5;
    int h = hn & 255, layer = hn >> 8;
    float dt   = expf(log_dt[hn]);
    float Are  = -expf(A_re_log[idx]);
    float Aim  = A_im[idx];
    float dtAre = dt * Are, dtAim = dt * Aim;
    float ea   = expf(dtAre);
    float dAre = ea * cosf(dtAim), dAim = ea * sinf(dtAim);
    float nre = dAre - 1.0f, nim = dAim;            // dA - 1
    float inv = 1.0f / (Are * Are + Aim * Aim);
    float tre = (nre * Are + nim * Aim) * inv;      // (dA-1)/A
    float tim = (nim * Are - nre * Aim) * inv;
    float Brv = B_re[idx], Biv = B_im[idx];
    float dBre = Brv * tre - Biv * tim;
    float dBim = Brv * tim + Biv * tre;
    float Crv = C_re[idx], Civ = C_im[idx];
    float Wre = Crv * dBre - Civ * dBim;
    float Wim = Crv * dBim + Civ * dBre;
    int o = (layer * NSTATE + n) * HDIM + h;        // [layer][n][h]
    PWt[o] = make_float4(dAre, dAim, Wre, Wim);
    float e64 = expf(64.0f * dtAre);
    float ph  = 64.0f * dtAim;
    PA64[o] = make_float2(e64 * cosf(ph), e64 * sinf(ph));
}

// ---------------- Toeplitz kernel values: Td[lh][d] = 2 Re sum_n W dA^d, d=0..64 ----------------
__global__ void k_td(const float4* __restrict__ PWt, float* __restrict__ Td) {
    int lh = blockIdx.x * 256 + threadIdx.x;        // layer*256 + h
    int layer = lh >> 8, h = lh & 255;
    const float4* P = PWt + (size_t)layer * NSTATE * HDIM;
    float acc[65];
#pragma unroll
    for (int d = 0; d < 65; ++d) acc[d] = 0.f;
    for (int n = 0; n < NSTATE; ++n) {
        float4 q = P[n * HDIM + h];
        float zr = q.z, zi = q.w;                   // W * dA^0
#pragma unroll
        for (int d = 0; d < 65; ++d) {
            acc[d] += zr;
            float nzr = zr * q.x - zi * q.y;
            zi = zr * q.y + zi * q.x;
            zr = nzr;
        }
    }
    for (int d = 0; d < 65; ++d) Td[(size_t)lh * 66 + d] = 2.f * acc[d];
}

// ---------------- V/M matrices, ALL layers (bf16): V[layer][h][comp][j], M likewise ----------------
// V[2n][j]=Re(W dA^(63-j)), V[2n+1][j]=Im; M[2n][l]=2Re(dA^(l+1)), M[2n+1][l]=-2Im
__global__ void k_vm(const float4* __restrict__ PWt, bf16* __restrict__ Vg, bf16* __restrict__ Mg) {
    int idx = blockIdx.x * 256 + threadIdx.x;       // ((layer*256+h)*64)+comp
    int comp = idx & 63, h = (idx >> 6) & 255, layer = idx >> 14;
    int n = comp >> 1, isIm = comp & 1;
    float4 q = PWt[((size_t)layer * NSTATE + n) * HDIM + h];
    float zr = q.z, zi = q.w;                       // W dA^0
    float wr = q.x, wi = q.y;                       // dA^1
    unsigned short vbuf[64], mbuf[64];
#pragma unroll
    for (int d = 0; d < 64; ++d) {
        vbuf[63 - d] = f2bu(isIm ? zi : zr);
        float nzr = zr * q.x - zi * q.y;
        zi = zr * q.y + zi * q.x;  zr = nzr;
        mbuf[d] = f2bu(isIm ? -2.f * wi : 2.f * wr);
        float nwr = wr * q.x - wi * q.y;
        wi = wr * q.y + wi * q.x;  wr = nwr;
    }
    unsigned int* Vrow = (unsigned int*)(Vg + (size_t)idx * 64);
    unsigned int* Mrow = (unsigned int*)(Mg + (size_t)idx * 64);
#pragma unroll
    for (int s = 0; s < 32; ++s) {
        Vrow[s] = (unsigned int)vbuf[2 * s] | ((unsigned int)vbuf[2 * s + 1] << 16);
        Mrow[s] = (unsigned int)mbuf[2 * s] | ((unsigned int)mbuf[2 * s + 1] << 16);
    }
}

// ---------------- one-off weight transpose+cast: Wt[layer][n(512)][k(256)] bf16 ----------------
__global__ void k_wcvt(const float* __restrict__ Wsrc, bf16* __restrict__ Wt) {
    int idx = blockIdx.x * 256 + threadIdx.x;   // ((layer*512)+n)*256+k
    int k = idx & 255;
    int n = (idx >> 8) & 511;
    int layer = idx >> 17;
    Wt[idx] = __float2bfloat16(Wsrc[((size_t)(layer * 256 + k)) * 512 + n]);
}

// ---------------- one-off encoder weight transpose+cast: Wet[n(256)][k(128)] bf16 ----------------
__global__ void k_wenc(const float* __restrict__ Wsrc, bf16* __restrict__ Wet) {
    int idx = blockIdx.x * 256 + threadIdx.x;   // n*128+k
    int k = idx & 127, n = idx >> 7;
    Wet[idx] = __float2bfloat16(Wsrc[(size_t)k * HDIM + n]);
}

// ---------------- transpose Yt bf16 [h][m] -> Y bf16 [m][h] ----------------
__global__ __launch_bounds__(256) void k_trY(const bf16* __restrict__ Yt, bf16* __restrict__ Y) {
    __shared__ bf16 t_s[64][72];
    int m0 = blockIdx.x * 64, h0 = blockIdx.y * 64;
    int tid = threadIdx.x;
#pragma unroll
    for (int i = 0; i < 2; ++i) {
        int q = tid + i * 256, row = q >> 3, seg = q & 7;
        uint4 v = *(const uint4*)&Yt[(size_t)(h0 + row) * M_ROWS + m0 + seg * 8];
        const bf16* pv = (const bf16*)&v;
#pragma unroll
        for (int e = 0; e < 8; ++e) t_s[seg * 8 + e][row] = pv[e];
    }
    __syncthreads();
#pragma unroll
    for (int i = 0; i < 2; ++i) {
        int q = tid + i * 256, row = q >> 3, seg = q & 7;
        *(uint4*)&Y[(size_t)(m0 + row) * HDIM + h0 + seg * 8] = *(uint4*)&t_s[row][seg * 8];
    }
}

// ---------------- encoder GEMM (bf16 MFMA): H = X@We + b, + transposed Ut output ----------------
__global__ __launch_bounds__(256) void k_enc2(const float* __restrict__ X, const bf16* __restrict__ Wet,
                                              const float* __restrict__ bias, float* __restrict__ H,
                                              bf16* __restrict__ Ut) {
    __shared__ bf16 A_s[128 * 136];
    __shared__ bf16 B_s[64 * 136];
    int tid = threadIdx.x;
    int lane = tid & 63, wv = tid >> 6, quad = lane >> 4, fr = lane & 15;
    int m0 = blockIdx.x * 128, n0 = blockIdx.y * 64;
#pragma unroll
    for (int i = 0; i < 16; ++i) {               // stage X fp32 -> bf16 [m][k]
        int q = tid + i * 256, row = q >> 5, seg = q & 31;
        float4 v = *(const float4*)&X[(size_t)(m0 + row) * DIN + seg * 4];
        bf16* dst = &A_s[row * 136 + seg * 4];
        dst[0] = __float2bfloat16(v.x); dst[1] = __float2bfloat16(v.y);
        dst[2] = __float2bfloat16(v.z); dst[3] = __float2bfloat16(v.w);
    }
#pragma unroll
    for (int i = 0; i < 4; ++i) {                // stage Wet [n][k]
        int q = tid + i * 256, row = q >> 4, seg = q & 15;
        *(uint4*)&B_s[row * 136 + seg * 8] = *(const uint4*)&Wet[(size_t)(n0 + row) * DIN + seg * 8];
    }
    __syncthreads();
    f32x4 acc[2][4];
#pragma unroll
    for (int mt = 0; mt < 2; ++mt)
#pragma unroll
        for (int nt = 0; nt < 4; ++nt) acc[mt][nt] = (f32x4){0.f, 0.f, 0.f, 0.f};
#pragma unroll
    for (int ks = 0; ks < 4; ++ks) {
        bf16x8 a[2], b[4];
#pragma unroll
        for (int mt = 0; mt < 2; ++mt)
            a[mt] = *(const bf16x8*)&A_s[(wv * 32 + mt * 16 + fr) * 136 + ks * 32 + quad * 8];
#pragma unroll
        for (int nt = 0; nt < 4; ++nt)
            b[nt] = *(const bf16x8*)&B_s[(nt * 16 + fr) * 136 + ks * 32 + quad * 8];
#pragma unroll
        for (int mt = 0; mt < 2; ++mt)
#pragma unroll
            for (int nt = 0; nt < 4; ++nt)
                acc[mt][nt] = __builtin_amdgcn_mfma_f32_16x16x32_bf16(a[mt], b[nt], acc[mt][nt], 0, 0, 0);
    }
    __syncthreads();                             // B_s reuse as transpose bounce
#pragma unroll
    for (int mt = 0; mt < 2; ++mt)
#pragma unroll
        for (int nt = 0; nt < 4; ++nt) {
            int n = n0 + nt * 16 + fr;
            float bv = bias[n];
#pragma unroll
            for (int r = 0; r < 4; ++r) {
                int m = m0 + wv * 32 + mt * 16 + quad * 4 + r;
                float hv = acc[mt][nt][r] + bv;
                H[(size_t)m * HDIM + n] = hv;
                B_s[(nt * 16 + fr) * 136 + (wv * 32 + mt * 16 + quad * 4 + r)] = __float2bfloat16(hv);
            }
        }
    __syncthreads();
#pragma unroll
    for (int i = 0; i < 4; ++i) {                // coalesced Ut store [h][m]
        int q = tid + i * 256, row = q >> 4, seg = q & 15;
        *(uint4*)&Ut[(size_t)(n0 + row) * M_ROWS + m0 + seg * 8] = *(uint4*)&B_s[row * 136 + seg * 8];
    }
}

// ---------------- fused conv: E-MFMA + in-LDS carry scan + T|M-MFMA + GELU ----------------
// grid (HDIM, NBC/128): a 128-bc tile = 8 complete batches; E never leaves LDS
__global__ __launch_bounds__(256) void k_conv(const bf16* __restrict__ Ut,
                                              const bf16* __restrict__ Vg,
                                              const bf16* __restrict__ Mg,
                                              const float* __restrict__ Tdl,
                                              const float2* __restrict__ PA,
                                              const float* __restrict__ Dw,
                                              bf16* __restrict__ Yt) {
    __shared__ bf16 u_s[128 * 72];               // [bc][j]
    __shared__ bf16 A_s[64 * 136];               // [l][k2], k2<64: T, k2>=64: M
    __shared__ bf16 Eo_s[128 * 72];              // [bc][comp] E bounce; reused as o_s
    __shared__ bf16 c_s[128 * 72];               // [bc][comp] carries
    __shared__ float Td_s[65];
    int h = blockIdx.x, bc0 = blockIdx.y * 128;
    int tid = threadIdx.x;
    int lane = tid & 63, wv = tid >> 6, quad = lane >> 4, fr = lane & 15;
    if (tid < 65) Td_s[tid] = Tdl[(size_t)h * 66 + tid];
#pragma unroll
    for (int i = 0; i < 2; ++i) {                // stage M transposed into A_s cols 64..127
        int q = tid + i * 256, comp = q >> 3, seg = q & 7;
        uint4 v = *(const uint4*)&Mg[((size_t)h * 64 + comp) * 64 + seg * 8];
        const bf16* pv = (const bf16*)&v;
#pragma unroll
        for (int e = 0; e < 8; ++e) A_s[(seg * 8 + e) * 136 + 64 + comp] = pv[e];
    }
#pragma unroll
    for (int i = 0; i < 4; ++i) {                // stage u tile
        int q = tid + i * 256, row = q >> 3, c8 = q & 7;
        *(uint4*)&u_s[row * 72 + c8 * 8] =
            *(const uint4*)&Ut[(size_t)h * M_ROWS + (size_t)(bc0 + row) * 64 + c8 * 8];
    }
    __syncthreads();                             // u_s + Td_s ready
#pragma unroll
    for (int i = 0; i < 16; ++i) {               // Toeplitz T fill (read before C-MFMA sync)
        int q = tid + i * 256, l = q >> 6, j = q & 63, d = l - j;
        A_s[l * 136 + j] = __float2bfloat16(d >= 0 ? Td_s[d] : 0.f);
    }
    // ---- E-MFMA: V fragments straight from global (L2-hot, 8KB/block read once) ----
    f32x4 eacc[4][2];
#pragma unroll
    for (int mt = 0; mt < 4; ++mt)
#pragma unroll
        for (int nf = 0; nf < 2; ++nf) eacc[mt][nf] = (f32x4){0.f, 0.f, 0.f, 0.f};
#pragma unroll
    for (int ks = 0; ks < 2; ++ks) {
        bf16x8 a[4], b[2];
#pragma unroll
        for (int mt = 0; mt < 4; ++mt)
            a[mt] = *(const bf16x8*)&Vg[((size_t)h * 64 + mt * 16 + fr) * 64 + ks * 32 + quad * 8];
#pragma unroll
        for (int nf = 0; nf < 2; ++nf)
            b[nf] = *(const bf16x8*)&u_s[(wv * 32 + nf * 16 + fr) * 72 + ks * 32 + quad * 8];
#pragma unroll
        for (int mt = 0; mt < 4; ++mt)
#pragma unroll
            for (int nf = 0; nf < 2; ++nf)
                eacc[mt][nf] = __builtin_amdgcn_mfma_f32_16x16x32_bf16(a[mt], b[nf], eacc[mt][nf], 0, 0, 0);
    }
#pragma unroll
    for (int mt = 0; mt < 4; ++mt)               // E -> Eo_s [bc][comp], packed pairs
#pragma unroll
        for (int nf = 0; nf < 2; ++nf) {
            int bc = wv * 32 + nf * 16 + fr;
#pragma unroll
            for (int r = 0; r < 4; r += 2) {
                int comp = mt * 16 + quad * 4 + r;
                *(unsigned int*)&Eo_s[bc * 72 + comp] =
                    (unsigned int)f2bu(eacc[mt][nf][r]) | ((unsigned int)f2bu(eacc[mt][nf][r + 1]) << 16);
            }
        }
    __syncthreads();                             // Eo ready
    {                                            // in-block carry scan: thread = (b_local, n)
        int bl = tid >> 5, n = tid & 31;
        float2 a = PA[n * HDIM + h];
        float cr = 0.f, ci = 0.f;
#pragma unroll
        for (int c = 0; c < NCH; ++c) {
            int bc = bl * NCH + c;
            unsigned int ev = *(const unsigned int*)&Eo_s[bc * 72 + 2 * n];
            *(unsigned int*)&c_s[bc * 72 + 2 * n] =
                (unsigned int)f2bu(cr) | ((unsigned int)f2bu(ci) << 16);
            float er = bu2f((unsigned short)(ev & 0xffff));
            float ei = bu2f((unsigned short)(ev >> 16));
            float nr = fmaf(a.x, cr, fmaf(-a.y, ci, er));
            ci = fmaf(a.x, ci, fmaf(a.y, cr, ei));
            cr = nr;
        }
    }
    __syncthreads();                             // carries + T fill complete; Eo reusable
    bf16* o_s = Eo_s;
    f32x4 acc[4][2];
#pragma unroll
    for (int mt = 0; mt < 4; ++mt)
#pragma unroll
        for (int nf = 0; nf < 2; ++nf) acc[mt][nf] = (f32x4){0.f, 0.f, 0.f, 0.f};
#pragma unroll
    for (int ks = 0; ks < 4; ++ks) {
        bf16x8 a[4], b[2];
#pragma unroll
        for (int mt = 0; mt < 4; ++mt)
            a[mt] = *(const bf16x8*)&A_s[(mt * 16 + fr) * 136 + ks * 32 + quad * 8];
#pragma unroll
        for (int nf = 0; nf < 2; ++nf) {
            int row = (wv * 32 + nf * 16 + fr) * 72;
            b[nf] = (ks < 2) ? *(const bf16x8*)&u_s[row + ks * 32 + quad * 8]
                             : *(const bf16x8*)&c_s[row + (ks - 2) * 32 + quad * 8];
        }
#pragma unroll
        for (int mt = 0; mt < 4; ++mt)
#pragma unroll
            for (int nf = 0; nf < 2; ++nf)
                acc[mt][nf] = __builtin_amdgcn_mfma_f32_16x16x32_bf16(a[mt], b[nf], acc[mt][nf], 0, 0, 0);
    }
    float Dv = Dw[h];
#pragma unroll
    for (int mt = 0; mt < 4; ++mt)
#pragma unroll
        for (int nf = 0; nf < 2; ++nf) {
            int bcl = wv * 32 + nf * 16 + fr;
#pragma unroll
            for (int r = 0; r < 4; ++r) {
                int l = mt * 16 + quad * 4 + r;
                float u = __bfloat162float(u_s[bcl * 72 + l]);
                float v = fmaf(Dv, u, acc[mt][nf][r]);
                float z2 = 1.5957691216057308f * (v + 0.044715f * v * v * v);
                o_s[bcl * 72 + l] = __float2bfloat16(v / (1.f + __expf(-z2)));
            }
        }
    __syncthreads();
#pragma unroll
    for (int i = 0; i < 4; ++i) {                // coalesced Yt store
        int q = tid + i * 256, row = q >> 3, c8 = q & 7;
        *(uint4*)&Yt[(size_t)h * M_ROWS + (size_t)(bc0 + row) * 64 + c8 * 8] =
            *(uint4*)&o_s[row * 72 + c8 * 8];
    }
}

// ---------------- output GEMM + fused GLU, bf16 MFMA, bf16 G out ----------------
__global__ __launch_bounds__(256) void k_glu(const bf16* __restrict__ Ybf,
                                             const bf16* __restrict__ Wt,
                                             const float* __restrict__ wb,
                                             bf16* __restrict__ G) {
    __shared__ short A_s[128 * 72];
    __shared__ short B1_s[64 * 72];
    __shared__ short B2_s[64 * 72];
    int tid = threadIdx.x;
    int lane = tid & 63, wv = tid >> 6;
    int quad = lane >> 4, fr = lane & 15;
    int m0 = blockIdx.x * 128, n0 = blockIdx.y * 64;
    f32x4 acc1[2][4], acc2[2][4];
#pragma unroll
    for (int mt = 0; mt < 2; ++mt)
#pragma unroll
        for (int nt = 0; nt < 4; ++nt) {
            acc1[mt][nt] = (f32x4){0.f,0.f,0.f,0.f};
            acc2[mt][nt] = (f32x4){0.f,0.f,0.f,0.f};
        }
    for (int kt = 0; kt < HDIM; kt += 64) {
#pragma unroll
        for (int i = 0; i < 4; ++i) {
            int e = tid + i * 256, row = e >> 3, cm = e & 7;
            *(uint4*)&A_s[row * 72 + cm * 8] =
                *(const uint4*)(Ybf + (size_t)(m0 + row) * HDIM + kt + cm * 8);
        }
#pragma unroll
        for (int i = 0; i < 2; ++i) {
            int e = tid + i * 256, row = e >> 3, cm = e & 7;
            *(uint4*)&B1_s[row * 72 + cm * 8] =
                *(const uint4*)(Wt + (size_t)(n0 + row) * HDIM + kt + cm * 8);
            *(uint4*)&B2_s[row * 72 + cm * 8] =
                *(const uint4*)(Wt + (size_t)(256 + n0 + row) * HDIM + kt + cm * 8);
        }
        __syncthreads();
#pragma unroll
        for (int s = 0; s < 2; ++s) {
            bf16x8 a[2], b1[4], b2[4];
#pragma unroll
            for (int mt = 0; mt < 2; ++mt)
                a[mt] = *(const bf16x8*)&A_s[(wv * 32 + mt * 16 + fr) * 72 + s * 32 + quad * 8];
#pragma unroll
            for (int nt = 0; nt < 4; ++nt) {
                b1[nt] = *(const bf16x8*)&B1_s[(nt * 16 + fr) * 72 + s * 32 + quad * 8];
                b2[nt] = *(const bf16x8*)&B2_s[(nt * 16 + fr) * 72 + s * 32 + quad * 8];
            }
#pragma unroll
            for (int mt = 0; mt < 2; ++mt)
#pragma unroll
                for (int nt = 0; nt < 4; ++nt) {
                    acc1[mt][nt] = __builtin_amdgcn_mfma_f32_16x16x32_bf16(a[mt], b1[nt], acc1[mt][nt], 0, 0, 0);
                    acc2[mt][nt] = __builtin_amdgcn_mfma_f32_16x16x32_bf16(a[mt], b2[nt], acc2[mt][nt], 0, 0, 0);
                }
        }
        __syncthreads();
    }
#pragma unroll
    for (int mt = 0; mt < 2; ++mt)
#pragma unroll
        for (int nt = 0; nt < 4; ++nt) {
            int n = n0 + nt * 16 + fr;
            float b1v = wb[n], b2v = wb[HDIM + n];
#pragma unroll
            for (int r = 0; r < 4; ++r) {
                int m = m0 + wv * 32 + mt * 16 + quad * 4 + r;
                float z1 = acc1[mt][nt][r] + b1v;
                float z2 = acc2[mt][nt][r] + b2v;
                G[(size_t)m * HDIM + n] = __float2bfloat16(z1 / (1.0f + __expf(-z2)));
            }
        }
}

// ---------------- residual + LayerNorm, 64-row tiles, fused transposed Ut emit ----------------
__global__ __launch_bounds__(256) void k_ln2(const bf16* __restrict__ G, float* __restrict__ Hb,
                                             const float* __restrict__ w, const float* __restrict__ bb,
                                             bf16* __restrict__ Ut, int writeUt) {
    __shared__ bf16 t_s[256][72];
    __shared__ float red[2][4][64];
    __shared__ float stat[2][64];
    __shared__ float w_s[256], b_s[256];
    int m0 = blockIdx.x * 64;
    int tid = threadIdx.x;
    int r = tid & 63, qd = tid >> 6;
    w_s[tid] = w[tid]; b_s[tid] = bb[tid];
    const bf16* Gp = G + (size_t)(m0 + r) * HDIM + qd * 64;
    float*      Hp = Hb + (size_t)(m0 + r) * HDIM + qd * 64;
    float rv[64];
    float sum = 0.f, sq = 0.f;
#pragma unroll
    for (int j = 0; j < 64; j += 8) {
        uint4 gv = *(const uint4*)&Gp[j];
        const bf16* gp = (const bf16*)&gv;
        float4 h0 = *(const float4*)&Hp[j];
        float4 h1 = *(const float4*)&Hp[j + 4];
        float hv[8] = {h0.x, h0.y, h0.z, h0.w, h1.x, h1.y, h1.z, h1.w};
#pragma unroll
        for (int e = 0; e < 8; ++e) {
            float v = __bfloat162float(gp[e]) + hv[e];
            rv[j + e] = v; sum += v; sq += v * v;
        }
    }
    red[0][qd][r] = sum; red[1][qd][r] = sq;
    __syncthreads();
    if (tid < 64) {
        float s  = red[0][0][tid] + red[0][1][tid] + red[0][2][tid] + red[0][3][tid];
        float s2 = red[1][0][tid] + red[1][1][tid] + red[1][2][tid] + red[1][3][tid];
        float mean = s * (1.f / HDIM);
        float var = s2 * (1.f / HDIM) - mean * mean;
        stat[0][tid] = mean; stat[1][tid] = rsqrtf(var + 1e-5f);
    }
    __syncthreads();
    float mean = stat[0][r], rstd = stat[1][r];
#pragma unroll
    for (int j = 0; j < 64; ++j)
        rv[j] = (rv[j] - mean) * rstd * w_s[qd * 64 + j] + b_s[qd * 64 + j];
#pragma unroll
    for (int j = 0; j < 64; j += 4)
        *(float4*)&Hp[j] = make_float4(rv[j], rv[j + 1], rv[j + 2], rv[j + 3]);
    if (writeUt) {
#pragma unroll
        for (int j = 0; j < 64; ++j) t_s[qd * 64 + j][r] = __float2bfloat16(rv[j]);
        __syncthreads();
#pragma unroll
        for (int i = 0; i < 8; ++i) {            // coalesced Ut store: 256 h rows x 64 m
            int q = tid + i * 256, hh = q >> 3, seg = q & 7;
            *(uint4*)&Ut[(size_t)hh * M_ROWS + m0 + seg * 8] = *(uint4*)&t_s[hh][seg * 8];
        }
    }
}

// ---------------- decoder ----------------
__global__ void k_dec(const float* __restrict__ Hb, const float* __restrict__ dw,
                      const float* __restrict__ db, float* __restrict__ out) {
    __shared__ float ws[HDIM * DOUT];
    int tid = threadIdx.x;                    // 320 threads
    for (int e = tid; e < HDIM * DOUT; e += 320) ws[e] = dw[e];
    __syncthreads();
    int r = tid / DOUT, o = tid - r * DOUT;
    int row = blockIdx.x * 32 + r;
    float acc = db[o];
    const float* hp = Hb + (size_t)row * HDIM;
#pragma unroll 8
    for (int k = 0; k < HDIM; ++k) acc = fmaf(hp[k], ws[k * DOUT + o], acc);
    out[row * DOUT + o] = acc;
}

extern "C" void kernel_launch(void* const* d_in, const int* in_sizes, int n_in,
                              void* d_out, int out_size, void* d_ws, size_t ws_size,
                              hipStream_t stream) {
    const float* x        = (const float*)d_in[0];
    const float* enc_w    = (const float*)d_in[1];
    const float* enc_b    = (const float*)d_in[2];
    const float* log_dt   = (const float*)d_in[3];
    const float* A_re_log = (const float*)d_in[4];
    const float* A_im     = (const float*)d_in[5];
    const float* B_re     = (const float*)d_in[6];
    const float* B_im     = (const float*)d_in[7];
    const float* C_re     = (const float*)d_in[8];
    const float* C_im     = (const float*)d_in[9];
    const float* Dp       = (const float*)d_in[10];
    const float* ln_w     = (const float*)d_in[11];
    const float* ln_b     = (const float*)d_in[12];
    const float* out_w    = (const float*)d_in[13];
    const float* out_b    = (const float*)d_in[14];
    const float* dec_w    = (const float*)d_in[15];
    const float* dec_b    = (const float*)d_in[16];
    float* outp = (float*)d_out;

    float* w = (float*)d_ws;
    const size_t PWE = (size_t)NLAYERS * NSTATE * HDIM;   // 32768
    const size_t MH  = (size_t)M_ROWS * HDIM;             // 8388608
    const size_t VME = (size_t)NLAYERS * HDIM * 64 * 64;  // 4M elements per matrix
    float4* PWt  = (float4*)w;                            // 512 KB
    float2* PA64 = (float2*)(w + 4 * PWE);                // 256 KB
    float*  Td   = w + 6 * PWE;                           // 270 KB
    float*  Hbuf = Td + (size_t)NLAYERS * HDIM * 66;      // 33.5 MB fp32
    bf16*   R4   = (bf16*)(Hbuf + MH);                    // 16.7 MB: Yt then G
    bf16*   R3   = R4 + MH;                               // 16.7 MB: Ut then Ybf
    bf16*   Wt   = R3 + MH;                               // 1 MB
    bf16*   Wet  = Wt + (size_t)NLAYERS * 512 * HDIM;     // 64 KB
    bf16*   Vg   = Wet + (size_t)HDIM * DIN;              // 8 MB (all layers)
    bf16*   Mg   = Vg + VME;                              // 8 MB (all layers)
    bf16*   Yt  = R4;
    bf16*   G   = R4;
    bf16*   Ut  = R3;
    bf16*   Ybf = R3;

    k_params<<<NLAYERS * HDIM * NSTATE / 256, 256, 0, stream>>>(log_dt, A_re_log, A_im,
                                                                B_re, B_im, C_re, C_im, PWt, PA64);
    k_td<<<NLAYERS, 256, 0, stream>>>(PWt, Td);
    k_vm<<<NLAYERS * HDIM * 64 / 256, 256, 0, stream>>>(PWt, Vg, Mg);
    k_wcvt<<<NLAYERS * 512 * 256 / 256, 256, 0, stream>>>(out_w, Wt);
    k_wenc<<<HDIM * DIN / 256, 256, 0, stream>>>(enc_w, Wet);

    dim3 ge(M_ROWS / 128, HDIM / 64);
    k_enc2<<<ge, 256, 0, stream>>>(x, Wet, enc_b, Hbuf, Ut);

    dim3 gtr(M_ROWS / 64, HDIM / 64);
    dim3 gconv(HDIM, NBC / 128);
    dim3 gg(M_ROWS / 128, HDIM / 64);

    for (int layer = 0; layer < NLAYERS; ++layer) {
        const float2* pal = PA64 + (size_t)layer * NSTATE * HDIM;
        const float*  tdl = Td + (size_t)layer * HDIM * 66;
        const bf16*   vgl = Vg + (size_t)layer * HDIM * 64 * 64;
        const bf16*   mgl = Mg + (size_t)layer * HDIM * 64 * 64;
        k_conv<<<gconv, 256, 0, stream>>>(Ut, vgl, mgl, tdl, pal, Dp + layer * HDIM, Yt);
        k_trY<<<gtr, 256, 0, stream>>>(Yt, Ybf);
        k_glu<<<gg, 256, 0, stream>>>(Ybf, Wt + (size_t)layer * 512 * HDIM,
                                      out_b + layer * 2 * HDIM, G);
        k_ln2<<<M_ROWS / 64, 256, 0, stream>>>(G, Hbuf, ln_w + layer * HDIM,
                                               ln_b + layer * HDIM, Ut,
                                               layer < NLAYERS - 1 ? 1 : 0);
    }
    k_dec<<<M_ROWS / 32, 320, 0, stream>>>(Hbuf, dec_w, dec_b, outp);
}